// Round 1
// baseline (3280.570 us; speedup 1.0000x reference)
//
#include <hip/hip_runtime.h>
#include <hip/hip_bf16.h>

// RetNet 2-layer forward, fp32 correctness-first implementation.
// B=16, S=1024, d=512, L=2, OUT=2, gamma = 1 - 2^-5.

#define D_MODEL 512
#define SEQ 1024
#define BATCH 16
#define NROWS (BATCH * SEQ)          // 16384
#define HID 1024                      // FFN hidden = 2*d
#define LOG2_GAMMA (-0.04580368961f)  // log2(0.96875)
#define KSCALE (0.044194173824f)      // 512^-0.5

// ---------------- LayerNorm: one wave per row ----------------
__global__ __launch_bounds__(64) void ln_kernel(const float* __restrict__ in,
                                                const float* __restrict__ g,
                                                const float* __restrict__ b,
                                                float* __restrict__ out) {
    int row = blockIdx.x;
    int t = threadIdx.x;
    const float* r = in + (long long)row * D_MODEL;
    float vals[8];
    float s = 0.f, s2 = 0.f;
#pragma unroll
    for (int i = 0; i < 8; i++) {
        float x = r[t + i * 64];
        vals[i] = x;
        s += x;
        s2 += x * x;
    }
#pragma unroll
    for (int off = 32; off > 0; off >>= 1) {
        s += __shfl_down(s, off);
        s2 += __shfl_down(s2, off);
    }
    s = __shfl(s, 0);
    s2 = __shfl(s2, 0);
    float mu = s * (1.f / D_MODEL);
    float var = s2 * (1.f / D_MODEL) - mu * mu;
    float rs = rsqrtf(var + 1e-6f);
    float* o = out + (long long)row * D_MODEL;
#pragma unroll
    for (int i = 0; i < 8; i++) {
        int c = t + i * 64;
        o[c] = (vals[i] - mu) * rs * g[c] + b[c];
    }
}

// ------------- GroupNorm(ret) * silu(g) -> ret (in place) -------------
__global__ __launch_bounds__(64) void gate_kernel(float* __restrict__ ret,
                                                  const float* __restrict__ gin) {
    int row = blockIdx.x;
    int t = threadIdx.x;
    float* r = ret + (long long)row * D_MODEL;
    const float* gg = gin + (long long)row * D_MODEL;
    float vals[8];
    float s = 0.f, s2 = 0.f;
#pragma unroll
    for (int i = 0; i < 8; i++) {
        float x = r[t + i * 64];
        vals[i] = x;
        s += x;
        s2 += x * x;
    }
#pragma unroll
    for (int off = 32; off > 0; off >>= 1) {
        s += __shfl_down(s, off);
        s2 += __shfl_down(s2, off);
    }
    s = __shfl(s, 0);
    s2 = __shfl(s2, 0);
    float mu = s * (1.f / D_MODEL);
    float var = s2 * (1.f / D_MODEL) - mu * mu;
    float rs = rsqrtf(var + 1e-6f);
#pragma unroll
    for (int i = 0; i < 8; i++) {
        int c = t + i * 64;
        float x = gg[c];
        float silu = x / (1.f + expf(-x));
        r[c] = silu * (vals[i] - mu) * rs;
    }
}

__device__ inline float gelu_tanh(float x) {
    const float c0 = 0.7978845608028654f;  // sqrt(2/pi)
    float x3 = x * x * x;
    return 0.5f * x * (1.f + tanhf(c0 * (x + 0.044715f * x3)));
}

// ---------------- tiled fp32 GEMM: C[M,N] (+)= A[M,K] @ B[K,N] ----------------
// EPI: 0 store, 1 store+bias, 2 store gelu(acc+bias), 3 accumulate into C,
//      4 accumulate + bias
constexpr int TS = 64;
constexpr int KTT = 16;

template <int EPI>
__global__ __launch_bounds__(256) void gemm_kernel(
    const float* __restrict__ A, const float* __restrict__ B,
    const float* __restrict__ bias, float* __restrict__ C,
    int M, int N, int K, long long sA, long long sB, long long sC) {
    A += (long long)blockIdx.z * sA;
    B += (long long)blockIdx.z * sB;
    C += (long long)blockIdx.z * sC;
    __shared__ float As[KTT][TS + 4];
    __shared__ float Bs[KTT][TS + 4];
    int tid = threadIdx.x;
    int tx = tid & 15, ty = tid >> 4;
    int m0 = blockIdx.y * TS, n0 = blockIdx.x * TS;
    float acc[4][4] = {};
    for (int k0 = 0; k0 < K; k0 += KTT) {
        {
            int c = tid & 15, r = tid >> 4;
#pragma unroll
            for (int i = 0; i < 4; i++)
                As[c][r + 16 * i] = A[(long long)(m0 + r + 16 * i) * K + k0 + c];
            int cb = tid & 63, rb = tid >> 6;
#pragma unroll
            for (int i = 0; i < 4; i++)
                Bs[rb + 4 * i][cb] = B[(long long)(k0 + rb + 4 * i) * N + n0 + cb];
        }
        __syncthreads();
#pragma unroll
        for (int kk = 0; kk < KTT; kk++) {
            float a0[4], b0[4];
#pragma unroll
            for (int i = 0; i < 4; i++) a0[i] = As[kk][ty * 4 + i];
#pragma unroll
            for (int j = 0; j < 4; j++) b0[j] = Bs[kk][tx * 4 + j];
#pragma unroll
            for (int i = 0; i < 4; i++)
#pragma unroll
                for (int j = 0; j < 4; j++) acc[i][j] += a0[i] * b0[j];
        }
        __syncthreads();
    }
#pragma unroll
    for (int i = 0; i < 4; i++) {
        int row = m0 + ty * 4 + i;
        float* crow = C + (long long)row * N + n0 + tx * 4;
#pragma unroll
        for (int j = 0; j < 4; j++) {
            float vv = acc[i][j];
            int col = n0 + tx * 4 + j;
            if (EPI == 1) vv += bias[col];
            if (EPI == 2) vv = gelu_tanh(vv + bias[col]);
            if (EPI == 3) vv += crow[j];
            if (EPI == 4) vv += crow[j] + bias[col];
            crow[j] = vv;
        }
    }
}

// ------ scores = (q @ k^T) * D * KSCALE, per-batch M=N=SEQ, K=D_MODEL ------
__global__ __launch_bounds__(256) void gemm_nt_decay(
    const float* __restrict__ A, const float* __restrict__ B,
    float* __restrict__ C) {
    const int K = D_MODEL;
    A += (long long)blockIdx.z * SEQ * K;
    B += (long long)blockIdx.z * SEQ * K;
    C += (long long)blockIdx.z * SEQ * SEQ;
    int m0 = blockIdx.x * TS;  // key index (col)
    int n0 = blockIdx.y * TS;  // query index (row)
    int tid = threadIdx.x;
    int tx = tid & 15, ty = tid >> 4;
    if (m0 >= n0 + TS) {  // entire tile above diagonal -> zero
#pragma unroll
        for (int i = 0; i < 4; i++) {
            float* crow = C + (long long)(n0 + ty * 4 + i) * SEQ + m0 + tx * 4;
#pragma unroll
            for (int j = 0; j < 4; j++) crow[j] = 0.f;
        }
        return;
    }
    __shared__ float As[KTT][TS + 4];
    __shared__ float Bs[KTT][TS + 4];
    float acc[4][4] = {};
    for (int k0 = 0; k0 < K; k0 += KTT) {
        int c = tid & 15, r = tid >> 4;
#pragma unroll
        for (int i = 0; i < 4; i++)
            As[c][r + 16 * i] = A[(long long)(n0 + r + 16 * i) * K + k0 + c];
#pragma unroll
        for (int i = 0; i < 4; i++)
            Bs[c][r + 16 * i] = B[(long long)(m0 + r + 16 * i) * K + k0 + c];
        __syncthreads();
#pragma unroll
        for (int kk = 0; kk < KTT; kk++) {
            float a0[4], b0[4];
#pragma unroll
            for (int i = 0; i < 4; i++) a0[i] = As[kk][ty * 4 + i];
#pragma unroll
            for (int j = 0; j < 4; j++) b0[j] = Bs[kk][tx * 4 + j];
#pragma unroll
            for (int i = 0; i < 4; i++)
#pragma unroll
                for (int j = 0; j < 4; j++) acc[i][j] += a0[i] * b0[j];
        }
        __syncthreads();
    }
#pragma unroll
    for (int i = 0; i < 4; i++) {
        int n = n0 + ty * 4 + i;
        float* crow = C + (long long)n * SEQ + m0 + tx * 4;
#pragma unroll
        for (int j = 0; j < 4; j++) {
            int m = m0 + tx * 4 + j;
            float w = (n >= m) ? exp2f((float)(n - m) * LOG2_GAMMA) * KSCALE : 0.f;
            crow[j] = acc[i][j] * w;
        }
    }
}

// ---------------- pooling over sequence ----------------
__global__ __launch_bounds__(256) void pool_kernel(const float* __restrict__ h,
                                                   float* __restrict__ pooled) {
    int idx = blockIdx.x * 256 + threadIdx.x;  // 0..8191
    int b = idx >> 9;
    int c = idx & 511;
    const float* p = h + (long long)b * SEQ * D_MODEL + c;
    float s = 0.f;
    for (int t = 0; t < SEQ; t++) s += p[t * D_MODEL];
    pooled[idx] = s;
}

// ---------------- readout: out[b,o] = pooled[b,:] . Wro[:,o] + bro[o] ----------------
__global__ __launch_bounds__(64) void readout_kernel(const float* __restrict__ pooled,
                                                     const float* __restrict__ Wro,
                                                     const float* __restrict__ bro,
                                                     float* __restrict__ out) {
    int bo = blockIdx.x;  // 0..31
    int b = bo >> 1, o = bo & 1;
    int t = threadIdx.x;
    float s = 0.f;
    for (int i = t; i < D_MODEL; i += 64) s += pooled[b * D_MODEL + i] * Wro[i * 2 + o];
#pragma unroll
    for (int off = 32; off > 0; off >>= 1) s += __shfl_down(s, off);
    if (t == 0) out[b * 2 + o] = s + bro[o];
}

extern "C" void kernel_launch(void* const* d_in, const int* in_sizes, int n_in,
                              void* d_out, int out_size, void* d_ws, size_t ws_size,
                              hipStream_t stream) {
    const float* x = (const float*)d_in[0];
    const float* Wq = (const float*)d_in[1];
    const float* Wk = (const float*)d_in[2];
    const float* Wv = (const float*)d_in[3];
    const float* Wg = (const float*)d_in[4];
    const float* Wo = (const float*)d_in[5];
    const float* ln1_g = (const float*)d_in[6];
    const float* ln1_b = (const float*)d_in[7];
    const float* ln2_g = (const float*)d_in[8];
    const float* ln2_b = (const float*)d_in[9];
    const float* W1 = (const float*)d_in[10];
    const float* b1 = (const float*)d_in[11];
    const float* W2 = (const float*)d_in[12];
    const float* b2 = (const float*)d_in[13];
    const float* Wro = (const float*)d_in[14];
    const float* bro = (const float*)d_in[15];
    float* out = (float*)d_out;

    const long long NE = (long long)NROWS * D_MODEL;  // 8,388,608
    float* h = (float*)d_ws;
    float* y = h + NE;
    float* qb = y + NE;      // q, later g
    float* kb = qb + NE;     // k, later ret/gated
    float* vb = kb + NE;     // v
    float* big = vb + NE;    // scores [B,S,S], later ffn hidden [NROWS,HID]
    float* pooled = big + 2 * NE;
    // total = 7*NE + 8192 floats ~= 235 MB, assumed <= ws_size

    const long long dd = (long long)D_MODEL * D_MODEL;

    // h = x
    hipMemcpyAsync(h, x, NE * sizeof(float), hipMemcpyDeviceToDevice, stream);

    dim3 blk(256);
    dim3 gProj(D_MODEL / TS, NROWS / TS, 1);    // (8, 256)
    dim3 gFF1(HID / TS, NROWS / TS, 1);         // (16, 256)
    dim3 gScores(SEQ / TS, SEQ / TS, BATCH);    // (16,16,16)
    dim3 gRet(D_MODEL / TS, SEQ / TS, BATCH);   // (8,16,16)

    for (int l = 0; l < 2; l++) {
        // y = LN1(h)
        ln_kernel<<<NROWS, 64, 0, stream>>>(h, ln1_g + l * D_MODEL, ln1_b + l * D_MODEL, y);
        // q, k, v
        gemm_kernel<0><<<gProj, blk, 0, stream>>>(y, Wq + l * dd, nullptr, qb,
                                                  NROWS, D_MODEL, D_MODEL, 0, 0, 0);
        gemm_kernel<0><<<gProj, blk, 0, stream>>>(y, Wk + l * dd, nullptr, kb,
                                                  NROWS, D_MODEL, D_MODEL, 0, 0, 0);
        gemm_kernel<0><<<gProj, blk, 0, stream>>>(y, Wv + l * dd, nullptr, vb,
                                                  NROWS, D_MODEL, D_MODEL, 0, 0, 0);
        // scores = (q k^T) * D, per batch
        gemm_nt_decay<<<gScores, blk, 0, stream>>>(qb, kb, big);
        // ret = scores @ v  -> into kb (k is dead)
        gemm_kernel<0><<<gRet, blk, 0, stream>>>(big, vb, nullptr, kb,
                                                 SEQ, D_MODEL, SEQ,
                                                 (long long)SEQ * SEQ,
                                                 (long long)SEQ * D_MODEL,
                                                 (long long)SEQ * D_MODEL);
        // g = y @ Wg -> into qb (q is dead)
        gemm_kernel<0><<<gProj, blk, 0, stream>>>(y, Wg + l * dd, nullptr, qb,
                                                  NROWS, D_MODEL, D_MODEL, 0, 0, 0);
        // kb = silu(g) * groupnorm(ret)
        gate_kernel<<<NROWS, 64, 0, stream>>>(kb, qb);
        // h += kb @ Wo
        gemm_kernel<3><<<gProj, blk, 0, stream>>>(kb, Wo + l * dd, nullptr, h,
                                                  NROWS, D_MODEL, D_MODEL, 0, 0, 0);
        // FFN
        ln_kernel<<<NROWS, 64, 0, stream>>>(h, ln2_g + l * D_MODEL, ln2_b + l * D_MODEL, y);
        gemm_kernel<2><<<gFF1, blk, 0, stream>>>(y, W1 + (long long)l * D_MODEL * HID,
                                                 b1 + l * HID, big,
                                                 NROWS, HID, D_MODEL, 0, 0, 0);
        gemm_kernel<4><<<gProj, blk, 0, stream>>>(big, W2 + (long long)l * HID * D_MODEL,
                                                  b2 + l * D_MODEL, h,
                                                  NROWS, D_MODEL, HID, 0, 0, 0);
    }

    pool_kernel<<<32, 256, 0, stream>>>(h, pooled);
    readout_kernel<<<32, 64, 0, stream>>>(pooled, Wro, bro, out);
}

// Round 2
// 727.439 us; speedup vs baseline: 4.5098x; 4.5098x over previous
//
#include <hip/hip_runtime.h>
#include <hip/hip_bf16.h>

// RetNet 2-layer forward. bf16 MFMA GEMMs (m97 structure), fp32 residual stream.
// B=16, S=1024, d=512, L=2, OUT=2, gamma = 1 - 2^-5.

#define D_MODEL 512
#define SEQ 1024
#define BATCH 16
#define NROWS (BATCH * SEQ)          // 16384
#define HID 1024
#define LOG2_GAMMA (-0.04580368961f)  // log2(0.96875)
#define KSCALE (0.044194173824f)      // 512^-0.5

typedef __attribute__((ext_vector_type(8))) short bf16x8;
typedef __attribute__((ext_vector_type(4))) float f32x4;

__device__ inline unsigned short f2bf(float x) {
    union { float f; unsigned u; } uu; uu.f = x;
    unsigned r = uu.u + 0x7fff + ((uu.u >> 16) & 1);
    return (unsigned short)(r >> 16);
}
__device__ inline float bf2f(unsigned short x) {
    union { unsigned u; float f; } uu; uu.u = ((unsigned)x) << 16; return uu.f;
}

__device__ inline void gload_lds16(const void* g, void* l) {
    __builtin_amdgcn_global_load_lds(
        (const __attribute__((address_space(1))) void*)g,
        (__attribute__((address_space(3))) void*)l, 16, 0, 0);
}

__device__ inline float gelu_tanh(float x) {
    const float c0 = 0.7978845608028654f;
    float x3 = x * x * x;
    return 0.5f * x * (1.f + tanhf(c0 * (x + 0.044715f * x3)));
}

// ============ MFMA GEMM: C[M,N] = A[M,K] @ B^T[N,K]^T  (both K-contiguous) ============
// EPI: 0 store bf16, 1 store f32, 2 gelu(acc+bias)->bf16, 3 C+=acc (f32), 4 C+=acc+bias (f32)
// tri!=0: K-loop truncated at m0+128 (for scores@v with causal-zero scores).
template <int EPI>
__global__ __launch_bounds__(256) void mgemm(
    const short* __restrict__ A, const short* __restrict__ B,
    const float* __restrict__ bias, void* __restrict__ Cv,
    int M, int N, int K, long long sA, long long sB, long long sC, int tri) {
    __shared__ short As[128 * 32];
    __shared__ short Bs[128 * 32];
    const int tid = threadIdx.x;
    const int lane = tid & 63;
    const int wid = tid >> 6;
    const int wr = wid >> 1, wc = wid & 1;
    const int m0 = blockIdx.y * 128, n0 = blockIdx.x * 128;
    A += (long long)blockIdx.z * sA;
    B += (long long)blockIdx.z * sB;

    int Keff = K;
    if (tri) { int km = m0 + 128; if (km < Keff) Keff = km; }

    f32x4 acc[4][4] = {};
    for (int k0 = 0; k0 < Keff; k0 += 32) {
#pragma unroll
        for (int it = 0; it < 2; ++it) {
            int slot = it * 256 + tid;
            int rr = slot >> 2;
            int cc = (slot & 3) * 8;
            gload_lds16(A + (long long)(m0 + rr) * K + k0 + cc,
                        &As[(it * 256 + wid * 64) * 8]);
            gload_lds16(B + (long long)(n0 + rr) * K + k0 + cc,
                        &Bs[(it * 256 + wid * 64) * 8]);
        }
        __syncthreads();
        bf16x8 af[4], bfr[4];
#pragma unroll
        for (int i = 0; i < 4; ++i)
            af[i] = *(const bf16x8*)&As[(wr * 64 + i * 16 + (lane & 15)) * 32 + (lane >> 4) * 8];
#pragma unroll
        for (int j = 0; j < 4; ++j)
            bfr[j] = *(const bf16x8*)&Bs[(wc * 64 + j * 16 + (lane & 15)) * 32 + (lane >> 4) * 8];
#pragma unroll
        for (int i = 0; i < 4; ++i)
#pragma unroll
            for (int j = 0; j < 4; ++j)
                acc[i][j] = __builtin_amdgcn_mfma_f32_16x16x32_bf16(af[i], bfr[j], acc[i][j], 0, 0, 0);
        __syncthreads();
    }
    const int orow = (lane >> 4) * 4;
    const int ocol = lane & 15;
    const long long zoff = (long long)blockIdx.z * sC;
#pragma unroll
    for (int i = 0; i < 4; ++i) {
#pragma unroll
        for (int j = 0; j < 4; ++j) {
            int colg = n0 + wc * 64 + j * 16 + ocol;
#pragma unroll
            for (int rj = 0; rj < 4; ++rj) {
                long long rowg = m0 + wr * 64 + i * 16 + orow + rj;
                long long idx = zoff + rowg * N + colg;
                float val = acc[i][j][rj];
                if (EPI == 0) ((unsigned short*)Cv)[idx] = f2bf(val);
                else if (EPI == 1) ((float*)Cv)[idx] = val;
                else if (EPI == 2) ((unsigned short*)Cv)[idx] = f2bf(gelu_tanh(val + bias[colg]));
                else if (EPI == 3) ((float*)Cv)[idx] += val;
                else if (EPI == 4) ((float*)Cv)[idx] += val + bias[colg];
            }
        }
    }
}

// ============ scores = (q @ k^T) * gamma^(n-m) * KSCALE, bf16 out, per-batch ============
__global__ __launch_bounds__(256) void mgemm_decay(
    const short* __restrict__ Q, const short* __restrict__ Kp,
    unsigned short* __restrict__ S) {
    const int q0 = blockIdx.y * 128;  // query rows
    const int c0 = blockIdx.x * 128;  // key cols
    unsigned short* Sb = S + (long long)blockIdx.z * SEQ * SEQ;
    if (blockIdx.x > blockIdx.y) {  // fully above diagonal -> zeros
        int4 z = {0, 0, 0, 0};
#pragma unroll
        for (int it = 0; it < 8; ++it) {
            int slot = it * 256 + threadIdx.x;
            int rr = slot >> 4;
            int cc = (slot & 15) * 8;
            *(int4*)&Sb[(long long)(q0 + rr) * SEQ + c0 + cc] = z;
        }
        return;
    }
    __shared__ short As[128 * 32];
    __shared__ short Bs[128 * 32];
    const int tid = threadIdx.x;
    const int lane = tid & 63;
    const int wid = tid >> 6;
    const int wr = wid >> 1, wc = wid & 1;
    const short* Ab = Q + (long long)blockIdx.z * SEQ * D_MODEL;
    const short* Bb = Kp + (long long)blockIdx.z * SEQ * D_MODEL;
    f32x4 acc[4][4] = {};
    for (int k0 = 0; k0 < D_MODEL; k0 += 32) {
#pragma unroll
        for (int it = 0; it < 2; ++it) {
            int slot = it * 256 + tid;
            int rr = slot >> 2;
            int cc = (slot & 3) * 8;
            gload_lds16(Ab + (long long)(q0 + rr) * D_MODEL + k0 + cc,
                        &As[(it * 256 + wid * 64) * 8]);
            gload_lds16(Bb + (long long)(c0 + rr) * D_MODEL + k0 + cc,
                        &Bs[(it * 256 + wid * 64) * 8]);
        }
        __syncthreads();
        bf16x8 af[4], bfr[4];
#pragma unroll
        for (int i = 0; i < 4; ++i)
            af[i] = *(const bf16x8*)&As[(wr * 64 + i * 16 + (lane & 15)) * 32 + (lane >> 4) * 8];
#pragma unroll
        for (int j = 0; j < 4; ++j)
            bfr[j] = *(const bf16x8*)&Bs[(wc * 64 + j * 16 + (lane & 15)) * 32 + (lane >> 4) * 8];
#pragma unroll
        for (int i = 0; i < 4; ++i)
#pragma unroll
            for (int j = 0; j < 4; ++j)
                acc[i][j] = __builtin_amdgcn_mfma_f32_16x16x32_bf16(af[i], bfr[j], acc[i][j], 0, 0, 0);
        __syncthreads();
    }
    const int orow = (lane >> 4) * 4;
    const int ocol = lane & 15;
#pragma unroll
    for (int i = 0; i < 4; ++i) {
#pragma unroll
        for (int j = 0; j < 4; ++j) {
            int m = c0 + wc * 64 + j * 16 + ocol;
#pragma unroll
            for (int rj = 0; rj < 4; ++rj) {
                int n = q0 + wr * 64 + i * 16 + orow + rj;
                float w = (n >= m) ? exp2f((float)(n - m) * LOG2_GAMMA) * KSCALE : 0.f;
                Sb[(long long)n * SEQ + m] = f2bf(acc[i][j][rj] * w);
            }
        }
    }
}

// ============ weight convert+transpose: fp32 [K][N] -> bf16 [N][K] ============
__global__ __launch_bounds__(256) void wconv_t(const float* __restrict__ in,
                                               unsigned short* __restrict__ out,
                                               int K, int N) {
    __shared__ unsigned short t[64][65];
    int n0 = blockIdx.x * 64, k0 = blockIdx.y * 64;
    int tx = threadIdx.x & 63, ty = threadIdx.x >> 6;
#pragma unroll
    for (int i = 0; i < 16; ++i)
        t[ty + i * 4][tx] = f2bf(in[(long long)(k0 + ty + i * 4) * N + n0 + tx]);
    __syncthreads();
#pragma unroll
    for (int i = 0; i < 16; ++i)
        out[(long long)(n0 + ty + i * 4) * K + k0 + tx] = t[tx][ty + i * 4];
}

// ============ per-batch transpose: bf16 [SEQ][D] -> [D][SEQ] ============
__global__ __launch_bounds__(256) void vtrans(const unsigned short* __restrict__ in,
                                              unsigned short* __restrict__ out) {
    __shared__ unsigned short t[64][65];
    const unsigned short* pin = in + (long long)blockIdx.z * SEQ * D_MODEL;
    unsigned short* pout = out + (long long)blockIdx.z * D_MODEL * SEQ;
    int c0 = blockIdx.x * 64, r0 = blockIdx.y * 64;
    int tx = threadIdx.x & 63, ty = threadIdx.x >> 6;
#pragma unroll
    for (int i = 0; i < 16; ++i)
        t[ty + i * 4][tx] = pin[(long long)(r0 + ty + i * 4) * D_MODEL + c0 + tx];
    __syncthreads();
#pragma unroll
    for (int i = 0; i < 16; ++i)
        pout[(long long)(c0 + ty + i * 4) * SEQ + r0 + tx] = t[tx][ty + i * 4];
}

// ============ LayerNorm -> bf16, 4 rows/block (1 wave each) ============
__global__ __launch_bounds__(256) void ln_bf16(const float* __restrict__ in,
                                               const float* __restrict__ g,
                                               const float* __restrict__ b,
                                               unsigned short* __restrict__ out) {
    int row = blockIdx.x * 4 + (threadIdx.x >> 6);
    int t = threadIdx.x & 63;
    const float4* r4 = (const float4*)(in + (long long)row * D_MODEL);
    float4 v0 = r4[t], v1 = r4[t + 64];
    float s = v0.x + v0.y + v0.z + v0.w + v1.x + v1.y + v1.z + v1.w;
    float s2 = v0.x * v0.x + v0.y * v0.y + v0.z * v0.z + v0.w * v0.w +
               v1.x * v1.x + v1.y * v1.y + v1.z * v1.z + v1.w * v1.w;
#pragma unroll
    for (int off = 32; off > 0; off >>= 1) {
        s += __shfl_down(s, off);
        s2 += __shfl_down(s2, off);
    }
    s = __shfl(s, 0); s2 = __shfl(s2, 0);
    float mu = s * (1.f / D_MODEL);
    float var = s2 * (1.f / D_MODEL) - mu * mu;
    float rs = rsqrtf(var + 1e-6f);
    const float4* g4 = (const float4*)g;
    const float4* b4 = (const float4*)b;
    float4 ga = g4[t], gb = g4[t + 64], ba = b4[t], bb = b4[t + 64];
    ushort4 o0, o1;
    o0.x = f2bf((v0.x - mu) * rs * ga.x + ba.x);
    o0.y = f2bf((v0.y - mu) * rs * ga.y + ba.y);
    o0.z = f2bf((v0.z - mu) * rs * ga.z + ba.z);
    o0.w = f2bf((v0.w - mu) * rs * ga.w + ba.w);
    o1.x = f2bf((v1.x - mu) * rs * gb.x + bb.x);
    o1.y = f2bf((v1.y - mu) * rs * gb.y + bb.y);
    o1.z = f2bf((v1.z - mu) * rs * gb.z + bb.z);
    o1.w = f2bf((v1.w - mu) * rs * gb.w + bb.w);
    ushort4* o4 = (ushort4*)(out + (long long)row * D_MODEL);
    o4[t] = o0; o4[t + 64] = o1;
}

// ============ gated = silu(g) * groupnorm(ret) -> bf16 ============
__global__ __launch_bounds__(256) void gate_bf16(const float* __restrict__ ret,
                                                 const unsigned short* __restrict__ g,
                                                 unsigned short* __restrict__ out) {
    int row = blockIdx.x * 4 + (threadIdx.x >> 6);
    int t = threadIdx.x & 63;
    const float4* r4 = (const float4*)(ret + (long long)row * D_MODEL);
    float4 v0 = r4[t], v1 = r4[t + 64];
    float s = v0.x + v0.y + v0.z + v0.w + v1.x + v1.y + v1.z + v1.w;
    float s2 = v0.x * v0.x + v0.y * v0.y + v0.z * v0.z + v0.w * v0.w +
               v1.x * v1.x + v1.y * v1.y + v1.z * v1.z + v1.w * v1.w;
#pragma unroll
    for (int off = 32; off > 0; off >>= 1) {
        s += __shfl_down(s, off);
        s2 += __shfl_down(s2, off);
    }
    s = __shfl(s, 0); s2 = __shfl(s2, 0);
    float mu = s * (1.f / D_MODEL);
    float var = s2 * (1.f / D_MODEL) - mu * mu;
    float rs = rsqrtf(var + 1e-6f);
    const ushort4* g4 = (const ushort4*)(g + (long long)row * D_MODEL);
    ushort4 ga = g4[t], gb = g4[t + 64];
    float gx[8] = {bf2f(ga.x), bf2f(ga.y), bf2f(ga.z), bf2f(ga.w),
                   bf2f(gb.x), bf2f(gb.y), bf2f(gb.z), bf2f(gb.w)};
    float rv[8] = {v0.x, v0.y, v0.z, v0.w, v1.x, v1.y, v1.z, v1.w};
    ushort4 o0, o1;
    unsigned short oo[8];
#pragma unroll
    for (int i = 0; i < 8; ++i) {
        float x = gx[i];
        float silu = x / (1.f + expf(-x));
        oo[i] = f2bf(silu * (rv[i] - mu) * rs);
    }
    o0.x = oo[0]; o0.y = oo[1]; o0.z = oo[2]; o0.w = oo[3];
    o1.x = oo[4]; o1.y = oo[5]; o1.z = oo[6]; o1.w = oo[7];
    ushort4* o4 = (ushort4*)(out + (long long)row * D_MODEL);
    o4[t] = o0; o4[t + 64] = o1;
}

// ============ pooling + readout ============
__global__ __launch_bounds__(256) void pool_kernel(const float* __restrict__ h,
                                                   float* __restrict__ pooled) {
    int idx = blockIdx.x * 256 + threadIdx.x;
    int b = idx >> 9;
    int c = idx & 511;
    const float* p = h + (long long)b * SEQ * D_MODEL + c;
    float s = 0.f;
    for (int t = 0; t < SEQ; t++) s += p[t * D_MODEL];
    pooled[idx] = s;
}

__global__ __launch_bounds__(64) void readout_kernel(const float* __restrict__ pooled,
                                                     const float* __restrict__ Wro,
                                                     const float* __restrict__ bro,
                                                     float* __restrict__ out) {
    int bo = blockIdx.x;
    int b = bo >> 1, o = bo & 1;
    int t = threadIdx.x;
    float s = 0.f;
    for (int i = t; i < D_MODEL; i += 64) s += pooled[b * D_MODEL + i] * Wro[i * 2 + o];
#pragma unroll
    for (int off = 32; off > 0; off >>= 1) s += __shfl_down(s, off);
    if (t == 0) out[b * 2 + o] = s + bro[o];
}

extern "C" void kernel_launch(void* const* d_in, const int* in_sizes, int n_in,
                              void* d_out, int out_size, void* d_ws, size_t ws_size,
                              hipStream_t stream) {
    const float* x = (const float*)d_in[0];
    const float* Wq = (const float*)d_in[1];
    const float* Wk = (const float*)d_in[2];
    const float* Wv = (const float*)d_in[3];
    const float* Wg = (const float*)d_in[4];
    const float* Wo = (const float*)d_in[5];
    const float* ln1_g = (const float*)d_in[6];
    const float* ln1_b = (const float*)d_in[7];
    const float* ln2_g = (const float*)d_in[8];
    const float* ln2_b = (const float*)d_in[9];
    const float* W1 = (const float*)d_in[10];
    const float* b1 = (const float*)d_in[11];
    const float* W2 = (const float*)d_in[12];
    const float* b2 = (const float*)d_in[13];
    const float* Wro = (const float*)d_in[14];
    const float* bro = (const float*)d_in[15];
    float* out = (float*)d_out;

    const long long NE = (long long)NROWS * D_MODEL;  // 8,388,608
    const long long dd = (long long)D_MODEL * D_MODEL;

    float* h = (float*)d_ws;                       // NE f32
    unsigned short* y = (unsigned short*)(h + NE); // NE bf16
    unsigned short* qb = y + NE;                   // NE bf16
    unsigned short* kb = qb + NE;                  // NE bf16
    float* ret = (float*)qb;                       // aliases q+k (NE f32)
    unsigned short* vb = kb + NE;                  // NE bf16
    unsigned short* gated = vb;                    // alias (v dead after vtrans+retGEMM)
    unsigned short* vT = vb + NE;                  // NE bf16
    unsigned short* sg = vT + NE;                  // 2*NE bf16: scores / g / ffn-hidden
    float* pooled = (float*)(sg + 2 * NE);         // 8192 f32
    unsigned short* wts = (unsigned short*)(pooled + 8192);
    unsigned short* WqT = wts;                 // [L][512][512]
    unsigned short* WkT = WqT + 2 * dd;
    unsigned short* WvT = WkT + 2 * dd;
    unsigned short* WgT = WvT + 2 * dd;
    unsigned short* WoT = WgT + 2 * dd;
    unsigned short* W1T = WoT + 2 * dd;        // [L][1024][512]
    unsigned short* W2T = W1T + 2 * (long long)D_MODEL * HID;  // [L][512][1024]

    hipMemcpyAsync(h, x, NE * sizeof(float), hipMemcpyDeviceToDevice, stream);

    dim3 blk(256);
    // weight prep: fp32 [K][N] -> bf16 [N][K]
    for (int l = 0; l < 2; l++) {
        wconv_t<<<dim3(8, 8), blk, 0, stream>>>(Wq + l * dd, WqT + l * dd, 512, 512);
        wconv_t<<<dim3(8, 8), blk, 0, stream>>>(Wk + l * dd, WkT + l * dd, 512, 512);
        wconv_t<<<dim3(8, 8), blk, 0, stream>>>(Wv + l * dd, WvT + l * dd, 512, 512);
        wconv_t<<<dim3(8, 8), blk, 0, stream>>>(Wg + l * dd, WgT + l * dd, 512, 512);
        wconv_t<<<dim3(8, 8), blk, 0, stream>>>(Wo + l * dd, WoT + l * dd, 512, 512);
        wconv_t<<<dim3(16, 8), blk, 0, stream>>>(W1 + (long long)l * D_MODEL * HID,
                                                 W1T + (long long)l * D_MODEL * HID, 512, 1024);
        wconv_t<<<dim3(8, 16), blk, 0, stream>>>(W2 + (long long)l * HID * D_MODEL,
                                                 W2T + (long long)l * HID * D_MODEL, 1024, 512);
    }

    dim3 gProj(4, 128, 1);     // N=512, M=16384
    dim3 gFF1(8, 128, 1);      // N=1024
    dim3 gScores(8, 8, BATCH);
    dim3 gRet(4, 8, BATCH);    // N=512, M=1024 per batch

    for (int l = 0; l < 2; l++) {
        ln_bf16<<<NROWS / 4, blk, 0, stream>>>(h, ln1_g + l * D_MODEL, ln1_b + l * D_MODEL, y);
        mgemm<0><<<gProj, blk, 0, stream>>>((const short*)y, (const short*)(WqT + l * dd),
                                            nullptr, qb, NROWS, 512, 512, 0, 0, 0, 0);
        mgemm<0><<<gProj, blk, 0, stream>>>((const short*)y, (const short*)(WkT + l * dd),
                                            nullptr, kb, NROWS, 512, 512, 0, 0, 0, 0);
        mgemm<0><<<gProj, blk, 0, stream>>>((const short*)y, (const short*)(WvT + l * dd),
                                            nullptr, vb, NROWS, 512, 512, 0, 0, 0, 0);
        vtrans<<<dim3(8, 16, BATCH), blk, 0, stream>>>(vb, vT);
        mgemm_decay<<<gScores, blk, 0, stream>>>((const short*)qb, (const short*)kb, sg);
        // ret = scores @ vT^T : A [1024 x 1024] bf16, B^T = vT [512][1024]
        mgemm<1><<<gRet, blk, 0, stream>>>((const short*)sg, (const short*)vT, nullptr, ret,
                                           SEQ, D_MODEL, SEQ,
                                           (long long)SEQ * SEQ, (long long)D_MODEL * SEQ,
                                           (long long)SEQ * D_MODEL, 1);
        // g = y @ Wg  (into sg region, scores dead)
        mgemm<0><<<gProj, blk, 0, stream>>>((const short*)y, (const short*)(WgT + l * dd),
                                            nullptr, sg, NROWS, 512, 512, 0, 0, 0, 0);
        gate_bf16<<<NROWS / 4, blk, 0, stream>>>(ret, sg, gated);
        // h += gated @ Wo
        mgemm<3><<<gProj, blk, 0, stream>>>((const short*)gated, (const short*)(WoT + l * dd),
                                            nullptr, h, NROWS, 512, 512, 0, 0, 0, 0);
        // FFN
        ln_bf16<<<NROWS / 4, blk, 0, stream>>>(h, ln2_g + l * D_MODEL, ln2_b + l * D_MODEL, y);
        mgemm<2><<<gFF1, blk, 0, stream>>>((const short*)y,
                                           (const short*)(W1T + (long long)l * D_MODEL * HID),
                                           b1 + l * HID, sg, NROWS, HID, 512, 0, 0, 0, 0);
        mgemm<4><<<gProj, blk, 0, stream>>>((const short*)sg,
                                           (const short*)(W2T + (long long)l * HID * D_MODEL),
                                           b2 + l * D_MODEL, h, NROWS, 512, HID, 0, 0, 0, 0);
    }

    pool_kernel<<<32, blk, 0, stream>>>(h, pooled);
    readout_kernel<<<32, 64, 0, stream>>>(pooled, Wro, bro, out);
}

// Round 3
// 664.669 us; speedup vs baseline: 4.9356x; 1.0944x over previous
//
#include <hip/hip_runtime.h>
#include <hip/hip_bf16.h>

// RetNet 2-layer forward. bf16 MFMA GEMMs, double-buffered LDS, fused QKVG.
// B=16, S=1024, d=512, L=2, OUT=2, gamma = 1 - 2^-5.

#define D_MODEL 512
#define SEQ 1024
#define BATCH 16
#define NROWS (BATCH * SEQ)          // 16384
#define HID 1024
#define LOG2_GAMMA (-0.04580368961f)  // log2(0.96875)
#define KSCALE (0.044194173824f)      // 512^-0.5

typedef __attribute__((ext_vector_type(8))) short bf16x8;
typedef __attribute__((ext_vector_type(4))) float f32x4;

__device__ inline unsigned short f2bf(float x) {
    union { float f; unsigned u; } uu; uu.f = x;
    unsigned r = uu.u + 0x7fff + ((uu.u >> 16) & 1);
    return (unsigned short)(r >> 16);
}
__device__ inline float bf2f(unsigned short x) {
    union { unsigned u; float f; } uu; uu.u = ((unsigned)x) << 16; return uu.f;
}

__device__ inline void gload_lds16(const void* g, void* l) {
    __builtin_amdgcn_global_load_lds(
        (const __attribute__((address_space(1))) void*)g,
        (__attribute__((address_space(3))) void*)l, 16, 0, 0);
}

// sigmoid via hardware exp2
__device__ inline float sigm(float z) {
    return 1.f / (1.f + exp2f(z * -1.442695040888963f));
}
__device__ inline float gelu_fast(float x) {
    // 0.5x(1+tanh(c0(x+0.044715x^3))) == x*sigmoid(2*c0*(x+0.044715x^3))
    float y = 1.5957691216057308f * (x + 0.044715f * x * x * x);
    return x * sigm(y);
}

// ============ MFMA GEMM, double-buffered ============
// C[M,N] = A[M,K(lda)] @ B[N,K(ldb)]^T ; BM=128, BN in {64,128}, BK=32.
// EPI: 0 store bf16, 1 store f32, 2 gelu(acc+bias)->bf16, 3 C+=acc (f32),
//      4 C+=acc+bias (f32)
// tri!=0: K truncated at m0+128 (scores@v with causal-zero scores).
template <int EPI, int BN>
__global__ __launch_bounds__(256) void mgemm(
    const short* __restrict__ A, const short* __restrict__ B,
    const float* __restrict__ bias, void* __restrict__ Cv,
    int N, int K, int lda, int ldb, int ldc,
    long long sA, long long sB, long long sC, int tri) {
    constexpr int MI = (BN == 128) ? 4 : 2;   // row frags per wave
    constexpr int WRS = (BN == 128) ? 64 : 32; // wave row span
    __shared__ short As[2][128 * 32];
    __shared__ short Bs[2][BN * 32];
    const int tid = threadIdx.x;
    const int lane = tid & 63;
    const int wid = tid >> 6;
    const int wr = (BN == 128) ? (wid >> 1) : wid;
    const int wc = (BN == 128) ? (wid & 1) : 0;
    const int m0 = blockIdx.y * 128, n0 = blockIdx.x * BN;
    A += (long long)blockIdx.z * sA;
    B += (long long)blockIdx.z * sB;

    int Keff = K;
    if (tri) { int km = m0 + 128; if (km < Keff) Keff = km; }
    const int nk = Keff >> 5;

    auto stage = [&](int buf, int k0) {
#pragma unroll
        for (int it = 0; it < 2; ++it) {
            int slot = it * 256 + tid;
            int rr = slot >> 2;
            int cc = (slot & 3) * 8;
            gload_lds16(A + (long long)(m0 + rr) * lda + k0 + cc,
                        &As[buf][(it * 256 + wid * 64) * 8]);
        }
#pragma unroll
        for (int it = 0; it < BN / 64; ++it) {
            int slot = it * 256 + tid;
            int rr = slot >> 2;
            int cc = (slot & 3) * 8;
            gload_lds16(B + (long long)(n0 + rr) * ldb + k0 + cc,
                        &Bs[buf][(it * 256 + wid * 64) * 8]);
        }
    };

    f32x4 acc[MI][4] = {};
    stage(0, 0);
    __syncthreads();
    for (int t = 0; t < nk; ++t) {
        int buf = t & 1;
        if (t + 1 < nk) stage(buf ^ 1, (t + 1) * 32);
        bf16x8 af[MI], bfr[4];
#pragma unroll
        for (int i = 0; i < MI; ++i)
            af[i] = *(const bf16x8*)&As[buf][(wr * WRS + i * 16 + (lane & 15)) * 32 + (lane >> 4) * 8];
#pragma unroll
        for (int j = 0; j < 4; ++j)
            bfr[j] = *(const bf16x8*)&Bs[buf][(wc * 64 + j * 16 + (lane & 15)) * 32 + (lane >> 4) * 8];
#pragma unroll
        for (int i = 0; i < MI; ++i)
#pragma unroll
            for (int j = 0; j < 4; ++j)
                acc[i][j] = __builtin_amdgcn_mfma_f32_16x16x32_bf16(af[i], bfr[j], acc[i][j], 0, 0, 0);
        __syncthreads();
    }
    const int orow = (lane >> 4) * 4;
    const int ocol = lane & 15;
    const long long zoff = (long long)blockIdx.z * sC;
#pragma unroll
    for (int i = 0; i < MI; ++i) {
#pragma unroll
        for (int j = 0; j < 4; ++j) {
            int colg = n0 + wc * 64 + j * 16 + ocol;
#pragma unroll
            for (int rj = 0; rj < 4; ++rj) {
                long long rowg = m0 + wr * WRS + i * 16 + orow + rj;
                long long idx = zoff + rowg * ldc + colg;
                float val = acc[i][j][rj];
                if (EPI == 0) ((unsigned short*)Cv)[idx] = f2bf(val);
                else if (EPI == 1) ((float*)Cv)[idx] = val;
                else if (EPI == 2) ((unsigned short*)Cv)[idx] = f2bf(gelu_fast(val + bias[colg]));
                else if (EPI == 3) ((float*)Cv)[idx] += val;
                else if (EPI == 4) ((float*)Cv)[idx] += val + bias[colg];
            }
        }
    }
}

// ============ scores = (q @ k^T) * gamma^(n-m) * KSCALE, bf16 out, per-batch ============
// q,k are strided slices (lda) of the fused qkvg buffer.
__global__ __launch_bounds__(256) void mgemm_decay(
    const short* __restrict__ Q, const short* __restrict__ Kp,
    unsigned short* __restrict__ S, int lda, long long sA) {
    const int q0 = blockIdx.y * 128;  // query rows
    const int c0 = blockIdx.x * 128;  // key cols
    unsigned short* Sb = S + (long long)blockIdx.z * SEQ * SEQ;
    if (blockIdx.x > blockIdx.y) {  // fully above diagonal -> zeros
        int4 z = {0, 0, 0, 0};
#pragma unroll
        for (int it = 0; it < 8; ++it) {
            int slot = it * 256 + threadIdx.x;
            int rr = slot >> 4;
            int cc = (slot & 15) * 8;
            *(int4*)&Sb[(long long)(q0 + rr) * SEQ + c0 + cc] = z;
        }
        return;
    }
    __shared__ short As[2][128 * 32];
    __shared__ short Bs[2][128 * 32];
    const int tid = threadIdx.x;
    const int lane = tid & 63;
    const int wid = tid >> 6;
    const int wr = wid >> 1, wc = wid & 1;
    const short* Ab = Q + (long long)blockIdx.z * sA;
    const short* Bb = Kp + (long long)blockIdx.z * sA;

    auto stage = [&](int buf, int k0) {
#pragma unroll
        for (int it = 0; it < 2; ++it) {
            int slot = it * 256 + tid;
            int rr = slot >> 2;
            int cc = (slot & 3) * 8;
            gload_lds16(Ab + (long long)(q0 + rr) * lda + k0 + cc,
                        &As[buf][(it * 256 + wid * 64) * 8]);
            gload_lds16(Bb + (long long)(c0 + rr) * lda + k0 + cc,
                        &Bs[buf][(it * 256 + wid * 64) * 8]);
        }
    };

    f32x4 acc[4][4] = {};
    stage(0, 0);
    __syncthreads();
    const int nk = D_MODEL / 32;
    for (int t = 0; t < nk; ++t) {
        int buf = t & 1;
        if (t + 1 < nk) stage(buf ^ 1, (t + 1) * 32);
        bf16x8 af[4], bfr[4];
#pragma unroll
        for (int i = 0; i < 4; ++i)
            af[i] = *(const bf16x8*)&As[buf][(wr * 64 + i * 16 + (lane & 15)) * 32 + (lane >> 4) * 8];
#pragma unroll
        for (int j = 0; j < 4; ++j)
            bfr[j] = *(const bf16x8*)&Bs[buf][(wc * 64 + j * 16 + (lane & 15)) * 32 + (lane >> 4) * 8];
#pragma unroll
        for (int i = 0; i < 4; ++i)
#pragma unroll
            for (int j = 0; j < 4; ++j)
                acc[i][j] = __builtin_amdgcn_mfma_f32_16x16x32_bf16(af[i], bfr[j], acc[i][j], 0, 0, 0);
        __syncthreads();
    }
    const int orow = (lane >> 4) * 4;
    const int ocol = lane & 15;
#pragma unroll
    for (int i = 0; i < 4; ++i) {
#pragma unroll
        for (int j = 0; j < 4; ++j) {
            int m = c0 + wc * 64 + j * 16 + ocol;
#pragma unroll
            for (int rj = 0; rj < 4; ++rj) {
                int n = q0 + wr * 64 + i * 16 + orow + rj;
                float w = (n >= m) ? exp2f((float)(n - m) * LOG2_GAMMA) * KSCALE : 0.f;
                Sb[(long long)n * SEQ + m] = f2bf(acc[i][j][rj] * w);
            }
        }
    }
}

// ============ weight convert+transpose: fp32 [K][N] -> bf16 [N][K] ============
__global__ __launch_bounds__(256) void wconv_t(const float* __restrict__ in,
                                               unsigned short* __restrict__ out,
                                               int K, int N) {
    __shared__ unsigned short t[64][65];
    int n0 = blockIdx.x * 64, k0 = blockIdx.y * 64;
    int tx = threadIdx.x & 63, ty = threadIdx.x >> 6;
#pragma unroll
    for (int i = 0; i < 16; ++i)
        t[ty + i * 4][tx] = f2bf(in[(long long)(k0 + ty + i * 4) * N + n0 + tx]);
    __syncthreads();
#pragma unroll
    for (int i = 0; i < 16; ++i)
        out[(long long)(n0 + ty + i * 4) * K + k0 + tx] = t[tx][ty + i * 4];
}

// ============ per-batch transpose: bf16 [SEQ][*istride slice] -> [D][SEQ] ============
__global__ __launch_bounds__(256) void vtrans(const unsigned short* __restrict__ in,
                                              unsigned short* __restrict__ out, int istride) {
    __shared__ unsigned short t[64][65];
    const unsigned short* pin = in + (long long)blockIdx.z * SEQ * istride;
    unsigned short* pout = out + (long long)blockIdx.z * D_MODEL * SEQ;
    int c0 = blockIdx.x * 64, r0 = blockIdx.y * 64;
    int tx = threadIdx.x & 63, ty = threadIdx.x >> 6;
#pragma unroll
    for (int i = 0; i < 16; ++i)
        t[ty + i * 4][tx] = pin[(long long)(r0 + ty + i * 4) * istride + c0 + tx];
    __syncthreads();
#pragma unroll
    for (int i = 0; i < 16; ++i)
        pout[(long long)(c0 + ty + i * 4) * SEQ + r0 + tx] = t[tx][ty + i * 4];
}

// ============ LayerNorm -> bf16, 4 rows/block (1 wave each) ============
__global__ __launch_bounds__(256) void ln_bf16(const float* __restrict__ in,
                                               const float* __restrict__ g,
                                               const float* __restrict__ b,
                                               unsigned short* __restrict__ out) {
    int row = blockIdx.x * 4 + (threadIdx.x >> 6);
    int t = threadIdx.x & 63;
    const float4* r4 = (const float4*)(in + (long long)row * D_MODEL);
    float4 v0 = r4[t], v1 = r4[t + 64];
    float s = v0.x + v0.y + v0.z + v0.w + v1.x + v1.y + v1.z + v1.w;
    float s2 = v0.x * v0.x + v0.y * v0.y + v0.z * v0.z + v0.w * v0.w +
               v1.x * v1.x + v1.y * v1.y + v1.z * v1.z + v1.w * v1.w;
#pragma unroll
    for (int off = 32; off > 0; off >>= 1) {
        s += __shfl_down(s, off);
        s2 += __shfl_down(s2, off);
    }
    s = __shfl(s, 0); s2 = __shfl(s2, 0);
    float mu = s * (1.f / D_MODEL);
    float var = s2 * (1.f / D_MODEL) - mu * mu;
    float rs = rsqrtf(var + 1e-6f);
    const float4* g4 = (const float4*)g;
    const float4* b4 = (const float4*)b;
    float4 ga = g4[t], gb = g4[t + 64], ba = b4[t], bb = b4[t + 64];
    ushort4 o0, o1;
    o0.x = f2bf((v0.x - mu) * rs * ga.x + ba.x);
    o0.y = f2bf((v0.y - mu) * rs * ga.y + ba.y);
    o0.z = f2bf((v0.z - mu) * rs * ga.z + ba.z);
    o0.w = f2bf((v0.w - mu) * rs * ga.w + ba.w);
    o1.x = f2bf((v1.x - mu) * rs * gb.x + bb.x);
    o1.y = f2bf((v1.y - mu) * rs * gb.y + bb.y);
    o1.z = f2bf((v1.z - mu) * rs * gb.z + bb.z);
    o1.w = f2bf((v1.w - mu) * rs * gb.w + bb.w);
    ushort4* o4 = (ushort4*)(out + (long long)row * D_MODEL);
    o4[t] = o0; o4[t + 64] = o1;
}

// ============ gated = silu(g) * groupnorm(ret) -> bf16 (g strided) ============
__global__ __launch_bounds__(256) void gate_bf16(const float* __restrict__ ret,
                                                 const unsigned short* __restrict__ g,
                                                 int gstride,
                                                 unsigned short* __restrict__ out) {
    int row = blockIdx.x * 4 + (threadIdx.x >> 6);
    int t = threadIdx.x & 63;
    const float4* r4 = (const float4*)(ret + (long long)row * D_MODEL);
    float4 v0 = r4[t], v1 = r4[t + 64];
    float s = v0.x + v0.y + v0.z + v0.w + v1.x + v1.y + v1.z + v1.w;
    float s2 = v0.x * v0.x + v0.y * v0.y + v0.z * v0.z + v0.w * v0.w +
               v1.x * v1.x + v1.y * v1.y + v1.z * v1.z + v1.w * v1.w;
#pragma unroll
    for (int off = 32; off > 0; off >>= 1) {
        s += __shfl_down(s, off);
        s2 += __shfl_down(s2, off);
    }
    s = __shfl(s, 0); s2 = __shfl(s2, 0);
    float mu = s * (1.f / D_MODEL);
    float var = s2 * (1.f / D_MODEL) - mu * mu;
    float rs = rsqrtf(var + 1e-6f);
    const ushort4* g4 = (const ushort4*)(g + (long long)row * gstride);
    ushort4 ga = g4[t], gb = g4[t + 64];
    float gx[8] = {bf2f(ga.x), bf2f(ga.y), bf2f(ga.z), bf2f(ga.w),
                   bf2f(gb.x), bf2f(gb.y), bf2f(gb.z), bf2f(gb.w)};
    float rv[8] = {v0.x, v0.y, v0.z, v0.w, v1.x, v1.y, v1.z, v1.w};
    ushort4 o0, o1;
    unsigned short oo[8];
#pragma unroll
    for (int i = 0; i < 8; ++i) {
        float x = gx[i];
        oo[i] = f2bf(x * sigm(x) * (rv[i] - mu) * rs);
    }
    o0.x = oo[0]; o0.y = oo[1]; o0.z = oo[2]; o0.w = oo[3];
    o1.x = oo[4]; o1.y = oo[5]; o1.z = oo[6]; o1.w = oo[7];
    ushort4* o4 = (ushort4*)(out + (long long)row * D_MODEL);
    o4[t] = o0; o4[t + 64] = o1;
}

// ============ pooling + readout ============
__global__ __launch_bounds__(256) void pool_kernel(const float* __restrict__ h,
                                                   float* __restrict__ pooled) {
    int idx = blockIdx.x * 256 + threadIdx.x;
    int b = idx >> 9;
    int c = idx & 511;
    const float* p = h + (long long)b * SEQ * D_MODEL + c;
    float s = 0.f;
    for (int t = 0; t < SEQ; t++) s += p[t * D_MODEL];
    pooled[idx] = s;
}

__global__ __launch_bounds__(64) void readout_kernel(const float* __restrict__ pooled,
                                                     const float* __restrict__ Wro,
                                                     const float* __restrict__ bro,
                                                     float* __restrict__ out) {
    int bo = blockIdx.x;
    int b = bo >> 1, o = bo & 1;
    int t = threadIdx.x;
    float s = 0.f;
    for (int i = t; i < D_MODEL; i += 64) s += pooled[b * D_MODEL + i] * Wro[i * 2 + o];
#pragma unroll
    for (int off = 32; off > 0; off >>= 1) s += __shfl_down(s, off);
    if (t == 0) out[b * 2 + o] = s + bro[o];
}

extern "C" void kernel_launch(void* const* d_in, const int* in_sizes, int n_in,
                              void* d_out, int out_size, void* d_ws, size_t ws_size,
                              hipStream_t stream) {
    const float* x = (const float*)d_in[0];
    const float* Wq = (const float*)d_in[1];
    const float* Wk = (const float*)d_in[2];
    const float* Wv = (const float*)d_in[3];
    const float* Wg = (const float*)d_in[4];
    const float* Wo = (const float*)d_in[5];
    const float* ln1_g = (const float*)d_in[6];
    const float* ln1_b = (const float*)d_in[7];
    const float* ln2_g = (const float*)d_in[8];
    const float* ln2_b = (const float*)d_in[9];
    const float* W1 = (const float*)d_in[10];
    const float* b1 = (const float*)d_in[11];
    const float* W2 = (const float*)d_in[12];
    const float* b2 = (const float*)d_in[13];
    const float* Wro = (const float*)d_in[14];
    const float* bro = (const float*)d_in[15];
    float* out = (float*)d_out;

    const long long NE = (long long)NROWS * D_MODEL;  // 8,388,608
    const long long dd = (long long)D_MODEL * D_MODEL;

    float* h = (float*)d_ws;                        // NE f32
    float* ret = h + NE;                            // NE f32
    float* pooled = ret + NE;                       // 8192 f32
    unsigned short* y = (unsigned short*)(pooled + 8192);  // NE bf16
    unsigned short* qkvg = y + NE;                  // 4*NE bf16 [16384][2048]
    unsigned short* vT = qkvg + 4 * NE;             // NE bf16 [16][512][1024]
    unsigned short* gated = vT;                     // alias (vT dead after ret GEMM)
    unsigned short* sg = vT + NE;                   // 2*NE bf16: scores / ffn-hidden
    unsigned short* wts = sg + 2 * NE;
    unsigned short* WqkvgT = wts;                   // [L][2048][512]
    unsigned short* WoT = WqkvgT + 2 * 4 * dd;      // [L][512][512]
    unsigned short* W1T = WoT + 2 * dd;             // [L][1024][512]
    unsigned short* W2T = W1T + 2 * (long long)D_MODEL * HID;  // [L][512][1024]

    hipMemcpyAsync(h, x, NE * sizeof(float), hipMemcpyDeviceToDevice, stream);

    dim3 blk(256);
    for (int l = 0; l < 2; l++) {
        long long qb = (long long)l * 4 * dd;
        wconv_t<<<dim3(8, 8), blk, 0, stream>>>(Wq + l * dd, WqkvgT + qb, 512, 512);
        wconv_t<<<dim3(8, 8), blk, 0, stream>>>(Wk + l * dd, WqkvgT + qb + dd, 512, 512);
        wconv_t<<<dim3(8, 8), blk, 0, stream>>>(Wv + l * dd, WqkvgT + qb + 2 * dd, 512, 512);
        wconv_t<<<dim3(8, 8), blk, 0, stream>>>(Wg + l * dd, WqkvgT + qb + 3 * dd, 512, 512);
        wconv_t<<<dim3(8, 8), blk, 0, stream>>>(Wo + l * dd, WoT + l * dd, 512, 512);
        wconv_t<<<dim3(16, 8), blk, 0, stream>>>(W1 + (long long)l * D_MODEL * HID,
                                                 W1T + (long long)l * D_MODEL * HID, 512, 1024);
        wconv_t<<<dim3(8, 16), blk, 0, stream>>>(W2 + (long long)l * HID * D_MODEL,
                                                 W2T + (long long)l * HID * D_MODEL, 1024, 512);
    }

    for (int l = 0; l < 2; l++) {
        ln_bf16<<<NROWS / 4, blk, 0, stream>>>(h, ln1_g + l * D_MODEL, ln1_b + l * D_MODEL, y);
        // fused qkvg = y @ [Wq|Wk|Wv|Wg]  (N=2048)
        mgemm<0, 128><<<dim3(16, 128), blk, 0, stream>>>(
            (const short*)y, (const short*)(WqkvgT + (long long)l * 4 * dd), nullptr, qkvg,
            2048, 512, 512, 512, 2048, 0, 0, 0, 0);
        // vT[b] = v[b]^T  (v = qkvg slice +1024, stride 2048)
        vtrans<<<dim3(8, 16, BATCH), blk, 0, stream>>>(qkvg + 1024, vT, 2048);
        // scores = (q k^T) * decay
        mgemm_decay<<<dim3(8, 8, BATCH), blk, 0, stream>>>(
            (const short*)qkvg, (const short*)(qkvg + 512), sg, 2048, (long long)SEQ * 2048);
        // ret = scores @ v   (BN=64, K truncated at diagonal)
        mgemm<1, 64><<<dim3(8, 8, BATCH), blk, 0, stream>>>(
            (const short*)sg, (const short*)vT, nullptr, ret,
            512, SEQ, SEQ, SEQ, 512,
            (long long)SEQ * SEQ, (long long)D_MODEL * SEQ, (long long)SEQ * D_MODEL, 1);
        // gated = silu(g) * groupnorm(ret)   (g = qkvg slice +1536)
        gate_bf16<<<NROWS / 4, blk, 0, stream>>>(ret, qkvg + 1536, 2048, gated);
        // h += gated @ Wo
        mgemm<3, 64><<<dim3(8, 128), blk, 0, stream>>>(
            (const short*)gated, (const short*)(WoT + l * dd), nullptr, h,
            512, 512, 512, 512, 512, 0, 0, 0, 0);
        // FFN
        ln_bf16<<<NROWS / 4, blk, 0, stream>>>(h, ln2_g + l * D_MODEL, ln2_b + l * D_MODEL, y);
        mgemm<2, 128><<<dim3(8, 128), blk, 0, stream>>>(
            (const short*)y, (const short*)(W1T + (long long)l * D_MODEL * HID),
            b1 + l * HID, sg, HID, 512, 512, 512, HID, 0, 0, 0, 0);
        mgemm<4, 64><<<dim3(8, 128), blk, 0, stream>>>(
            (const short*)sg, (const short*)(W2T + (long long)l * HID * D_MODEL),
            b2 + l * D_MODEL, h, 512, HID, HID, HID, 512, 0, 0, 0, 0);
    }

    pool_kernel<<<32, blk, 0, stream>>>(h, pooled);
    readout_kernel<<<32, 64, 0, stream>>>(pooled, Wro, bro, out);
}

// Round 5
// 603.245 us; speedup vs baseline: 5.4382x; 1.1018x over previous
//
#include <hip/hip_runtime.h>
#include <hip/hip_bf16.h>

// RetNet 2-layer forward. All-bf16 dataflow, MFMA GEMMs w/ LDS-staged epilogues.
// B=16, S=1024, d=512, L=2, OUT=2, gamma = 1 - 2^-5.

#define D_MODEL 512
#define SEQ 1024
#define BATCH 16
#define NROWS (BATCH * SEQ)          // 16384
#define HID 1024
#define LOG2_GAMMA (-0.04580368961f)  // log2(0.96875)
#define KSCALE (0.044194173824f)      // 512^-0.5

typedef __attribute__((ext_vector_type(8))) short bf16x8;
typedef __attribute__((ext_vector_type(4))) float f32x4;

__device__ inline unsigned short f2bf(float x) {
    union { float f; unsigned u; } uu; uu.f = x;
    unsigned r = uu.u + 0x7fff + ((uu.u >> 16) & 1);
    return (unsigned short)(r >> 16);
}
__device__ inline float bf2f(unsigned short x) {
    union { unsigned u; float f; } uu; uu.u = ((unsigned)x) << 16; return uu.f;
}

__device__ inline void gload_lds16(const void* g, void* l) {
    __builtin_amdgcn_global_load_lds(
        (const __attribute__((address_space(1))) void*)g,
        (__attribute__((address_space(3))) void*)l, 16, 0, 0);
}

__device__ inline float sigm(float z) {
    return 1.f / (1.f + exp2f(z * -1.442695040888963f));
}
__device__ inline float gelu_fast(float x) {
    float y = 1.5957691216057308f * (x + 0.044715f * x * x * x);
    return x * sigm(y);
}

// ============ MFMA GEMM, double-buffered, LDS-staged bf16 epilogue ============
// C[M,N] = A[M,K(lda)] @ B[N,K(ldb)]^T ; BM=128, BN in {64,128}, BK=32.
// LDS layout: A tiles at [buf*4096], B tiles at [8192 + buf*BN*32].
// EPI: 0 plain store, 1 store acc+bias, 2 store gelu(acc+bias)
// tri!=0: K truncated at m0+128 (scores@v with causal-zero scores).
template <int EPI, int BN>
__global__ __launch_bounds__(256) void mgemm(
    const short* __restrict__ A, const short* __restrict__ B,
    const float* __restrict__ bias, unsigned short* __restrict__ C,
    int K, int lda, int ldb, int ldc,
    long long sA, long long sB, long long sC, int tri) {
    constexpr int MI = (BN == 128) ? 4 : 2;
    constexpr int WRS = (BN == 128) ? 64 : 32;
    __shared__ short smem[(128 + BN) * 64];
    const int tid = threadIdx.x;
    const int lane = tid & 63;
    const int wid = tid >> 6;
    const int wr = (BN == 128) ? (wid >> 1) : wid;
    const int wc = (BN == 128) ? (wid & 1) : 0;
    const int m0 = blockIdx.y * 128, n0 = blockIdx.x * BN;
    A += (long long)blockIdx.z * sA;
    B += (long long)blockIdx.z * sB;

    int Keff = K;
    if (tri) { int km = m0 + 128; if (km < Keff) Keff = km; }
    const int nk = Keff >> 5;

    auto stage = [&](int buf, int k0) {
#pragma unroll
        for (int it = 0; it < 2; ++it) {
            int slot = it * 256 + tid;
            int rr = slot >> 2;
            int cc = (slot & 3) * 8;
            gload_lds16(A + (long long)(m0 + rr) * lda + k0 + cc,
                        &smem[buf * 4096 + (it * 256 + wid * 64) * 8]);
        }
#pragma unroll
        for (int it = 0; it < BN / 64; ++it) {
            int slot = it * 256 + tid;
            int rr = slot >> 2;
            int cc = (slot & 3) * 8;
            gload_lds16(B + (long long)(n0 + rr) * ldb + k0 + cc,
                        &smem[8192 + buf * (BN * 32) + (it * 256 + wid * 64) * 8]);
        }
    };

    f32x4 acc[MI][4] = {};
    stage(0, 0);
    __syncthreads();
    for (int t = 0; t < nk; ++t) {
        int buf = t & 1;
        if (t + 1 < nk) stage(buf ^ 1, (t + 1) * 32);
        bf16x8 af[MI], bfr[4];
#pragma unroll
        for (int i = 0; i < MI; ++i)
            af[i] = *(const bf16x8*)&smem[buf * 4096 +
                (wr * WRS + i * 16 + (lane & 15)) * 32 + (lane >> 4) * 8];
#pragma unroll
        for (int j = 0; j < 4; ++j)
            bfr[j] = *(const bf16x8*)&smem[8192 + buf * (BN * 32) +
                (wc * 64 + j * 16 + (lane & 15)) * 32 + (lane >> 4) * 8];
#pragma unroll
        for (int i = 0; i < MI; ++i)
#pragma unroll
            for (int j = 0; j < 4; ++j)
                acc[i][j] = __builtin_amdgcn_mfma_f32_16x16x32_bf16(af[i], bfr[j], acc[i][j], 0, 0, 0);
        __syncthreads();
    }
    // ---- epilogue: frags -> LDS bf16 -> vectorized stores ----
    const int orow = (lane >> 4) * 4;
    const int ocol = lane & 15;
    float bv[4];
    if (EPI >= 1) {
#pragma unroll
        for (int j = 0; j < 4; ++j) bv[j] = bias[n0 + wc * 64 + j * 16 + ocol];
    }
#pragma unroll
    for (int i = 0; i < MI; ++i)
#pragma unroll
        for (int j = 0; j < 4; ++j)
#pragma unroll
            for (int rj = 0; rj < 4; ++rj) {
                int lrow = wr * WRS + i * 16 + orow + rj;
                int lcol = wc * 64 + j * 16 + ocol;
                float val = acc[i][j][rj];
                if (EPI == 1) val += bv[j];
                if (EPI == 2) val = gelu_fast(val + bv[j]);
                smem[lrow * BN + lcol] = (short)f2bf(val);
            }
    __syncthreads();
    const long long zoff = (long long)blockIdx.z * sC;
    constexpr int CH = 128 * BN / 8;
#pragma unroll
    for (int p = 0; p < CH / 256; ++p) {
        int s = p * 256 + tid;
        int row = s / (BN / 8);
        int cc = (s % (BN / 8)) * 8;
        *(int4*)&C[zoff + (long long)(m0 + row) * ldc + n0 + cc] = *(const int4*)&smem[row * BN + cc];
    }
}

// ============ scores = (q @ k^T) * gamma^(n-m) * KSCALE, bf16, per-batch ============
// Above-diagonal tiles are never read downstream -> skip entirely.
__global__ __launch_bounds__(256) void mgemm_decay(
    const short* __restrict__ Q, const short* __restrict__ Kp,
    unsigned short* __restrict__ S, int lda, long long sA) {
    if (blockIdx.x > blockIdx.y) return;
    const int q0 = blockIdx.y * 128;
    const int c0 = blockIdx.x * 128;
    unsigned short* Sb = S + (long long)blockIdx.z * SEQ * SEQ;
    __shared__ short smem[16384];
    const int tid = threadIdx.x;
    const int lane = tid & 63;
    const int wid = tid >> 6;
    const int wr = wid >> 1, wc = wid & 1;
    const short* Ab = Q + (long long)blockIdx.z * sA;
    const short* Bb = Kp + (long long)blockIdx.z * sA;

    auto stage = [&](int buf, int k0) {
#pragma unroll
        for (int it = 0; it < 2; ++it) {
            int slot = it * 256 + tid;
            int rr = slot >> 2;
            int cc = (slot & 3) * 8;
            gload_lds16(Ab + (long long)(q0 + rr) * lda + k0 + cc,
                        &smem[buf * 4096 + (it * 256 + wid * 64) * 8]);
            gload_lds16(Bb + (long long)(c0 + rr) * lda + k0 + cc,
                        &smem[8192 + buf * 4096 + (it * 256 + wid * 64) * 8]);
        }
    };

    f32x4 acc[4][4] = {};
    stage(0, 0);
    __syncthreads();
    const int nk = D_MODEL / 32;
    for (int t = 0; t < nk; ++t) {
        int buf = t & 1;
        if (t + 1 < nk) stage(buf ^ 1, (t + 1) * 32);
        bf16x8 af[4], bfr[4];
#pragma unroll
        for (int i = 0; i < 4; ++i)
            af[i] = *(const bf16x8*)&smem[buf * 4096 +
                (wr * 64 + i * 16 + (lane & 15)) * 32 + (lane >> 4) * 8];
#pragma unroll
        for (int j = 0; j < 4; ++j)
            bfr[j] = *(const bf16x8*)&smem[8192 + buf * 4096 +
                (wc * 64 + j * 16 + (lane & 15)) * 32 + (lane >> 4) * 8];
#pragma unroll
        for (int i = 0; i < 4; ++i)
#pragma unroll
            for (int j = 0; j < 4; ++j)
                acc[i][j] = __builtin_amdgcn_mfma_f32_16x16x32_bf16(af[i], bfr[j], acc[i][j], 0, 0, 0);
        __syncthreads();
    }
    const int orow = (lane >> 4) * 4;
    const int ocol = lane & 15;
#pragma unroll
    for (int i = 0; i < 4; ++i)
#pragma unroll
        for (int j = 0; j < 4; ++j)
#pragma unroll
            for (int rj = 0; rj < 4; ++rj) {
                int lrow = wr * 64 + i * 16 + orow + rj;
                int lcol = wc * 64 + j * 16 + ocol;
                int n = q0 + lrow, m = c0 + lcol;
                float w = (n >= m) ? exp2f((float)(n - m) * LOG2_GAMMA) * KSCALE : 0.f;
                smem[lrow * 128 + lcol] = (short)f2bf(acc[i][j][rj] * w);
            }
    __syncthreads();
#pragma unroll
    for (int p = 0; p < 8; ++p) {
        int s = p * 256 + tid;
        int row = s >> 4;
        int cc = (s & 15) * 8;
        *(int4*)&Sb[(long long)(q0 + row) * SEQ + c0 + cc] = *(const int4*)&smem[row * 128 + cc];
    }
}

// ============ fused weight convert+transpose (all 14 matrices, one launch) ============
__global__ __launch_bounds__(256) void wconv_all(
    const float* __restrict__ Wq, const float* __restrict__ Wk,
    const float* __restrict__ Wv, const float* __restrict__ Wg,
    const float* __restrict__ Wo, const float* __restrict__ W1,
    const float* __restrict__ W2,
    unsigned short* __restrict__ WqkvgT, unsigned short* __restrict__ WoT,
    unsigned short* __restrict__ W1T, unsigned short* __restrict__ W2T) {
    const long long dd = 512LL * 512;
    int z = blockIdx.z;
    int l = z / 7, w = z % 7;
    const float* src; unsigned short* dst; int K, N;
    switch (w) {
        case 0: src = Wq + l * dd; dst = WqkvgT + (long long)l * 4 * dd; K = 512; N = 512; break;
        case 1: src = Wk + l * dd; dst = WqkvgT + (long long)l * 4 * dd + dd; K = 512; N = 512; break;
        case 2: src = Wv + l * dd; dst = WqkvgT + (long long)l * 4 * dd + 2 * dd; K = 512; N = 512; break;
        case 3: src = Wg + l * dd; dst = WqkvgT + (long long)l * 4 * dd + 3 * dd; K = 512; N = 512; break;
        case 4: src = Wo + l * dd; dst = WoT + l * dd; K = 512; N = 512; break;
        case 5: src = W1 + (long long)l * 512 * 1024; dst = W1T + (long long)l * 512 * 1024; K = 512; N = 1024; break;
        default: src = W2 + (long long)l * 1024 * 512; dst = W2T + (long long)l * 1024 * 512; K = 1024; N = 512; break;
    }
    if ((int)blockIdx.x >= N / 64 || (int)blockIdx.y >= K / 64) return;
    __shared__ unsigned short t[64][65];
    int n0 = blockIdx.x * 64, k0 = blockIdx.y * 64;
    int tx = threadIdx.x & 63, ty = threadIdx.x >> 6;
#pragma unroll
    for (int i = 0; i < 16; ++i)
        t[ty + i * 4][tx] = f2bf(src[(long long)(k0 + ty + i * 4) * N + n0 + tx]);
    __syncthreads();
#pragma unroll
    for (int i = 0; i < 16; ++i)
        dst[(long long)(n0 + ty + i * 4) * K + k0 + tx] = t[tx][ty + i * 4];
}

// ============ per-batch transpose: bf16 [SEQ][*stride slice] -> [D][SEQ] ============
__global__ __launch_bounds__(256) void vtrans(const unsigned short* __restrict__ in,
                                              unsigned short* __restrict__ out, int istride) {
    __shared__ unsigned short t[64][65];
    const unsigned short* pin = in + (long long)blockIdx.z * SEQ * istride;
    unsigned short* pout = out + (long long)blockIdx.z * D_MODEL * SEQ;
    int c0 = blockIdx.x * 64, r0 = blockIdx.y * 64;
    int tx = threadIdx.x & 63, ty = threadIdx.x >> 6;
#pragma unroll
    for (int i = 0; i < 16; ++i)
        t[ty + i * 4][tx] = pin[(long long)(r0 + ty + i * 4) * istride + c0 + tx];
    __syncthreads();
#pragma unroll
    for (int i = 0; i < 16; ++i)
        pout[(long long)(c0 + ty + i * 4) * SEQ + r0 + tx] = t[tx][ty + i * 4];
}

// ============ x (f32) -> h (bf16) ============
__global__ __launch_bounds__(256) void conv_x(const float* __restrict__ x,
                                              unsigned short* __restrict__ h) {
    int i = blockIdx.x * 256 + threadIdx.x;
    float4 v = ((const float4*)x)[i];
    ushort4 o;
    o.x = f2bf(v.x); o.y = f2bf(v.y); o.z = f2bf(v.z); o.w = f2bf(v.w);
    ((ushort4*)h)[i] = o;
}

// ============ fused residual-add + LayerNorm, all bf16 ============
// MODE 0: y = LN(hin)            (no update)
// MODE 1: hn = hin+delta; hout=hn; y = LN(hn)
template <int MODE>
__global__ __launch_bounds__(256) void ln_fuse(
    const unsigned short* __restrict__ hin,
    const unsigned short* __restrict__ delta,
    const float* __restrict__ g, const float* __restrict__ b,
    unsigned short* __restrict__ hout,
    unsigned short* __restrict__ y) {
    int row = blockIdx.x * 4 + (threadIdx.x >> 6);
    int t = threadIdx.x & 63;
    int4 hv = ((const int4*)(hin + (long long)row * D_MODEL))[t];
    const unsigned short* hu = (const unsigned short*)&hv;
    float f[8];
#pragma unroll
    for (int k = 0; k < 8; ++k) f[k] = bf2f(hu[k]);
    if (MODE == 1) {
        int4 dv = ((const int4*)(delta + (long long)row * D_MODEL))[t];
        const unsigned short* du = (const unsigned short*)&dv;
#pragma unroll
        for (int k = 0; k < 8; ++k) f[k] += bf2f(du[k]);
    }
    float s = 0.f, s2 = 0.f;
#pragma unroll
    for (int k = 0; k < 8; ++k) { s += f[k]; s2 += f[k] * f[k]; }
#pragma unroll
    for (int off = 32; off > 0; off >>= 1) {
        s += __shfl_down(s, off);
        s2 += __shfl_down(s2, off);
    }
    s = __shfl(s, 0); s2 = __shfl(s2, 0);
    float mu = s * (1.f / D_MODEL);
    float var = s2 * (1.f / D_MODEL) - mu * mu;
    float rs = rsqrtf(var + 1e-6f);
    if (MODE == 1) {
        ushort4 ho[2];
        unsigned short* hp = (unsigned short*)ho;
#pragma unroll
        for (int k = 0; k < 8; ++k) hp[k] = f2bf(f[k]);
        ((int4*)(hout + (long long)row * D_MODEL))[t] = *(int4*)ho;
    }
    const float4* g4 = (const float4*)g;
    const float4* b4 = (const float4*)b;
    float4 ga = g4[2 * t], gb2 = g4[2 * t + 1];
    float4 ba = b4[2 * t], bb2 = b4[2 * t + 1];
    float gg[8] = {ga.x, ga.y, ga.z, ga.w, gb2.x, gb2.y, gb2.z, gb2.w};
    float bb[8] = {ba.x, ba.y, ba.z, ba.w, bb2.x, bb2.y, bb2.z, bb2.w};
    ushort4 yo[2];
    unsigned short* yp = (unsigned short*)yo;
#pragma unroll
    for (int k = 0; k < 8; ++k) yp[k] = f2bf((f[k] - mu) * rs * gg[k] + bb[k]);
    ((int4*)(y + (long long)row * D_MODEL))[t] = *(int4*)yo;
}

// ============ gated = silu(g) * groupnorm(ret), all bf16 (g strided) ============
__global__ __launch_bounds__(256) void gate_bf16(const unsigned short* __restrict__ ret,
                                                 const unsigned short* __restrict__ g,
                                                 int gstride,
                                                 unsigned short* __restrict__ out) {
    int row = blockIdx.x * 4 + (threadIdx.x >> 6);
    int t = threadIdx.x & 63;
    int4 rv4 = ((const int4*)(ret + (long long)row * D_MODEL))[t];
    const unsigned short* ru = (const unsigned short*)&rv4;
    float f[8];
#pragma unroll
    for (int k = 0; k < 8; ++k) f[k] = bf2f(ru[k]);
    float s = 0.f, s2 = 0.f;
#pragma unroll
    for (int k = 0; k < 8; ++k) { s += f[k]; s2 += f[k] * f[k]; }
#pragma unroll
    for (int off = 32; off > 0; off >>= 1) {
        s += __shfl_down(s, off);
        s2 += __shfl_down(s2, off);
    }
    s = __shfl(s, 0); s2 = __shfl(s2, 0);
    float mu = s * (1.f / D_MODEL);
    float var = s2 * (1.f / D_MODEL) - mu * mu;
    float rs = rsqrtf(var + 1e-6f);
    int4 gv4 = ((const int4*)(g + (long long)row * gstride))[t];
    const unsigned short* gu = (const unsigned short*)&gv4;
    ushort4 o[2];
    unsigned short* op = (unsigned short*)o;
#pragma unroll
    for (int k = 0; k < 8; ++k) {
        float x = bf2f(gu[k]);
        op[k] = f2bf(x * sigm(x) * (f[k] - mu) * rs);
    }
    ((int4*)(out + (long long)row * D_MODEL))[t] = *(int4*)o;
}

// ============ pooled = sum_rows (h + dlast) ============
__global__ __launch_bounds__(256) void pool2(const unsigned short* __restrict__ h,
                                             const unsigned short* __restrict__ d,
                                             float* __restrict__ pooled) {
    int idx = blockIdx.x * 256 + threadIdx.x;  // 0..8191
    int b = idx >> 9;
    int c = idx & 511;
    long long base = (long long)b * SEQ * D_MODEL + c;
    float s = 0.f;
    for (int t = 0; t < SEQ; t++) {
        long long o = base + (long long)t * D_MODEL;
        s += bf2f(h[o]) + bf2f(d[o]);
    }
    pooled[idx] = s;
}

__global__ __launch_bounds__(64) void readout_kernel(const float* __restrict__ pooled,
                                                     const float* __restrict__ Wro,
                                                     const float* __restrict__ bro,
                                                     float* __restrict__ out) {
    int bo = blockIdx.x;
    int b = bo >> 1, o = bo & 1;
    int t = threadIdx.x;
    float s = 0.f;
    for (int i = t; i < D_MODEL; i += 64) s += pooled[b * D_MODEL + i] * Wro[i * 2 + o];
#pragma unroll
    for (int off = 32; off > 0; off >>= 1) s += __shfl_down(s, off);
    if (t == 0) out[b * 2 + o] = s + bro[o];
}

extern "C" void kernel_launch(void* const* d_in, const int* in_sizes, int n_in,
                              void* d_out, int out_size, void* d_ws, size_t ws_size,
                              hipStream_t stream) {
    const float* x = (const float*)d_in[0];
    const float* Wq = (const float*)d_in[1];
    const float* Wk = (const float*)d_in[2];
    const float* Wv = (const float*)d_in[3];
    const float* Wg = (const float*)d_in[4];
    const float* Wo = (const float*)d_in[5];
    const float* ln1_g = (const float*)d_in[6];
    const float* ln1_b = (const float*)d_in[7];
    const float* ln2_g = (const float*)d_in[8];
    const float* ln2_b = (const float*)d_in[9];
    const float* W1 = (const float*)d_in[10];
    const float* b1 = (const float*)d_in[11];
    const float* W2 = (const float*)d_in[12];
    const float* b2 = (const float*)d_in[13];
    const float* Wro = (const float*)d_in[14];
    const float* bro = (const float*)d_in[15];
    float* out = (float*)d_out;

    const long long NE = (long long)NROWS * D_MODEL;  // 8,388,608
    const long long dd = (long long)D_MODEL * D_MODEL;

    unsigned short* h = (unsigned short*)d_ws;   // NE
    unsigned short* y = h + NE;                  // NE
    unsigned short* qkvg = y + NE;               // 4*NE  [16384][2048]
    unsigned short* vT = qkvg + 4 * NE;          // NE    [16][512][1024]
    unsigned short* gated = vT;                  // alias (vT dead after ret GEMM)
    unsigned short* ret = vT + NE;               // NE    (also ffn-delta buffer)
    unsigned short* sg = ret + NE;               // 2*NE  scores / attn-delta / ffn-hidden
    float* pooled = (float*)(sg + 2 * NE);       // 8192 f32
    unsigned short* wts = (unsigned short*)(pooled + 8192);
    unsigned short* WqkvgT = wts;                          // [L][2048][512]
    unsigned short* WoT = WqkvgT + 2 * 4 * dd;             // [L][512][512]
    unsigned short* W1T = WoT + 2 * dd;                    // [L][1024][512]
    unsigned short* W2T = W1T + 2 * (long long)D_MODEL * HID;  // [L][512][1024]

    dim3 blk(256);
    conv_x<<<NE / 1024, blk, 0, stream>>>(x, h);
    wconv_all<<<dim3(16, 16, 14), blk, 0, stream>>>(Wq, Wk, Wv, Wg, Wo, W1, W2,
                                                    WqkvgT, WoT, W1T, W2T);

    for (int l = 0; l < 2; l++) {
        if (l == 0)
            ln_fuse<0><<<NROWS / 4, blk, 0, stream>>>(h, nullptr, ln1_g, ln1_b, nullptr, y);
        else
            ln_fuse<1><<<NROWS / 4, blk, 0, stream>>>(h, ret, ln1_g + l * D_MODEL,
                                                      ln1_b + l * D_MODEL, h, y);
        // qkvg = y @ [Wq|Wk|Wv|Wg]
        mgemm<0, 128><<<dim3(16, 128), blk, 0, stream>>>(
            (const short*)y, (const short*)(WqkvgT + (long long)l * 4 * dd), nullptr, qkvg,
            512, 512, 512, 2048, 0, 0, 0, 0);
        vtrans<<<dim3(8, 16, BATCH), blk, 0, stream>>>(qkvg + 1024, vT, 2048);
        mgemm_decay<<<dim3(8, 8, BATCH), blk, 0, stream>>>(
            (const short*)qkvg, (const short*)(qkvg + 512), sg, 2048, (long long)SEQ * 2048);
        // ret = scores @ v  (K truncated at diagonal)
        mgemm<0, 64><<<dim3(8, 8, BATCH), blk, 0, stream>>>(
            (const short*)sg, (const short*)vT, nullptr, ret,
            SEQ, SEQ, SEQ, 512,
            (long long)SEQ * SEQ, (long long)D_MODEL * SEQ, (long long)SEQ * D_MODEL, 1);
        gate_bf16<<<NROWS / 4, blk, 0, stream>>>(ret, qkvg + 1536, 2048, gated);
        // attn delta = gated @ Wo  -> sg[0..NE)
        mgemm<0, 64><<<dim3(8, 128), blk, 0, stream>>>(
            (const short*)gated, (const short*)(WoT + l * dd), nullptr, sg,
            512, 512, 512, 512, 0, 0, 0, 0);
        // h += attn delta; y = LN2(h)
        ln_fuse<1><<<NROWS / 4, blk, 0, stream>>>(h, sg, ln2_g + l * D_MODEL,
                                                  ln2_b + l * D_MODEL, h, y);
        // hidden = gelu(y @ W1 + b1)
        mgemm<2, 128><<<dim3(8, 128), blk, 0, stream>>>(
            (const short*)y, (const short*)(W1T + (long long)l * D_MODEL * HID),
            b1 + l * HID, sg, 512, 512, 512, HID, 0, 0, 0, 0);
        // ffn delta = hidden @ W2 + b2 -> ret buffer
        mgemm<1, 64><<<dim3(8, 128), blk, 0, stream>>>(
            (const short*)sg, (const short*)(W2T + (long long)l * HID * D_MODEL),
            b2 + l * D_MODEL, ret, HID, HID, HID, 512, 0, 0, 0, 0);
    }

    pool2<<<32, blk, 0, stream>>>(h, ret, pooled);
    readout_kernel<<<32, 64, 0, stream>>>(pooled, Wro, bro, out);
}

// Round 6
// 555.799 us; speedup vs baseline: 5.9024x; 1.0854x over previous
//
#include <hip/hip_runtime.h>
#include <hip/hip_bf16.h>

// RetNet 2-layer forward. All-bf16 dataflow.
// Big GEMMs: 256x256 tile, 3-deep ring, counted vmcnt (T3/T4), swizzled LDS (T2),
// setprio (T5), XCD swizzle (T1). Others: proven 2-phase 128-tile MFMA.

#define D_MODEL 512
#define SEQ 1024
#define BATCH 16
#define NROWS (BATCH * SEQ)          // 16384
#define HID 1024
#define LOG2_GAMMA (-0.04580368961f)  // log2(0.96875)
#define KSCALE (0.044194173824f)      // 512^-0.5

typedef __attribute__((ext_vector_type(8))) short bf16x8;
typedef __attribute__((ext_vector_type(4))) float f32x4;

__device__ inline unsigned short f2bf(float x) {
    union { float f; unsigned u; } uu; uu.f = x;
    unsigned r = uu.u + 0x7fff + ((uu.u >> 16) & 1);
    return (unsigned short)(r >> 16);
}
__device__ inline float bf2f(unsigned short x) {
    union { unsigned u; float f; } uu; uu.u = ((unsigned)x) << 16; return uu.f;
}

__device__ inline void gload_lds16(const void* g, void* l) {
    __builtin_amdgcn_global_load_lds(
        (const __attribute__((address_space(1))) void*)g,
        (__attribute__((address_space(3))) void*)l, 16, 0, 0);
}

__device__ inline float sigm(float z) {
    return 1.f / (1.f + exp2f(z * -1.442695040888963f));
}
__device__ inline float gelu_fast(float x) {
    float y = 1.5957691216057308f * (x + 0.044715f * x * x * x);
    return x * sigm(y);
}

// ================== gemm256: C[M,N] = A[M,K] @ B[N,K]^T, bf16 out ==================
// 512 threads = 8 waves (wm=wid>>2 in {0,1}, wn=wid&3 in {0..3}); per-wave C 128x64.
// BK=32; LDS ring of 3 slots x (A 8192 + B 8192 shorts) = 96 KiB.
// Swizzle: LDS(row, s) holds global 16B-slot (s ^ (row&3)); read at slot q^(row&3).
// EPI: 0 plain, 2 gelu(acc+bias).
template <int EPI>
__global__ __launch_bounds__(512, 1) void gemm256(
    const short* __restrict__ A, const short* __restrict__ B,
    const float* __restrict__ bias, unsigned short* __restrict__ C,
    int K, int lda, int ldb, int ldc, int nbx) {
    __shared__ __align__(16) short smem[3 * 16384];
    const int tid = threadIdx.x;
    const int lane = tid & 63;
    const int wid = tid >> 6;
    const int wm = wid >> 2, wn = wid & 3;
    // bijective XCD swizzle (grid multiple of 8)
    const int cpx = gridDim.x >> 3;
    const int wg = ((int)blockIdx.x & 7) * cpx + ((int)blockIdx.x >> 3);
    const int m0 = (wg / nbx) * 256;
    const int n0 = (wg % nbx) * 256;

    const int srow = tid >> 2;                                   // 0..127 per round
    const int scol = (((tid & 3) ^ ((tid >> 2) & 3)) * 8);       // inverse-swizzled source col
    auto stage = [&](int slot, int k0) {
#pragma unroll
        for (int r = 0; r < 2; ++r) {
            gload_lds16(A + (long long)(m0 + r * 128 + srow) * lda + k0 + scol,
                        &smem[slot * 16384 + r * 4096 + wid * 512]);
            gload_lds16(B + (long long)(n0 + r * 128 + srow) * ldb + k0 + scol,
                        &smem[slot * 16384 + 8192 + r * 4096 + wid * 512]);
        }
    };

    const int NT = K >> 5;
    f32x4 acc[8][4] = {};
    stage(0, 0);
    stage(1, 32);
    // per-lane swizzled read offsets (shorts): row*32 + (q^(row&3))*8, row&3 == lane&3
    const int sw8 = (((lane >> 4) ^ (lane & 3)) * 8);
    const int aoff = (wm * 128 + (lane & 15)) * 32 + sw8;
    const int boff = 8192 + (wn * 64 + (lane & 15)) * 32 + sw8;

    int sl = 0;
    for (int t = 0; t < NT; ++t) {
        int sp = sl + 2; if (sp >= 3) sp -= 3;
        if (t + 2 < NT) stage(sp, (t + 2) * 32);
        if (t + 2 < NT)      asm volatile("s_waitcnt vmcnt(8)" ::: "memory");
        else if (t + 1 < NT) asm volatile("s_waitcnt vmcnt(4)" ::: "memory");
        else                 asm volatile("s_waitcnt vmcnt(0)" ::: "memory");
        __builtin_amdgcn_s_barrier();
        asm volatile("" ::: "memory");
        __builtin_amdgcn_sched_barrier(0);
        const short* As = &smem[sl * 16384 + aoff];
        const short* Bs = &smem[sl * 16384 + boff];
        bf16x8 a[8], b[4];
#pragma unroll
        for (int m = 0; m < 8; ++m) a[m] = *(const bf16x8*)&As[m * 512];
#pragma unroll
        for (int n = 0; n < 4; ++n) b[n] = *(const bf16x8*)&Bs[n * 512];
        __builtin_amdgcn_s_setprio(1);
#pragma unroll
        for (int m = 0; m < 8; ++m)
#pragma unroll
            for (int n = 0; n < 4; ++n)
                acc[m][n] = __builtin_amdgcn_mfma_f32_16x16x32_bf16(a[m], b[n], acc[m][n], 0, 0, 0);
        __builtin_amdgcn_s_setprio(0);
        __builtin_amdgcn_s_barrier();
        asm volatile("" ::: "memory");
        sl = (sl == 2) ? 0 : sl + 1;
    }

    // ---- epilogue: two half-rounds (rows 0-127, 128-255) via LDS, vector stores ----
    const int ocol = lane & 15;
    const int orow4 = (lane >> 4) * 4;
    float bv[4];
    if (EPI == 2) {
#pragma unroll
        for (int n = 0; n < 4; ++n) bv[n] = bias[n0 + wn * 64 + n * 16 + ocol];
    }
#pragma unroll 1
    for (int half = 0; half < 2; ++half) {
        __syncthreads();
        if (wm == half) {
#pragma unroll
            for (int m = 0; m < 8; ++m)
#pragma unroll
                for (int n = 0; n < 4; ++n)
#pragma unroll
                    for (int rj = 0; rj < 4; ++rj) {
                        int lr = m * 16 + orow4 + rj;
                        int lc = wn * 64 + n * 16 + ocol;
                        float v = acc[m][n][rj];
                        if (EPI == 2) v = gelu_fast(v + bv[n]);
                        smem[lr * 256 + lc] = (short)f2bf(v);
                    }
        }
        __syncthreads();
#pragma unroll
        for (int p = 0; p < 8; ++p) {
            int s = p * 512 + tid;
            int row = s >> 5;
            int cc = (s & 31) * 8;
            *(int4*)&C[(long long)(m0 + half * 128 + row) * ldc + n0 + cc] =
                *(const int4*)&smem[row * 256 + cc];
        }
    }
}

// ============ MFMA GEMM (2-phase 128-tile, proven) ============
// EPI: 0 plain store, 1 store acc+bias, 2 store gelu(acc+bias)
template <int EPI, int BN>
__global__ __launch_bounds__(256) void mgemm(
    const short* __restrict__ A, const short* __restrict__ B,
    const float* __restrict__ bias, unsigned short* __restrict__ C,
    int K, int lda, int ldb, int ldc,
    long long sA, long long sB, long long sC, int tri) {
    constexpr int MI = (BN == 128) ? 4 : 2;
    constexpr int WRS = (BN == 128) ? 64 : 32;
    __shared__ __align__(16) short smem[(128 + BN) * 64];
    const int tid = threadIdx.x;
    const int lane = tid & 63;
    const int wid = tid >> 6;
    const int wr = (BN == 128) ? (wid >> 1) : wid;
    const int wc = (BN == 128) ? (wid & 1) : 0;
    const int m0 = blockIdx.y * 128, n0 = blockIdx.x * BN;
    A += (long long)blockIdx.z * sA;
    B += (long long)blockIdx.z * sB;

    int Keff = K;
    if (tri) { int km = m0 + 128; if (km < Keff) Keff = km; }
    const int nk = Keff >> 5;

    auto stage = [&](int buf, int k0) {
#pragma unroll
        for (int it = 0; it < 2; ++it) {
            int slot = it * 256 + tid;
            int rr = slot >> 2;
            int cc = (slot & 3) * 8;
            gload_lds16(A + (long long)(m0 + rr) * lda + k0 + cc,
                        &smem[buf * 4096 + (it * 256 + wid * 64) * 8]);
        }
#pragma unroll
        for (int it = 0; it < BN / 64; ++it) {
            int slot = it * 256 + tid;
            int rr = slot >> 2;
            int cc = (slot & 3) * 8;
            gload_lds16(B + (long long)(n0 + rr) * ldb + k0 + cc,
                        &smem[8192 + buf * (BN * 32) + (it * 256 + wid * 64) * 8]);
        }
    };

    f32x4 acc[MI][4] = {};
    stage(0, 0);
    __syncthreads();
    for (int t = 0; t < nk; ++t) {
        int buf = t & 1;
        if (t + 1 < nk) stage(buf ^ 1, (t + 1) * 32);
        bf16x8 af[MI], bfr[4];
#pragma unroll
        for (int i = 0; i < MI; ++i)
            af[i] = *(const bf16x8*)&smem[buf * 4096 +
                (wr * WRS + i * 16 + (lane & 15)) * 32 + (lane >> 4) * 8];
#pragma unroll
        for (int j = 0; j < 4; ++j)
            bfr[j] = *(const bf16x8*)&smem[8192 + buf * (BN * 32) +
                (wc * 64 + j * 16 + (lane & 15)) * 32 + (lane >> 4) * 8];
#pragma unroll
        for (int i = 0; i < MI; ++i)
#pragma unroll
            for (int j = 0; j < 4; ++j)
                acc[i][j] = __builtin_amdgcn_mfma_f32_16x16x32_bf16(af[i], bfr[j], acc[i][j], 0, 0, 0);
        __syncthreads();
    }
    const int orow = (lane >> 4) * 4;
    const int ocol = lane & 15;
    float bv[4];
    if (EPI >= 1) {
#pragma unroll
        for (int j = 0; j < 4; ++j) bv[j] = bias[n0 + wc * 64 + j * 16 + ocol];
    }
#pragma unroll
    for (int i = 0; i < MI; ++i)
#pragma unroll
        for (int j = 0; j < 4; ++j)
#pragma unroll
            for (int rj = 0; rj < 4; ++rj) {
                int lrow = wr * WRS + i * 16 + orow + rj;
                int lcol = wc * 64 + j * 16 + ocol;
                float val = acc[i][j][rj];
                if (EPI == 1) val += bv[j];
                if (EPI == 2) val = gelu_fast(val + bv[j]);
                smem[lrow * BN + lcol] = (short)f2bf(val);
            }
    __syncthreads();
    const long long zoff = (long long)blockIdx.z * sC;
    constexpr int CH = 128 * BN / 8;
#pragma unroll
    for (int p = 0; p < CH / 256; ++p) {
        int s = p * 256 + tid;
        int row = s / (BN / 8);
        int cc = (s % (BN / 8)) * 8;
        *(int4*)&C[zoff + (long long)(m0 + row) * ldc + n0 + cc] = *(const int4*)&smem[row * BN + cc];
    }
}

// ============ scores = (q @ k^T) * gamma^(n-m) * KSCALE, bf16, per-batch ============
__global__ __launch_bounds__(256) void mgemm_decay(
    const short* __restrict__ Q, const short* __restrict__ Kp,
    unsigned short* __restrict__ S, int lda, long long sA) {
    if (blockIdx.x > blockIdx.y) return;
    const int q0 = blockIdx.y * 128;
    const int c0 = blockIdx.x * 128;
    unsigned short* Sb = S + (long long)blockIdx.z * SEQ * SEQ;
    __shared__ __align__(16) short smem[16384];
    const int tid = threadIdx.x;
    const int lane = tid & 63;
    const int wid = tid >> 6;
    const int wr = wid >> 1, wc = wid & 1;
    const short* Ab = Q + (long long)blockIdx.z * sA;
    const short* Bb = Kp + (long long)blockIdx.z * sA;

    auto stage = [&](int buf, int k0) {
#pragma unroll
        for (int it = 0; it < 2; ++it) {
            int slot = it * 256 + tid;
            int rr = slot >> 2;
            int cc = (slot & 3) * 8;
            gload_lds16(Ab + (long long)(q0 + rr) * lda + k0 + cc,
                        &smem[buf * 4096 + (it * 256 + wid * 64) * 8]);
            gload_lds16(Bb + (long long)(c0 + rr) * lda + k0 + cc,
                        &smem[8192 + buf * 4096 + (it * 256 + wid * 64) * 8]);
        }
    };

    f32x4 acc[4][4] = {};
    stage(0, 0);
    __syncthreads();
    const int nk = D_MODEL / 32;
    for (int t = 0; t < nk; ++t) {
        int buf = t & 1;
        if (t + 1 < nk) stage(buf ^ 1, (t + 1) * 32);
        bf16x8 af[4], bfr[4];
#pragma unroll
        for (int i = 0; i < 4; ++i)
            af[i] = *(const bf16x8*)&smem[buf * 4096 +
                (wr * 64 + i * 16 + (lane & 15)) * 32 + (lane >> 4) * 8];
#pragma unroll
        for (int j = 0; j < 4; ++j)
            bfr[j] = *(const bf16x8*)&smem[8192 + buf * 4096 +
                (wc * 64 + j * 16 + (lane & 15)) * 32 + (lane >> 4) * 8];
#pragma unroll
        for (int i = 0; i < 4; ++i)
#pragma unroll
            for (int j = 0; j < 4; ++j)
                acc[i][j] = __builtin_amdgcn_mfma_f32_16x16x32_bf16(af[i], bfr[j], acc[i][j], 0, 0, 0);
        __syncthreads();
    }
    const int orow = (lane >> 4) * 4;
    const int ocol = lane & 15;
#pragma unroll
    for (int i = 0; i < 4; ++i)
#pragma unroll
        for (int j = 0; j < 4; ++j)
#pragma unroll
            for (int rj = 0; rj < 4; ++rj) {
                int lrow = wr * 64 + i * 16 + orow + rj;
                int lcol = wc * 64 + j * 16 + ocol;
                int n = q0 + lrow, m = c0 + lcol;
                float w = (n >= m) ? exp2f((float)(n - m) * LOG2_GAMMA) * KSCALE : 0.f;
                smem[lrow * 128 + lcol] = (short)f2bf(acc[i][j][rj] * w);
            }
    __syncthreads();
#pragma unroll
    for (int p = 0; p < 8; ++p) {
        int s = p * 256 + tid;
        int row = s >> 4;
        int cc = (s & 15) * 8;
        *(int4*)&Sb[(long long)(q0 + row) * SEQ + c0 + cc] = *(const int4*)&smem[row * 128 + cc];
    }
}

// ============ fused weight convert+transpose ============
__global__ __launch_bounds__(256) void wconv_all(
    const float* __restrict__ Wq, const float* __restrict__ Wk,
    const float* __restrict__ Wv, const float* __restrict__ Wg,
    const float* __restrict__ Wo, const float* __restrict__ W1,
    const float* __restrict__ W2,
    unsigned short* __restrict__ WqkvgT, unsigned short* __restrict__ WoT,
    unsigned short* __restrict__ W1T, unsigned short* __restrict__ W2T) {
    const long long dd = 512LL * 512;
    int z = blockIdx.z;
    int l = z / 7, w = z % 7;
    const float* src; unsigned short* dst; int K, N;
    switch (w) {
        case 0: src = Wq + l * dd; dst = WqkvgT + (long long)l * 4 * dd; K = 512; N = 512; break;
        case 1: src = Wk + l * dd; dst = WqkvgT + (long long)l * 4 * dd + dd; K = 512; N = 512; break;
        case 2: src = Wv + l * dd; dst = WqkvgT + (long long)l * 4 * dd + 2 * dd; K = 512; N = 512; break;
        case 3: src = Wg + l * dd; dst = WqkvgT + (long long)l * 4 * dd + 3 * dd; K = 512; N = 512; break;
        case 4: src = Wo + l * dd; dst = WoT + l * dd; K = 512; N = 512; break;
        case 5: src = W1 + (long long)l * 512 * 1024; dst = W1T + (long long)l * 512 * 1024; K = 512; N = 1024; break;
        default: src = W2 + (long long)l * 1024 * 512; dst = W2T + (long long)l * 1024 * 512; K = 1024; N = 512; break;
    }
    if ((int)blockIdx.x >= N / 64 || (int)blockIdx.y >= K / 64) return;
    __shared__ unsigned short t[64][65];
    int n0 = blockIdx.x * 64, k0 = blockIdx.y * 64;
    int tx = threadIdx.x & 63, ty = threadIdx.x >> 6;
#pragma unroll
    for (int i = 0; i < 16; ++i)
        t[ty + i * 4][tx] = f2bf(src[(long long)(k0 + ty + i * 4) * N + n0 + tx]);
    __syncthreads();
#pragma unroll
    for (int i = 0; i < 16; ++i)
        dst[(long long)(n0 + ty + i * 4) * K + k0 + tx] = t[tx][ty + i * 4];
}

// ============ per-batch transpose: bf16 [SEQ][*stride slice] -> [D][SEQ] ============
__global__ __launch_bounds__(256) void vtrans(const unsigned short* __restrict__ in,
                                              unsigned short* __restrict__ out, int istride) {
    __shared__ unsigned short t[64][65];
    const unsigned short* pin = in + (long long)blockIdx.z * SEQ * istride;
    unsigned short* pout = out + (long long)blockIdx.z * D_MODEL * SEQ;
    int c0 = blockIdx.x * 64, r0 = blockIdx.y * 64;
    int tx = threadIdx.x & 63, ty = threadIdx.x >> 6;
#pragma unroll
    for (int i = 0; i < 16; ++i)
        t[ty + i * 4][tx] = pin[(long long)(r0 + ty + i * 4) * istride + c0 + tx];
    __syncthreads();
#pragma unroll
    for (int i = 0; i < 16; ++i)
        pout[(long long)(c0 + ty + i * 4) * SEQ + r0 + tx] = t[tx][ty + i * 4];
}

// ============ x (f32) -> h (bf16) ============
__global__ __launch_bounds__(256) void conv_x(const float* __restrict__ x,
                                              unsigned short* __restrict__ h) {
    int i = blockIdx.x * 256 + threadIdx.x;
    float4 v = ((const float4*)x)[i];
    ushort4 o;
    o.x = f2bf(v.x); o.y = f2bf(v.y); o.z = f2bf(v.z); o.w = f2bf(v.w);
    ((ushort4*)h)[i] = o;
}

// ============ fused residual-add + LayerNorm, all bf16 ============
template <int MODE>
__global__ __launch_bounds__(256) void ln_fuse(
    const unsigned short* __restrict__ hin,
    const unsigned short* __restrict__ delta,
    const float* __restrict__ g, const float* __restrict__ b,
    unsigned short* __restrict__ hout,
    unsigned short* __restrict__ y) {
    int row = blockIdx.x * 4 + (threadIdx.x >> 6);
    int t = threadIdx.x & 63;
    int4 hv = ((const int4*)(hin + (long long)row * D_MODEL))[t];
    const unsigned short* hu = (const unsigned short*)&hv;
    float f[8];
#pragma unroll
    for (int k = 0; k < 8; ++k) f[k] = bf2f(hu[k]);
    if (MODE == 1) {
        int4 dv = ((const int4*)(delta + (long long)row * D_MODEL))[t];
        const unsigned short* du = (const unsigned short*)&dv;
#pragma unroll
        for (int k = 0; k < 8; ++k) f[k] += bf2f(du[k]);
    }
    float s = 0.f, s2 = 0.f;
#pragma unroll
    for (int k = 0; k < 8; ++k) { s += f[k]; s2 += f[k] * f[k]; }
#pragma unroll
    for (int off = 32; off > 0; off >>= 1) {
        s += __shfl_down(s, off);
        s2 += __shfl_down(s2, off);
    }
    s = __shfl(s, 0); s2 = __shfl(s2, 0);
    float mu = s * (1.f / D_MODEL);
    float var = s2 * (1.f / D_MODEL) - mu * mu;
    float rs = rsqrtf(var + 1e-6f);
    if (MODE == 1) {
        ushort4 ho[2];
        unsigned short* hp = (unsigned short*)ho;
#pragma unroll
        for (int k = 0; k < 8; ++k) hp[k] = f2bf(f[k]);
        ((int4*)(hout + (long long)row * D_MODEL))[t] = *(int4*)ho;
    }
    const float4* g4 = (const float4*)g;
    const float4* b4 = (const float4*)b;
    float4 ga = g4[2 * t], gb2 = g4[2 * t + 1];
    float4 ba = b4[2 * t], bb2 = b4[2 * t + 1];
    float gg[8] = {ga.x, ga.y, ga.z, ga.w, gb2.x, gb2.y, gb2.z, gb2.w};
    float bb[8] = {ba.x, ba.y, ba.z, ba.w, bb2.x, bb2.y, bb2.z, bb2.w};
    ushort4 yo[2];
    unsigned short* yp = (unsigned short*)yo;
#pragma unroll
    for (int k = 0; k < 8; ++k) yp[k] = f2bf((f[k] - mu) * rs * gg[k] + bb[k]);
    ((int4*)(y + (long long)row * D_MODEL))[t] = *(int4*)yo;
}

// ============ gated = silu(g) * groupnorm(ret), all bf16 (g strided) ============
__global__ __launch_bounds__(256) void gate_bf16(const unsigned short* __restrict__ ret,
                                                 const unsigned short* __restrict__ g,
                                                 int gstride,
                                                 unsigned short* __restrict__ out) {
    int row = blockIdx.x * 4 + (threadIdx.x >> 6);
    int t = threadIdx.x & 63;
    int4 rv4 = ((const int4*)(ret + (long long)row * D_MODEL))[t];
    const unsigned short* ru = (const unsigned short*)&rv4;
    float f[8];
#pragma unroll
    for (int k = 0; k < 8; ++k) f[k] = bf2f(ru[k]);
    float s = 0.f, s2 = 0.f;
#pragma unroll
    for (int k = 0; k < 8; ++k) { s += f[k]; s2 += f[k] * f[k]; }
#pragma unroll
    for (int off = 32; off > 0; off >>= 1) {
        s += __shfl_down(s, off);
        s2 += __shfl_down(s2, off);
    }
    s = __shfl(s, 0); s2 = __shfl(s2, 0);
    float mu = s * (1.f / D_MODEL);
    float var = s2 * (1.f / D_MODEL) - mu * mu;
    float rs = rsqrtf(var + 1e-6f);
    int4 gv4 = ((const int4*)(g + (long long)row * gstride))[t];
    const unsigned short* gu = (const unsigned short*)&gv4;
    ushort4 o[2];
    unsigned short* op = (unsigned short*)o;
#pragma unroll
    for (int k = 0; k < 8; ++k) {
        float x = bf2f(gu[k]);
        op[k] = f2bf(x * sigm(x) * (f[k] - mu) * rs);
    }
    ((int4*)(out + (long long)row * D_MODEL))[t] = *(int4*)o;
}

// ============ pooled = sum_rows (h + dlast): two-stage ============
__global__ __launch_bounds__(256) void pool_s1(const unsigned short* __restrict__ h,
                                               const unsigned short* __restrict__ d,
                                               float* __restrict__ partial) {
    int b = blockIdx.x >> 4, g = blockIdx.x & 15;
    long long base = ((long long)b * SEQ + g * 64) * D_MODEL;
    int cw = (threadIdx.x & 63) * 8;
    int rg = threadIdx.x >> 6;
    float a[8] = {};
    for (int r = rg; r < 64; r += 4) {
        long long o = base + (long long)r * D_MODEL + cw;
        int4 hv = *(const int4*)&h[o];
        int4 dv = *(const int4*)&d[o];
        const unsigned short* hp = (const unsigned short*)&hv;
        const unsigned short* dp = (const unsigned short*)&dv;
#pragma unroll
        for (int j = 0; j < 8; ++j) a[j] += bf2f(hp[j]) + bf2f(dp[j]);
    }
    __shared__ float red[4][512];
#pragma unroll
    for (int j = 0; j < 8; ++j) red[rg][cw + j] = a[j];
    __syncthreads();
#pragma unroll
    for (int cc = 0; cc < 2; ++cc) {
        int c = threadIdx.x * 2 + cc;
        partial[(long long)blockIdx.x * D_MODEL + c] =
            red[0][c] + red[1][c] + red[2][c] + red[3][c];
    }
}

__global__ __launch_bounds__(256) void pool_s2(const float* __restrict__ partial,
                                               float* __restrict__ pooled) {
    int idx = blockIdx.x * 256 + threadIdx.x;  // 0..8191
    int b = idx >> 9, c = idx & 511;
    float s = 0.f;
#pragma unroll
    for (int g = 0; g < 16; ++g) s += partial[(long long)(b * 16 + g) * D_MODEL + c];
    pooled[idx] = s;
}

__global__ __launch_bounds__(64) void readout_kernel(const float* __restrict__ pooled,
                                                     const float* __restrict__ Wro,
                                                     const float* __restrict__ bro,
                                                     float* __restrict__ out) {
    int bo = blockIdx.x;
    int b = bo >> 1, o = bo & 1;
    int t = threadIdx.x;
    float s = 0.f;
    for (int i = t; i < D_MODEL; i += 64) s += pooled[b * D_MODEL + i] * Wro[i * 2 + o];
#pragma unroll
    for (int off = 32; off > 0; off >>= 1) s += __shfl_down(s, off);
    if (t == 0) out[b * 2 + o] = s + bro[o];
}

extern "C" void kernel_launch(void* const* d_in, const int* in_sizes, int n_in,
                              void* d_out, int out_size, void* d_ws, size_t ws_size,
                              hipStream_t stream) {
    const float* x = (const float*)d_in[0];
    const float* Wq = (const float*)d_in[1];
    const float* Wk = (const float*)d_in[2];
    const float* Wv = (const float*)d_in[3];
    const float* Wg = (const float*)d_in[4];
    const float* Wo = (const float*)d_in[5];
    const float* ln1_g = (const float*)d_in[6];
    const float* ln1_b = (const float*)d_in[7];
    const float* ln2_g = (const float*)d_in[8];
    const float* ln2_b = (const float*)d_in[9];
    const float* W1 = (const float*)d_in[10];
    const float* b1 = (const float*)d_in[11];
    const float* W2 = (const float*)d_in[12];
    const float* b2 = (const float*)d_in[13];
    const float* Wro = (const float*)d_in[14];
    const float* bro = (const float*)d_in[15];
    float* out = (float*)d_out;

    const long long NE = (long long)NROWS * D_MODEL;  // 8,388,608
    const long long dd = (long long)D_MODEL * D_MODEL;

    unsigned short* h = (unsigned short*)d_ws;   // NE
    unsigned short* y = h + NE;                  // NE
    unsigned short* qkvg = y + NE;               // 4*NE  [16384][2048]
    unsigned short* vT = qkvg + 4 * NE;          // NE    [16][512][1024]
    unsigned short* gated = vT;                  // alias (vT dead after ret GEMM)
    unsigned short* ret = vT + NE;               // NE    (also ffn-delta buffer)
    unsigned short* sg = ret + NE;               // 2*NE  scores / attn-delta / ffn-hidden
    float* pooled = (float*)(sg + 2 * NE);       // 8192 f32
    float* partial = pooled + 8192;              // 256*512 f32
    unsigned short* wts = (unsigned short*)(partial + 256 * 512);
    unsigned short* WqkvgT = wts;                          // [L][2048][512]
    unsigned short* WoT = WqkvgT + 2 * 4 * dd;             // [L][512][512]
    unsigned short* W1T = WoT + 2 * dd;                    // [L][1024][512]
    unsigned short* W2T = W1T + 2 * (long long)D_MODEL * HID;  // [L][512][1024]

    dim3 blk(256);
    conv_x<<<NE / 1024, blk, 0, stream>>>(x, h);
    wconv_all<<<dim3(16, 16, 14), blk, 0, stream>>>(Wq, Wk, Wv, Wg, Wo, W1, W2,
                                                    WqkvgT, WoT, W1T, W2T);

    for (int l = 0; l < 2; l++) {
        if (l == 0)
            ln_fuse<0><<<NROWS / 4, blk, 0, stream>>>(h, nullptr, ln1_g, ln1_b, nullptr, y);
        else
            ln_fuse<1><<<NROWS / 4, blk, 0, stream>>>(h, ret, ln1_g + l * D_MODEL,
                                                      ln1_b + l * D_MODEL, h, y);
        // qkvg = y @ [Wq|Wk|Wv|Wg]   (256² pipelined GEMM, 512 blocks)
        gemm256<0><<<512, 512, 0, stream>>>(
            (const short*)y, (const short*)(WqkvgT + (long long)l * 4 * dd), nullptr, qkvg,
            512, 512, 512, 2048, 8);
        vtrans<<<dim3(8, 16, BATCH), blk, 0, stream>>>(qkvg + 1024, vT, 2048);
        mgemm_decay<<<dim3(8, 8, BATCH), blk, 0, stream>>>(
            (const short*)qkvg, (const short*)(qkvg + 512), sg, 2048, (long long)SEQ * 2048);
        // ret = scores @ v  (K truncated at diagonal)
        mgemm<0, 64><<<dim3(8, 8, BATCH), blk, 0, stream>>>(
            (const short*)sg, (const short*)vT, nullptr, ret,
            SEQ, SEQ, SEQ, 512,
            (long long)SEQ * SEQ, (long long)D_MODEL * SEQ, (long long)SEQ * D_MODEL, 1);
        gate_bf16<<<NROWS / 4, blk, 0, stream>>>(ret, qkvg + 1536, 2048, gated);
        // attn delta = gated @ Wo  -> sg
        mgemm<0, 64><<<dim3(8, 128), blk, 0, stream>>>(
            (const short*)gated, (const short*)(WoT + l * dd), nullptr, sg,
            512, 512, 512, 512, 0, 0, 0, 0);
        // h += attn delta; y = LN2(h)
        ln_fuse<1><<<NROWS / 4, blk, 0, stream>>>(h, sg, ln2_g + l * D_MODEL,
                                                  ln2_b + l * D_MODEL, h, y);
        // hidden = gelu(y @ W1 + b1)   (256² pipelined GEMM, 256 blocks)
        gemm256<2><<<256, 512, 0, stream>>>(
            (const short*)y, (const short*)(W1T + (long long)l * D_MODEL * HID),
            b1 + l * HID, sg, 512, 512, 512, HID, 4);
        // ffn delta = hidden @ W2 + b2 -> ret buffer
        mgemm<1, 64><<<dim3(8, 128), blk, 0, stream>>>(
            (const short*)sg, (const short*)(W2T + (long long)l * HID * D_MODEL),
            b2 + l * D_MODEL, ret, HID, HID, HID, 512, 0, 0, 0, 0);
    }

    pool_s1<<<256, blk, 0, stream>>>(h, ret, partial);
    pool_s2<<<32, blk, 0, stream>>>(partial, pooled);
    readout_kernel<<<32, 64, 0, stream>>>(pooled, Wro, bro, out);
}

// Round 7
// 543.071 us; speedup vs baseline: 6.0408x; 1.0234x over previous
//
#include <hip/hip_runtime.h>
#include <hip/hip_bf16.h>

// RetNet 2-layer forward. All-bf16 dataflow.
// Big GEMMs: 256x256 tile, 3-deep ring, counted vmcnt, CORRECT 2-way LDS swizzle.
// Swizzle: 16B-slot p in a row stores source slot p ^ ((row>>1)&3); reads use
// q ^ ((row>>1)&3)  -> 2 lanes/bank-bucket per quarter (free, m136).

#define D_MODEL 512
#define SEQ 1024
#define BATCH 16
#define NROWS (BATCH * SEQ)          // 16384
#define HID 1024
#define LOG2_GAMMA (-0.04580368961f)  // log2(0.96875)
#define KSCALE (0.044194173824f)      // 512^-0.5

typedef __attribute__((ext_vector_type(8))) short bf16x8;
typedef __attribute__((ext_vector_type(4))) float f32x4;

__device__ inline unsigned short f2bf(float x) {
    union { float f; unsigned u; } uu; uu.f = x;
    unsigned r = uu.u + 0x7fff + ((uu.u >> 16) & 1);
    return (unsigned short)(r >> 16);
}
__device__ inline float bf2f(unsigned short x) {
    union { unsigned u; float f; } uu; uu.u = ((unsigned)x) << 16; return uu.f;
}

__device__ inline void gload_lds16(const void* g, void* l) {
    __builtin_amdgcn_global_load_lds(
        (const __attribute__((address_space(1))) void*)g,
        (__attribute__((address_space(3))) void*)l, 16, 0, 0);
}

__device__ inline float sigm(float z) {
    return 1.f / (1.f + exp2f(z * -1.442695040888963f));
}
__device__ inline float gelu_fast(float x) {
    float y = 1.5957691216057308f * (x + 0.044715f * x * x * x);
    return x * sigm(y);
}

// ================== gemm256: C[M,N] = A[M,K] @ B[N,K]^T, bf16 out ==================
template <int EPI>
__global__ __launch_bounds__(512, 1) void gemm256(
    const short* __restrict__ A, const short* __restrict__ B,
    const float* __restrict__ bias, unsigned short* __restrict__ C,
    int K, int lda, int ldb, int ldc, int nbx) {
    __shared__ __align__(16) short smem[3 * 16384];
    const int tid = threadIdx.x;
    const int lane = tid & 63;
    const int wid = tid >> 6;
    const int wm = wid >> 2, wn = wid & 3;
    const int cpx = gridDim.x >> 3;
    const int wg = ((int)blockIdx.x & 7) * cpx + ((int)blockIdx.x >> 3);
    const int m0 = (wg / nbx) * 256;
    const int n0 = (wg % nbx) * 256;

    const int srow = tid >> 2;                                    // 0..127 per half
    const int scol = (((tid & 3) ^ ((tid >> 3) & 3)) * 8);        // inverse-swizzled src col
    auto stage = [&](int slot, int k0) {
#pragma unroll
        for (int r = 0; r < 2; ++r) {
            gload_lds16(A + (long long)(m0 + r * 128 + srow) * lda + k0 + scol,
                        &smem[slot * 16384 + r * 4096 + wid * 512]);
            gload_lds16(B + (long long)(n0 + r * 128 + srow) * ldb + k0 + scol,
                        &smem[slot * 16384 + 8192 + r * 4096 + wid * 512]);
        }
    };

    const int NT = K >> 5;
    f32x4 acc[8][4] = {};
    stage(0, 0);
    stage(1, 32);
    const int sw8 = (((lane >> 4) ^ ((lane >> 1) & 3)) * 8);
    const int aoff = (wm * 128 + (lane & 15)) * 32 + sw8;
    const int boff = 8192 + (wn * 64 + (lane & 15)) * 32 + sw8;

    int sl = 0;
    for (int t = 0; t < NT; ++t) {
        int sp = sl + 2; if (sp >= 3) sp -= 3;
        if (t + 2 < NT) stage(sp, (t + 2) * 32);
        if (t + 2 < NT)      asm volatile("s_waitcnt vmcnt(8)" ::: "memory");
        else if (t + 1 < NT) asm volatile("s_waitcnt vmcnt(4)" ::: "memory");
        else                 asm volatile("s_waitcnt vmcnt(0)" ::: "memory");
        __builtin_amdgcn_s_barrier();
        asm volatile("" ::: "memory");
        __builtin_amdgcn_sched_barrier(0);
        const short* As = &smem[sl * 16384 + aoff];
        const short* Bs = &smem[sl * 16384 + boff];
        bf16x8 a[8], b[4];
#pragma unroll
        for (int m = 0; m < 8; ++m) a[m] = *(const bf16x8*)&As[m * 512];
#pragma unroll
        for (int n = 0; n < 4; ++n) b[n] = *(const bf16x8*)&Bs[n * 512];
        __builtin_amdgcn_s_setprio(1);
#pragma unroll
        for (int m = 0; m < 8; ++m)
#pragma unroll
            for (int n = 0; n < 4; ++n)
                acc[m][n] = __builtin_amdgcn_mfma_f32_16x16x32_bf16(a[m], b[n], acc[m][n], 0, 0, 0);
        __builtin_amdgcn_s_setprio(0);
        __builtin_amdgcn_s_barrier();
        asm volatile("" ::: "memory");
        sl = (sl == 2) ? 0 : sl + 1;
    }

    const int ocol = lane & 15;
    const int orow4 = (lane >> 4) * 4;
    float bv[4];
    if (EPI == 2) {
#pragma unroll
        for (int n = 0; n < 4; ++n) bv[n] = bias[n0 + wn * 64 + n * 16 + ocol];
    }
#pragma unroll 1
    for (int half = 0; half < 2; ++half) {
        __syncthreads();
        if (wm == half) {
#pragma unroll
            for (int m = 0; m < 8; ++m)
#pragma unroll
                for (int n = 0; n < 4; ++n)
#pragma unroll
                    for (int rj = 0; rj < 4; ++rj) {
                        int lr = m * 16 + orow4 + rj;
                        int lc = wn * 64 + n * 16 + ocol;
                        float v = acc[m][n][rj];
                        if (EPI == 2) v = gelu_fast(v + bv[n]);
                        smem[lr * 256 + lc] = (short)f2bf(v);
                    }
        }
        __syncthreads();
#pragma unroll
        for (int p = 0; p < 8; ++p) {
            int s = p * 512 + tid;
            int row = s >> 5;
            int cc = (s & 31) * 8;
            *(int4*)&C[(long long)(m0 + half * 128 + row) * ldc + n0 + cc] =
                *(const int4*)&smem[row * 256 + cc];
        }
    }
}

// ============ MFMA GEMM (2-phase 128-tile) ============
template <int EPI, int BN>
__global__ __launch_bounds__(256) void mgemm(
    const short* __restrict__ A, const short* __restrict__ B,
    const float* __restrict__ bias, unsigned short* __restrict__ C,
    int K, int lda, int ldb, int ldc,
    long long sA, long long sB, long long sC, int tri) {
    constexpr int MI = (BN == 128) ? 4 : 2;
    constexpr int WRS = (BN == 128) ? 64 : 32;
    __shared__ __align__(16) short smem[(128 + BN) * 64];
    const int tid = threadIdx.x;
    const int lane = tid & 63;
    const int wid = tid >> 6;
    const int wr = (BN == 128) ? (wid >> 1) : wid;
    const int wc = (BN == 128) ? (wid & 1) : 0;
    const int m0 = blockIdx.y * 128, n0 = blockIdx.x * BN;
    A += (long long)blockIdx.z * sA;
    B += (long long)blockIdx.z * sB;

    int Keff = K;
    if (tri) { int km = m0 + 128; if (km < Keff) Keff = km; }
    const int nk = Keff >> 5;

    auto stage = [&](int buf, int k0) {
#pragma unroll
        for (int it = 0; it < 2; ++it) {
            int slot = it * 256 + tid;
            int rr = slot >> 2;
            int cc = ((slot & 3) ^ ((slot >> 3) & 3)) * 8;
            gload_lds16(A + (long long)(m0 + rr) * lda + k0 + cc,
                        &smem[buf * 4096 + (it * 256 + wid * 64) * 8]);
        }
#pragma unroll
        for (int it = 0; it < BN / 64; ++it) {
            int slot = it * 256 + tid;
            int rr = slot >> 2;
            int cc = ((slot & 3) ^ ((slot >> 3) & 3)) * 8;
            gload_lds16(B + (long long)(n0 + rr) * ldb + k0 + cc,
                        &smem[8192 + buf * (BN * 32) + (it * 256 + wid * 64) * 8]);
        }
    };

    f32x4 acc[MI][4] = {};
    stage(0, 0);
    __syncthreads();
    const int sw8 = (((lane >> 4) ^ ((lane >> 1) & 3)) * 8);
    for (int t = 0; t < nk; ++t) {
        int buf = t & 1;
        if (t + 1 < nk) stage(buf ^ 1, (t + 1) * 32);
        bf16x8 af[MI], bfr[4];
#pragma unroll
        for (int i = 0; i < MI; ++i)
            af[i] = *(const bf16x8*)&smem[buf * 4096 +
                (wr * WRS + i * 16 + (lane & 15)) * 32 + sw8];
#pragma unroll
        for (int j = 0; j < 4; ++j)
            bfr[j] = *(const bf16x8*)&smem[8192 + buf * (BN * 32) +
                (wc * 64 + j * 16 + (lane & 15)) * 32 + sw8];
#pragma unroll
        for (int i = 0; i < MI; ++i)
#pragma unroll
            for (int j = 0; j < 4; ++j)
                acc[i][j] = __builtin_amdgcn_mfma_f32_16x16x32_bf16(af[i], bfr[j], acc[i][j], 0, 0, 0);
        __syncthreads();
    }
    const int orow = (lane >> 4) * 4;
    const int ocol = lane & 15;
    float bv[4];
    if (EPI >= 1) {
#pragma unroll
        for (int j = 0; j < 4; ++j) bv[j] = bias[n0 + wc * 64 + j * 16 + ocol];
    }
#pragma unroll
    for (int i = 0; i < MI; ++i)
#pragma unroll
        for (int j = 0; j < 4; ++j)
#pragma unroll
            for (int rj = 0; rj < 4; ++rj) {
                int lrow = wr * WRS + i * 16 + orow + rj;
                int lcol = wc * 64 + j * 16 + ocol;
                float val = acc[i][j][rj];
                if (EPI == 1) val += bv[j];
                if (EPI == 2) val = gelu_fast(val + bv[j]);
                smem[lrow * BN + lcol] = (short)f2bf(val);
            }
    __syncthreads();
    const long long zoff = (long long)blockIdx.z * sC;
    constexpr int CH = 128 * BN / 8;
#pragma unroll
    for (int p = 0; p < CH / 256; ++p) {
        int s = p * 256 + tid;
        int row = s / (BN / 8);
        int cc = (s % (BN / 8)) * 8;
        *(int4*)&C[zoff + (long long)(m0 + row) * ldc + n0 + cc] = *(const int4*)&smem[row * BN + cc];
    }
}

// ============ scores = (q @ k^T) * gamma^(n-m) * KSCALE, bf16, per-batch ============
__global__ __launch_bounds__(256) void mgemm_decay(
    const short* __restrict__ Q, const short* __restrict__ Kp,
    unsigned short* __restrict__ S, int lda, long long sA) {
    if (blockIdx.x > blockIdx.y) return;
    const int q0 = blockIdx.y * 128;
    const int c0 = blockIdx.x * 128;
    unsigned short* Sb = S + (long long)blockIdx.z * SEQ * SEQ;
    __shared__ __align__(16) short smem[16384];
    const int tid = threadIdx.x;
    const int lane = tid & 63;
    const int wid = tid >> 6;
    const int wr = wid >> 1, wc = wid & 1;
    const short* Ab = Q + (long long)blockIdx.z * sA;
    const short* Bb = Kp + (long long)blockIdx.z * sA;

    auto stage = [&](int buf, int k0) {
#pragma unroll
        for (int it = 0; it < 2; ++it) {
            int slot = it * 256 + tid;
            int rr = slot >> 2;
            int cc = ((slot & 3) ^ ((slot >> 3) & 3)) * 8;
            gload_lds16(Ab + (long long)(q0 + rr) * lda + k0 + cc,
                        &smem[buf * 4096 + (it * 256 + wid * 64) * 8]);
            gload_lds16(Bb + (long long)(c0 + rr) * lda + k0 + cc,
                        &smem[8192 + buf * 4096 + (it * 256 + wid * 64) * 8]);
        }
    };

    f32x4 acc[4][4] = {};
    stage(0, 0);
    __syncthreads();
    const int sw8 = (((lane >> 4) ^ ((lane >> 1) & 3)) * 8);
    const int nk = D_MODEL / 32;
    for (int t = 0; t < nk; ++t) {
        int buf = t & 1;
        if (t + 1 < nk) stage(buf ^ 1, (t + 1) * 32);
        bf16x8 af[4], bfr[4];
#pragma unroll
        for (int i = 0; i < 4; ++i)
            af[i] = *(const bf16x8*)&smem[buf * 4096 +
                (wr * 64 + i * 16 + (lane & 15)) * 32 + sw8];
#pragma unroll
        for (int j = 0; j < 4; ++j)
            bfr[j] = *(const bf16x8*)&smem[8192 + buf * 4096 +
                (wc * 64 + j * 16 + (lane & 15)) * 32 + sw8];
#pragma unroll
        for (int i = 0; i < 4; ++i)
#pragma unroll
            for (int j = 0; j < 4; ++j)
                acc[i][j] = __builtin_amdgcn_mfma_f32_16x16x32_bf16(af[i], bfr[j], acc[i][j], 0, 0, 0);
        __syncthreads();
    }
    const int orow = (lane >> 4) * 4;
    const int ocol = lane & 15;
#pragma unroll
    for (int i = 0; i < 4; ++i)
#pragma unroll
        for (int j = 0; j < 4; ++j)
#pragma unroll
            for (int rj = 0; rj < 4; ++rj) {
                int lrow = wr * 64 + i * 16 + orow + rj;
                int lcol = wc * 64 + j * 16 + ocol;
                int n = q0 + lrow, m = c0 + lcol;
                float w = (n >= m) ? exp2f((float)(n - m) * LOG2_GAMMA) * KSCALE : 0.f;
                smem[lrow * 128 + lcol] = (short)f2bf(acc[i][j][rj] * w);
            }
    __syncthreads();
#pragma unroll
    for (int p = 0; p < 8; ++p) {
        int s = p * 256 + tid;
        int row = s >> 4;
        int cc = (s & 15) * 8;
        *(int4*)&Sb[(long long)(q0 + row) * SEQ + c0 + cc] = *(const int4*)&smem[row * 128 + cc];
    }
}

// ============ fused weight convert+transpose ============
__global__ __launch_bounds__(256) void wconv_all(
    const float* __restrict__ Wq, const float* __restrict__ Wk,
    const float* __restrict__ Wv, const float* __restrict__ Wg,
    const float* __restrict__ Wo, const float* __restrict__ W1,
    const float* __restrict__ W2,
    unsigned short* __restrict__ WqkvgT, unsigned short* __restrict__ WoT,
    unsigned short* __restrict__ W1T, unsigned short* __restrict__ W2T) {
    const long long dd = 512LL * 512;
    int z = blockIdx.z;
    int l = z / 7, w = z % 7;
    const float* src; unsigned short* dst; int K, N;
    switch (w) {
        case 0: src = Wq + l * dd; dst = WqkvgT + (long long)l * 4 * dd; K = 512; N = 512; break;
        case 1: src = Wk + l * dd; dst = WqkvgT + (long long)l * 4 * dd + dd; K = 512; N = 512; break;
        case 2: src = Wv + l * dd; dst = WqkvgT + (long long)l * 4 * dd + 2 * dd; K = 512; N = 512; break;
        case 3: src = Wg + l * dd; dst = WqkvgT + (long long)l * 4 * dd + 3 * dd; K = 512; N = 512; break;
        case 4: src = Wo + l * dd; dst = WoT + l * dd; K = 512; N = 512; break;
        case 5: src = W1 + (long long)l * 512 * 1024; dst = W1T + (long long)l * 512 * 1024; K = 512; N = 1024; break;
        default: src = W2 + (long long)l * 1024 * 512; dst = W2T + (long long)l * 1024 * 512; K = 1024; N = 512; break;
    }
    if ((int)blockIdx.x >= N / 64 || (int)blockIdx.y >= K / 64) return;
    __shared__ unsigned short t[64][65];
    int n0 = blockIdx.x * 64, k0 = blockIdx.y * 64;
    int tx = threadIdx.x & 63, ty = threadIdx.x >> 6;
#pragma unroll
    for (int i = 0; i < 16; ++i)
        t[ty + i * 4][tx] = f2bf(src[(long long)(k0 + ty + i * 4) * N + n0 + tx]);
    __syncthreads();
#pragma unroll
    for (int i = 0; i < 16; ++i)
        dst[(long long)(n0 + ty + i * 4) * K + k0 + tx] = t[tx][ty + i * 4];
}

// ============ per-batch transpose: bf16 [SEQ][*stride slice] -> [D][SEQ] ============
__global__ __launch_bounds__(256) void vtrans(const unsigned short* __restrict__ in,
                                              unsigned short* __restrict__ out, int istride) {
    __shared__ unsigned short t[64][65];
    const unsigned short* pin = in + (long long)blockIdx.z * SEQ * istride;
    unsigned short* pout = out + (long long)blockIdx.z * D_MODEL * SEQ;
    int c0 = blockIdx.x * 64, r0 = blockIdx.y * 64;
    int tx = threadIdx.x & 63, ty = threadIdx.x >> 6;
#pragma unroll
    for (int i = 0; i < 16; ++i)
        t[ty + i * 4][tx] = pin[(long long)(r0 + ty + i * 4) * istride + c0 + tx];
    __syncthreads();
#pragma unroll
    for (int i = 0; i < 16; ++i)
        pout[(long long)(c0 + ty + i * 4) * SEQ + r0 + tx] = t[tx][ty + i * 4];
}

// ============ x (f32) -> h (bf16) ============
__global__ __launch_bounds__(256) void conv_x(const float* __restrict__ x,
                                              unsigned short* __restrict__ h) {
    int i = blockIdx.x * 256 + threadIdx.x;
    float4 v = ((const float4*)x)[i];
    ushort4 o;
    o.x = f2bf(v.x); o.y = f2bf(v.y); o.z = f2bf(v.z); o.w = f2bf(v.w);
    ((ushort4*)h)[i] = o;
}

// ============ fused residual-add + LayerNorm, all bf16 ============
template <int MODE>
__global__ __launch_bounds__(256) void ln_fuse(
    const unsigned short* __restrict__ hin,
    const unsigned short* __restrict__ delta,
    const float* __restrict__ g, const float* __restrict__ b,
    unsigned short* __restrict__ hout,
    unsigned short* __restrict__ y) {
    int row = blockIdx.x * 4 + (threadIdx.x >> 6);
    int t = threadIdx.x & 63;
    int4 hv = ((const int4*)(hin + (long long)row * D_MODEL))[t];
    const unsigned short* hu = (const unsigned short*)&hv;
    float f[8];
#pragma unroll
    for (int k = 0; k < 8; ++k) f[k] = bf2f(hu[k]);
    if (MODE == 1) {
        int4 dv = ((const int4*)(delta + (long long)row * D_MODEL))[t];
        const unsigned short* du = (const unsigned short*)&dv;
#pragma unroll
        for (int k = 0; k < 8; ++k) f[k] += bf2f(du[k]);
    }
    float s = 0.f, s2 = 0.f;
#pragma unroll
    for (int k = 0; k < 8; ++k) { s += f[k]; s2 += f[k] * f[k]; }
#pragma unroll
    for (int off = 32; off > 0; off >>= 1) {
        s += __shfl_down(s, off);
        s2 += __shfl_down(s2, off);
    }
    s = __shfl(s, 0); s2 = __shfl(s2, 0);
    float mu = s * (1.f / D_MODEL);
    float var = s2 * (1.f / D_MODEL) - mu * mu;
    float rs = rsqrtf(var + 1e-6f);
    if (MODE == 1) {
        ushort4 ho[2];
        unsigned short* hp = (unsigned short*)ho;
#pragma unroll
        for (int k = 0; k < 8; ++k) hp[k] = f2bf(f[k]);
        ((int4*)(hout + (long long)row * D_MODEL))[t] = *(int4*)ho;
    }
    const float4* g4 = (const float4*)g;
    const float4* b4 = (const float4*)b;
    float4 ga = g4[2 * t], gb2 = g4[2 * t + 1];
    float4 ba = b4[2 * t], bb2 = b4[2 * t + 1];
    float gg[8] = {ga.x, ga.y, ga.z, ga.w, gb2.x, gb2.y, gb2.z, gb2.w};
    float bb[8] = {ba.x, ba.y, ba.z, ba.w, bb2.x, bb2.y, bb2.z, bb2.w};
    ushort4 yo[2];
    unsigned short* yp = (unsigned short*)yo;
#pragma unroll
    for (int k = 0; k < 8; ++k) yp[k] = f2bf((f[k] - mu) * rs * gg[k] + bb[k]);
    ((int4*)(y + (long long)row * D_MODEL))[t] = *(int4*)yo;
}

// ============ gated = silu(g) * groupnorm(ret), all bf16 (g strided) ============
__global__ __launch_bounds__(256) void gate_bf16(const unsigned short* __restrict__ ret,
                                                 const unsigned short* __restrict__ g,
                                                 int gstride,
                                                 unsigned short* __restrict__ out) {
    int row = blockIdx.x * 4 + (threadIdx.x >> 6);
    int t = threadIdx.x & 63;
    int4 rv4 = ((const int4*)(ret + (long long)row * D_MODEL))[t];
    const unsigned short* ru = (const unsigned short*)&rv4;
    float f[8];
#pragma unroll
    for (int k = 0; k < 8; ++k) f[k] = bf2f(ru[k]);
    float s = 0.f, s2 = 0.f;
#pragma unroll
    for (int k = 0; k < 8; ++k) { s += f[k]; s2 += f[k] * f[k]; }
#pragma unroll
    for (int off = 32; off > 0; off >>= 1) {
        s += __shfl_down(s, off);
        s2 += __shfl_down(s2, off);
    }
    s = __shfl(s, 0); s2 = __shfl(s2, 0);
    float mu = s * (1.f / D_MODEL);
    float var = s2 * (1.f / D_MODEL) - mu * mu;
    float rs = rsqrtf(var + 1e-6f);
    int4 gv4 = ((const int4*)(g + (long long)row * gstride))[t];
    const unsigned short* gu = (const unsigned short*)&gv4;
    ushort4 o[2];
    unsigned short* op = (unsigned short*)o;
#pragma unroll
    for (int k = 0; k < 8; ++k) {
        float x = bf2f(gu[k]);
        op[k] = f2bf(x * sigm(x) * (f[k] - mu) * rs);
    }
    ((int4*)(out + (long long)row * D_MODEL))[t] = *(int4*)o;
}

// ============ pooled = sum_rows (h + dlast): two-stage ============
__global__ __launch_bounds__(256) void pool_s1(const unsigned short* __restrict__ h,
                                               const unsigned short* __restrict__ d,
                                               float* __restrict__ partial) {
    int b = blockIdx.x >> 4, g = blockIdx.x & 15;
    long long base = ((long long)b * SEQ + g * 64) * D_MODEL;
    int cw = (threadIdx.x & 63) * 8;
    int rg = threadIdx.x >> 6;
    float a[8] = {};
    for (int r = rg; r < 64; r += 4) {
        long long o = base + (long long)r * D_MODEL + cw;
        int4 hv = *(const int4*)&h[o];
        int4 dv = *(const int4*)&d[o];
        const unsigned short* hp = (const unsigned short*)&hv;
        const unsigned short* dp = (const unsigned short*)&dv;
#pragma unroll
        for (int j = 0; j < 8; ++j) a[j] += bf2f(hp[j]) + bf2f(dp[j]);
    }
    __shared__ float red[4][512];
#pragma unroll
    for (int j = 0; j < 8; ++j) red[rg][cw + j] = a[j];
    __syncthreads();
#pragma unroll
    for (int cc = 0; cc < 2; ++cc) {
        int c = threadIdx.x * 2 + cc;
        partial[(long long)blockIdx.x * D_MODEL + c] =
            red[0][c] + red[1][c] + red[2][c] + red[3][c];
    }
}

__global__ __launch_bounds__(256) void pool_s2(const float* __restrict__ partial,
                                               float* __restrict__ pooled) {
    int idx = blockIdx.x * 256 + threadIdx.x;  // 0..8191
    int b = idx >> 9, c = idx & 511;
    float s = 0.f;
#pragma unroll
    for (int g = 0; g < 16; ++g) s += partial[(long long)(b * 16 + g) * D_MODEL + c];
    pooled[idx] = s;
}

__global__ __launch_bounds__(64) void readout_kernel(const float* __restrict__ pooled,
                                                     const float* __restrict__ Wro,
                                                     const float* __restrict__ bro,
                                                     float* __restrict__ out) {
    int bo = blockIdx.x;
    int b = bo >> 1, o = bo & 1;
    int t = threadIdx.x;
    float s = 0.f;
    for (int i = t; i < D_MODEL; i += 64) s += pooled[b * D_MODEL + i] * Wro[i * 2 + o];
#pragma unroll
    for (int off = 32; off > 0; off >>= 1) s += __shfl_down(s, off);
    if (t == 0) out[b * 2 + o] = s + bro[o];
}

extern "C" void kernel_launch(void* const* d_in, const int* in_sizes, int n_in,
                              void* d_out, int out_size, void* d_ws, size_t ws_size,
                              hipStream_t stream) {
    const float* x = (const float*)d_in[0];
    const float* Wq = (const float*)d_in[1];
    const float* Wk = (const float*)d_in[2];
    const float* Wv = (const float*)d_in[3];
    const float* Wg = (const float*)d_in[4];
    const float* Wo = (const float*)d_in[5];
    const float* ln1_g = (const float*)d_in[6];
    const float* ln1_b = (const float*)d_in[7];
    const float* ln2_g = (const float*)d_in[8];
    const float* ln2_b = (const float*)d_in[9];
    const float* W1 = (const float*)d_in[10];
    const float* b1 = (const float*)d_in[11];
    const float* W2 = (const float*)d_in[12];
    const float* b2 = (const float*)d_in[13];
    const float* Wro = (const float*)d_in[14];
    const float* bro = (const float*)d_in[15];
    float* out = (float*)d_out;

    const long long NE = (long long)NROWS * D_MODEL;  // 8,388,608
    const long long dd = (long long)D_MODEL * D_MODEL;

    unsigned short* h = (unsigned short*)d_ws;   // NE
    unsigned short* y = h + NE;                  // NE
    unsigned short* qkvg = y + NE;               // 4*NE  [16384][2048]
    unsigned short* vT = qkvg + 4 * NE;          // NE    [16][512][1024]
    unsigned short* gated = vT;                  // alias (vT dead after ret GEMM)
    unsigned short* ret = vT + NE;               // NE    (also ffn-delta buffer)
    unsigned short* sg = ret + NE;               // 2*NE  scores / attn-delta / ffn-hidden
    float* pooled = (float*)(sg + 2 * NE);       // 8192 f32
    float* partial = pooled + 8192;              // 256*512 f32
    unsigned short* wts = (unsigned short*)(partial + 256 * 512);
    unsigned short* WqkvgT = wts;                          // [L][2048][512]
    unsigned short* WoT = WqkvgT + 2 * 4 * dd;             // [L][512][512]
    unsigned short* W1T = WoT + 2 * dd;                    // [L][1024][512]
    unsigned short* W2T = W1T + 2 * (long long)D_MODEL * HID;  // [L][512][1024]

    dim3 blk(256);
    conv_x<<<NE / 1024, blk, 0, stream>>>(x, h);
    wconv_all<<<dim3(16, 16, 14), blk, 0, stream>>>(Wq, Wk, Wv, Wg, Wo, W1, W2,
                                                    WqkvgT, WoT, W1T, W2T);

    for (int l = 0; l < 2; l++) {
        if (l == 0)
            ln_fuse<0><<<NROWS / 4, blk, 0, stream>>>(h, nullptr, ln1_g, ln1_b, nullptr, y);
        else
            ln_fuse<1><<<NROWS / 4, blk, 0, stream>>>(h, ret, ln1_g + l * D_MODEL,
                                                      ln1_b + l * D_MODEL, h, y);
        // qkvg = y @ [Wq|Wk|Wv|Wg]   (256² pipelined GEMM, 512 blocks)
        gemm256<0><<<512, 512, 0, stream>>>(
            (const short*)y, (const short*)(WqkvgT + (long long)l * 4 * dd), nullptr, qkvg,
            512, 512, 512, 2048, 8);
        vtrans<<<dim3(8, 16, BATCH), blk, 0, stream>>>(qkvg + 1024, vT, 2048);
        mgemm_decay<<<dim3(8, 8, BATCH), blk, 0, stream>>>(
            (const short*)qkvg, (const short*)(qkvg + 512), sg, 2048, (long long)SEQ * 2048);
        // ret = scores @ v  (K truncated at diagonal)
        mgemm<0, 64><<<dim3(8, 8, BATCH), blk, 0, stream>>>(
            (const short*)sg, (const short*)vT, nullptr, ret,
            SEQ, SEQ, SEQ, 512,
            (long long)SEQ * SEQ, (long long)D_MODEL * SEQ, (long long)SEQ * D_MODEL, 1);
        gate_bf16<<<NROWS / 4, blk, 0, stream>>>(ret, qkvg + 1536, 2048, gated);
        // attn delta = gated @ Wo  -> sg
        mgemm<0, 64><<<dim3(8, 128), blk, 0, stream>>>(
            (const short*)gated, (const short*)(WoT + l * dd), nullptr, sg,
            512, 512, 512, 512, 0, 0, 0, 0);
        // h += attn delta; y = LN2(h)
        ln_fuse<1><<<NROWS / 4, blk, 0, stream>>>(h, sg, ln2_g + l * D_MODEL,
                                                  ln2_b + l * D_MODEL, h, y);
        // hidden = gelu(y @ W1 + b1)   (256² pipelined GEMM, 256 blocks)
        gemm256<2><<<256, 512, 0, stream>>>(
            (const short*)y, (const short*)(W1T + (long long)l * D_MODEL * HID),
            b1 + l * HID, sg, 512, 512, 512, HID, 4);
        // ffn delta = hidden @ W2 + b2 -> ret buffer
        mgemm<1, 64><<<dim3(8, 128), blk, 0, stream>>>(
            (const short*)sg, (const short*)(W2T + (long long)l * HID * D_MODEL),
            b2 + l * D_MODEL, ret, HID, HID, HID, 512, 0, 0, 0, 0);
    }

    pool_s1<<<256, blk, 0, stream>>>(h, ret, partial);
    pool_s2<<<32, blk, 0, stream>>>(partial, pooled);
    readout_kernel<<<32, 64, 0, stream>>>(pooled, Wro, bro, out);
}

// Round 8
// 532.353 us; speedup vs baseline: 6.1624x; 1.0201x over previous
//
#include <hip/hip_runtime.h>
#include <hip/hip_bf16.h>

// RetNet 2-layer forward. All-bf16 dataflow.
// All MFMA GEMMs: ring-4 LDS + register-double-buffered fragments,
// ONE barrier per K-step, counted vmcnt (never 0 mid-loop), conflict-free swizzle.

#define D_MODEL 512
#define SEQ 1024
#define BATCH 16
#define NROWS (BATCH * SEQ)          // 16384
#define HID 1024
#define LOG2_GAMMA (-0.04580368961f)  // log2(0.96875)
#define KSCALE (0.044194173824f)      // 512^-0.5

typedef __attribute__((ext_vector_type(8))) short bf16x8;
typedef __attribute__((ext_vector_type(4))) float f32x4;

__device__ inline unsigned short f2bf(float x) {
    union { float f; unsigned u; } uu; uu.f = x;
    unsigned r = uu.u + 0x7fff + ((uu.u >> 16) & 1);
    return (unsigned short)(r >> 16);
}
__device__ inline float bf2f(unsigned short x) {
    union { unsigned u; float f; } uu; uu.u = ((unsigned)x) << 16; return uu.f;
}

__device__ inline void gload_lds16(const void* g, void* l) {
    __builtin_amdgcn_global_load_lds(
        (const __attribute__((address_space(1))) void*)g,
        (__attribute__((address_space(3))) void*)l, 16, 0, 0);
}

__device__ inline float sigm(float z) {
    return 1.f / (1.f + exp2f(z * -1.442695040888963f));
}
__device__ inline float gelu_fast(float x) {
    float y = 1.5957691216057308f * (x + 0.044715f * x * x * x);
    return x * sigm(y);
}

// ================== gemm256p: C[M,N] = A[M,K] @ B[N,K]^T, bf16 out ==================
// 512 thr = 8 waves (wm 2 x wn 4), wave C = 128x64. BK=32, ring-4 slots of 32KB.
template <int EPI>
__global__ __launch_bounds__(512, 2) void gemm256p(
    const short* __restrict__ A, const short* __restrict__ B,
    const float* __restrict__ bias, unsigned short* __restrict__ C,
    int K, int lda, int ldb, int ldc, int nbx) {
    __shared__ __align__(16) short smem[4 * 16384];
    const int tid = threadIdx.x;
    const int lane = tid & 63;
    const int wid = tid >> 6;
    const int wm = wid >> 2, wn = wid & 3;
    const int cpx = gridDim.x >> 3;
    const int wg = ((int)blockIdx.x & 7) * cpx + ((int)blockIdx.x >> 3);
    const int m0 = (wg / nbx) * 256;
    const int n0 = (wg % nbx) * 256;

    const int srow = tid >> 2;
    const int scol = (((tid & 3) ^ ((tid >> 3) & 3)) * 8);
    auto stage = [&](int slot, int t) {
        int k0 = t * 32;
#pragma unroll
        for (int r = 0; r < 2; ++r) {
            gload_lds16(A + (long long)(m0 + r * 128 + srow) * lda + k0 + scol,
                        &smem[slot * 16384 + r * 4096 + wid * 512]);
            gload_lds16(B + (long long)(n0 + r * 128 + srow) * ldb + k0 + scol,
                        &smem[slot * 16384 + 8192 + r * 4096 + wid * 512]);
        }
    };

    const int NT = K >> 5;
    f32x4 acc[8][4] = {};
    const int sw8 = (((lane >> 4) ^ ((lane >> 1) & 3)) * 8);
    const int aoff = (wm * 128 + (lane & 15)) * 32 + sw8;
    const int boff = 8192 + (wn * 64 + (lane & 15)) * 32 + sw8;

    bf16x8 aR0[8], bR0[4], aR1[8], bR1[4];
    stage(0, 0); stage(1, 1); stage(2, 2);
    asm volatile("s_waitcnt vmcnt(8)" ::: "memory");
    __builtin_amdgcn_s_barrier();
#pragma unroll
    for (int m = 0; m < 8; ++m) aR0[m] = *(const bf16x8*)&smem[aoff + m * 512];
#pragma unroll
    for (int n = 0; n < 4; ++n) bR0[n] = *(const bf16x8*)&smem[boff + n * 512];

#define STEP256(T, AC, BC, AN, BN2)                                                   \
    {                                                                                 \
        int t = (T);                                                                  \
        if (t + 3 < NT) stage((t + 3) & 3, t + 3);                                    \
        if (t + 3 < NT)      asm volatile("s_waitcnt vmcnt(8)" ::: "memory");         \
        else if (t + 2 < NT) asm volatile("s_waitcnt vmcnt(4)" ::: "memory");         \
        else if (t + 1 < NT) asm volatile("s_waitcnt vmcnt(0)" ::: "memory");         \
        __builtin_amdgcn_s_barrier();                                                 \
        if (t + 1 < NT) {                                                             \
            const int sb = ((t + 1) & 3) * 16384;                                     \
            _Pragma("unroll")                                                         \
            for (int m = 0; m < 8; ++m) AN[m] = *(const bf16x8*)&smem[sb + aoff + m * 512]; \
            _Pragma("unroll")                                                         \
            for (int n = 0; n < 4; ++n) BN2[n] = *(const bf16x8*)&smem[sb + boff + n * 512]; \
        }                                                                             \
        __builtin_amdgcn_s_setprio(1);                                                \
        _Pragma("unroll")                                                             \
        for (int m = 0; m < 8; ++m)                                                   \
            _Pragma("unroll")                                                         \
            for (int n = 0; n < 4; ++n)                                               \
                acc[m][n] = __builtin_amdgcn_mfma_f32_16x16x32_bf16(AC[m], BC[n], acc[m][n], 0, 0, 0); \
        __builtin_amdgcn_s_setprio(0);                                                \
        asm volatile("s_waitcnt lgkmcnt(0)" ::: "memory");                            \
        __builtin_amdgcn_sched_barrier(0);                                            \
    }

    for (int tt = 0; tt < NT; tt += 2) {
        STEP256(tt, aR0, bR0, aR1, bR1)
        STEP256(tt + 1, aR1, bR1, aR0, bR0)
    }
#undef STEP256

    // ---- epilogue via LDS, vector stores ----
    const int ocol = lane & 15;
    const int orow4 = (lane >> 4) * 4;
    float bv[4];
    if (EPI == 2) {
#pragma unroll
        for (int n = 0; n < 4; ++n) bv[n] = bias[n0 + wn * 64 + n * 16 + ocol];
    }
#pragma unroll 1
    for (int half = 0; half < 2; ++half) {
        __syncthreads();
        if (wm == half) {
#pragma unroll
            for (int m = 0; m < 8; ++m)
#pragma unroll
                for (int n = 0; n < 4; ++n)
#pragma unroll
                    for (int rj = 0; rj < 4; ++rj) {
                        int lr = m * 16 + orow4 + rj;
                        int lc = wn * 64 + n * 16 + ocol;
                        float v = acc[m][n][rj];
                        if (EPI == 2) v = gelu_fast(v + bv[n]);
                        smem[lr * 256 + lc] = (short)f2bf(v);
                    }
        }
        __syncthreads();
#pragma unroll
        for (int p = 0; p < 8; ++p) {
            int s = p * 512 + tid;
            int row = s >> 5;
            int cc = (s & 31) * 8;
            *(int4*)&C[(long long)(m0 + half * 128 + row) * ldc + n0 + cc] =
                *(const int4*)&smem[row * 256 + cc];
        }
    }
}

// ================== pgemm64: BM=128, BN=64, 4 waves, ring-4 (48KB) ==================
// EPI: 0 plain, 1 acc+bias, 2 gelu(acc+bias). tri!=0: K truncated at m0+128.
template <int EPI>
__global__ __launch_bounds__(256, 4) void pgemm64(
    const short* __restrict__ A, const short* __restrict__ B,
    const float* __restrict__ bias, unsigned short* __restrict__ C,
    int K, int lda, int ldb, int ldc,
    long long sA, long long sB, long long sC, int tri) {
    __shared__ __align__(16) short smem[4 * 6144];
    const int tid = threadIdx.x;
    const int lane = tid & 63;
    const int wid = tid >> 6;
    const int wr = wid;                    // wave rows: wr*32
    const int m0 = blockIdx.y * 128, n0 = blockIdx.x * 64;
    A += (long long)blockIdx.z * sA;
    B += (long long)blockIdx.z * sB;

    int Keff = K;
    if (tri) { int km = m0 + 128; if (km < Keff) Keff = km; }
    const int NT = Keff >> 5;

    auto stage = [&](int slot, int t) {
        int k0 = t * 32;
#pragma unroll
        for (int it = 0; it < 2; ++it) {
            int c = it * 256 + tid;
            int rr = c >> 2;
            int cc = ((c & 3) ^ ((c >> 3) & 3)) * 8;
            gload_lds16(A + (long long)(m0 + rr) * lda + k0 + cc,
                        &smem[slot * 6144 + (it * 256 + wid * 64) * 8]);
        }
        {
            int c = tid;
            int rr = c >> 2;
            int cc = ((c & 3) ^ ((c >> 3) & 3)) * 8;
            gload_lds16(B + (long long)(n0 + rr) * ldb + k0 + cc,
                        &smem[slot * 6144 + 4096 + (wid * 64) * 8]);
        }
    };

    f32x4 acc[2][4] = {};
    const int sw8 = (((lane >> 4) ^ ((lane >> 1) & 3)) * 8);
    const int aoff = (wr * 32 + (lane & 15)) * 32 + sw8;
    const int boff = 4096 + ((lane & 15)) * 32 + sw8;

    bf16x8 aR0[2], bR0[4], aR1[2], bR1[4];
    stage(0, 0); stage(1, 1); stage(2, 2);
    asm volatile("s_waitcnt vmcnt(6)" ::: "memory");
    __builtin_amdgcn_s_barrier();
#pragma unroll
    for (int m = 0; m < 2; ++m) aR0[m] = *(const bf16x8*)&smem[aoff + m * 512];
#pragma unroll
    for (int n = 0; n < 4; ++n) bR0[n] = *(const bf16x8*)&smem[boff + n * 512];

#define STEP64(T, AC, BC, AN, BN2)                                                    \
    {                                                                                 \
        int t = (T);                                                                  \
        if (t + 3 < NT) stage((t + 3) & 3, t + 3);                                    \
        if (t + 3 < NT)      asm volatile("s_waitcnt vmcnt(6)" ::: "memory");         \
        else if (t + 2 < NT) asm volatile("s_waitcnt vmcnt(3)" ::: "memory");         \
        else if (t + 1 < NT) asm volatile("s_waitcnt vmcnt(0)" ::: "memory");         \
        __builtin_amdgcn_s_barrier();                                                 \
        if (t + 1 < NT) {                                                             \
            const int sb = ((t + 1) & 3) * 6144;                                      \
            _Pragma("unroll")                                                         \
            for (int m = 0; m < 2; ++m) AN[m] = *(const bf16x8*)&smem[sb + aoff + m * 512]; \
            _Pragma("unroll")                                                         \
            for (int n = 0; n < 4; ++n) BN2[n] = *(const bf16x8*)&smem[sb + boff + n * 512]; \
        }                                                                             \
        __builtin_amdgcn_s_setprio(1);                                                \
        _Pragma("unroll")                                                             \
        for (int m = 0; m < 2; ++m)                                                   \
            _Pragma("unroll")                                                         \
            for (int n = 0; n < 4; ++n)                                               \
                acc[m][n] = __builtin_amdgcn_mfma_f32_16x16x32_bf16(AC[m], BC[n], acc[m][n], 0, 0, 0); \
        __builtin_amdgcn_s_setprio(0);                                                \
        asm volatile("s_waitcnt lgkmcnt(0)" ::: "memory");                            \
        __builtin_amdgcn_sched_barrier(0);                                            \
    }

    for (int tt = 0; tt < NT; tt += 2) {
        STEP64(tt, aR0, bR0, aR1, bR1)
        STEP64(tt + 1, aR1, bR1, aR0, bR0)
    }
#undef STEP64

    __syncthreads();
    const int orow = (lane >> 4) * 4;
    const int ocol = lane & 15;
    float bv[4];
    if (EPI >= 1) {
#pragma unroll
        for (int j = 0; j < 4; ++j) bv[j] = bias[n0 + j * 16 + ocol];
    }
#pragma unroll
    for (int i = 0; i < 2; ++i)
#pragma unroll
        for (int j = 0; j < 4; ++j)
#pragma unroll
            for (int rj = 0; rj < 4; ++rj) {
                int lrow = wr * 32 + i * 16 + orow + rj;
                int lcol = j * 16 + ocol;
                float val = acc[i][j][rj];
                if (EPI == 1) val += bv[j];
                if (EPI == 2) val = gelu_fast(val + bv[j]);
                smem[lrow * 64 + lcol] = (short)f2bf(val);
            }
    __syncthreads();
    const long long zoff = (long long)blockIdx.z * sC;
#pragma unroll
    for (int p = 0; p < 4; ++p) {
        int s = p * 256 + tid;
        int row = s >> 3;
        int cc = (s & 7) * 8;
        *(int4*)&C[zoff + (long long)(m0 + row) * ldc + n0 + cc] = *(const int4*)&smem[row * 64 + cc];
    }
}

// ====== pdecay: scores = (q k^T) * gamma^(n-m) * KSCALE, 128x128, ring-4 (64KB) ======
__global__ __launch_bounds__(256, 2) void pdecay(
    const short* __restrict__ Q, const short* __restrict__ Kp,
    unsigned short* __restrict__ S, int lda, long long sA) {
    if (blockIdx.x > blockIdx.y) return;
    const int q0 = blockIdx.y * 128;
    const int c0 = blockIdx.x * 128;
    unsigned short* Sb = S + (long long)blockIdx.z * SEQ * SEQ;
    __shared__ __align__(16) short smem[4 * 8192];
    const int tid = threadIdx.x;
    const int lane = tid & 63;
    const int wid = tid >> 6;
    const int wr = wid >> 1, wc = wid & 1;
    const short* Ab = Q + (long long)blockIdx.z * sA;
    const short* Bb = Kp + (long long)blockIdx.z * sA;

    auto stage = [&](int slot, int t) {
        int k0 = t * 32;
#pragma unroll
        for (int it = 0; it < 2; ++it) {
            int c = it * 256 + tid;
            int rr = c >> 2;
            int cc = ((c & 3) ^ ((c >> 3) & 3)) * 8;
            gload_lds16(Ab + (long long)(q0 + rr) * lda + k0 + cc,
                        &smem[slot * 8192 + (it * 256 + wid * 64) * 8]);
            gload_lds16(Bb + (long long)(c0 + rr) * lda + k0 + cc,
                        &smem[slot * 8192 + 4096 + (it * 256 + wid * 64) * 8]);
        }
    };

    const int NT = D_MODEL / 32;   // 16
    f32x4 acc[4][4] = {};
    const int sw8 = (((lane >> 4) ^ ((lane >> 1) & 3)) * 8);
    const int aoff = (wr * 64 + (lane & 15)) * 32 + sw8;
    const int boff = 4096 + (wc * 64 + (lane & 15)) * 32 + sw8;

    bf16x8 aR0[4], bR0[4], aR1[4], bR1[4];
    stage(0, 0); stage(1, 1); stage(2, 2);
    asm volatile("s_waitcnt vmcnt(8)" ::: "memory");
    __builtin_amdgcn_s_barrier();
#pragma unroll
    for (int m = 0; m < 4; ++m) aR0[m] = *(const bf16x8*)&smem[aoff + m * 512];
#pragma unroll
    for (int n = 0; n < 4; ++n) bR0[n] = *(const bf16x8*)&smem[boff + n * 512];

#define STEPD(T, AC, BC, AN, BN2)                                                     \
    {                                                                                 \
        int t = (T);                                                                  \
        if (t + 3 < NT) stage((t + 3) & 3, t + 3);                                    \
        if (t + 3 < NT)      asm volatile("s_waitcnt vmcnt(8)" ::: "memory");         \
        else if (t + 2 < NT) asm volatile("s_waitcnt vmcnt(4)" ::: "memory");         \
        else if (t + 1 < NT) asm volatile("s_waitcnt vmcnt(0)" ::: "memory");         \
        __builtin_amdgcn_s_barrier();                                                 \
        if (t + 1 < NT) {                                                             \
            const int sb = ((t + 1) & 3) * 8192;                                      \
            _Pragma("unroll")                                                         \
            for (int m = 0; m < 4; ++m) AN[m] = *(const bf16x8*)&smem[sb + aoff + m * 512]; \
            _Pragma("unroll")                                                         \
            for (int n = 0; n < 4; ++n) BN2[n] = *(const bf16x8*)&smem[sb + boff + n * 512]; \
        }                                                                             \
        __builtin_amdgcn_s_setprio(1);                                                \
        _Pragma("unroll")                                                             \
        for (int m = 0; m < 4; ++m)                                                   \
            _Pragma("unroll")                                                         \
            for (int n = 0; n < 4; ++n)                                               \
                acc[m][n] = __builtin_amdgcn_mfma_f32_16x16x32_bf16(AC[m], BC[n], acc[m][n], 0, 0, 0); \
        __builtin_amdgcn_s_setprio(0);                                                \
        asm volatile("s_waitcnt lgkmcnt(0)" ::: "memory");                            \
        __builtin_amdgcn_sched_barrier(0);                                            \
    }

    for (int tt = 0; tt < NT; tt += 2) {
        STEPD(tt, aR0, bR0, aR1, bR1)
        STEPD(tt + 1, aR1, bR1, aR0, bR0)
    }
#undef STEPD

    __syncthreads();
    const int orow = (lane >> 4) * 4;
    const int ocol = lane & 15;
#pragma unroll
    for (int i = 0; i < 4; ++i)
#pragma unroll
        for (int j = 0; j < 4; ++j)
#pragma unroll
            for (int rj = 0; rj < 4; ++rj) {
                int lrow = wr * 64 + i * 16 + orow + rj;
                int lcol = wc * 64 + j * 16 + ocol;
                int n = q0 + lrow, m = c0 + lcol;
                float w = (n >= m) ? exp2f((float)(n - m) * LOG2_GAMMA) * KSCALE : 0.f;
                smem[lrow * 128 + lcol] = (short)f2bf(acc[i][j][rj] * w);
            }
    __syncthreads();
#pragma unroll
    for (int p = 0; p < 8; ++p) {
        int s = p * 256 + tid;
        int row = s >> 4;
        int cc = (s & 15) * 8;
        *(int4*)&Sb[(long long)(q0 + row) * SEQ + c0 + cc] = *(const int4*)&smem[row * 128 + cc];
    }
}

// ============ fused weight convert+transpose ============
__global__ __launch_bounds__(256) void wconv_all(
    const float* __restrict__ Wq, const float* __restrict__ Wk,
    const float* __restrict__ Wv, const float* __restrict__ Wg,
    const float* __restrict__ Wo, const float* __restrict__ W1,
    const float* __restrict__ W2,
    unsigned short* __restrict__ WqkvgT, unsigned short* __restrict__ WoT,
    unsigned short* __restrict__ W1T, unsigned short* __restrict__ W2T) {
    const long long dd = 512LL * 512;
    int z = blockIdx.z;
    int l = z / 7, w = z % 7;
    const float* src; unsigned short* dst; int K, N;
    switch (w) {
        case 0: src = Wq + l * dd; dst = WqkvgT + (long long)l * 4 * dd; K = 512; N = 512; break;
        case 1: src = Wk + l * dd; dst = WqkvgT + (long long)l * 4 * dd + dd; K = 512; N = 512; break;
        case 2: src = Wv + l * dd; dst = WqkvgT + (long long)l * 4 * dd + 2 * dd; K = 512; N = 512; break;
        case 3: src = Wg + l * dd; dst = WqkvgT + (long long)l * 4 * dd + 3 * dd; K = 512; N = 512; break;
        case 4: src = Wo + l * dd; dst = WoT + l * dd; K = 512; N = 512; break;
        case 5: src = W1 + (long long)l * 512 * 1024; dst = W1T + (long long)l * 512 * 1024; K = 512; N = 1024; break;
        default: src = W2 + (long long)l * 1024 * 512; dst = W2T + (long long)l * 1024 * 512; K = 1024; N = 512; break;
    }
    if ((int)blockIdx.x >= N / 64 || (int)blockIdx.y >= K / 64) return;
    __shared__ unsigned short t[64][65];
    int n0 = blockIdx.x * 64, k0 = blockIdx.y * 64;
    int tx = threadIdx.x & 63, ty = threadIdx.x >> 6;
#pragma unroll
    for (int i = 0; i < 16; ++i)
        t[ty + i * 4][tx] = f2bf(src[(long long)(k0 + ty + i * 4) * N + n0 + tx]);
    __syncthreads();
#pragma unroll
    for (int i = 0; i < 16; ++i)
        dst[(long long)(n0 + ty + i * 4) * K + k0 + tx] = t[tx][ty + i * 4];
}

// ============ per-batch transpose: bf16 [SEQ][*stride slice] -> [D][SEQ] ============
__global__ __launch_bounds__(256) void vtrans(const unsigned short* __restrict__ in,
                                              unsigned short* __restrict__ out, int istride) {
    __shared__ unsigned short t[64][65];
    const unsigned short* pin = in + (long long)blockIdx.z * SEQ * istride;
    unsigned short* pout = out + (long long)blockIdx.z * D_MODEL * SEQ;
    int c0 = blockIdx.x * 64, r0 = blockIdx.y * 64;
    int tx = threadIdx.x & 63, ty = threadIdx.x >> 6;
#pragma unroll
    for (int i = 0; i < 16; ++i)
        t[ty + i * 4][tx] = pin[(long long)(r0 + ty + i * 4) * istride + c0 + tx];
    __syncthreads();
#pragma unroll
    for (int i = 0; i < 16; ++i)
        pout[(long long)(c0 + ty + i * 4) * SEQ + r0 + tx] = t[tx][ty + i * 4];
}

// ============ x (f32) -> h (bf16) ============
__global__ __launch_bounds__(256) void conv_x(const float* __restrict__ x,
                                              unsigned short* __restrict__ h) {
    int i = blockIdx.x * 256 + threadIdx.x;
    float4 v = ((const float4*)x)[i];
    ushort4 o;
    o.x = f2bf(v.x); o.y = f2bf(v.y); o.z = f2bf(v.z); o.w = f2bf(v.w);
    ((ushort4*)h)[i] = o;
}

// ============ fused residual-add + LayerNorm, all bf16 ============
template <int MODE>
__global__ __launch_bounds__(256) void ln_fuse(
    const unsigned short* __restrict__ hin,
    const unsigned short* __restrict__ delta,
    const float* __restrict__ g, const float* __restrict__ b,
    unsigned short* __restrict__ hout,
    unsigned short* __restrict__ y) {
    int row = blockIdx.x * 4 + (threadIdx.x >> 6);
    int t = threadIdx.x & 63;
    int4 hv = ((const int4*)(hin + (long long)row * D_MODEL))[t];
    const unsigned short* hu = (const unsigned short*)&hv;
    float f[8];
#pragma unroll
    for (int k = 0; k < 8; ++k) f[k] = bf2f(hu[k]);
    if (MODE == 1) {
        int4 dv = ((const int4*)(delta + (long long)row * D_MODEL))[t];
        const unsigned short* du = (const unsigned short*)&dv;
#pragma unroll
        for (int k = 0; k < 8; ++k) f[k] += bf2f(du[k]);
    }
    float s = 0.f, s2 = 0.f;
#pragma unroll
    for (int k = 0; k < 8; ++k) { s += f[k]; s2 += f[k] * f[k]; }
#pragma unroll
    for (int off = 32; off > 0; off >>= 1) {
        s += __shfl_down(s, off);
        s2 += __shfl_down(s2, off);
    }
    s = __shfl(s, 0); s2 = __shfl(s2, 0);
    float mu = s * (1.f / D_MODEL);
    float var = s2 * (1.f / D_MODEL) - mu * mu;
    float rs = rsqrtf(var + 1e-6f);
    if (MODE == 1) {
        ushort4 ho[2];
        unsigned short* hp = (unsigned short*)ho;
#pragma unroll
        for (int k = 0; k < 8; ++k) hp[k] = f2bf(f[k]);
        ((int4*)(hout + (long long)row * D_MODEL))[t] = *(int4*)ho;
    }
    const float4* g4 = (const float4*)g;
    const float4* b4 = (const float4*)b;
    float4 ga = g4[2 * t], gb2 = g4[2 * t + 1];
    float4 ba = b4[2 * t], bb2 = b4[2 * t + 1];
    float gg[8] = {ga.x, ga.y, ga.z, ga.w, gb2.x, gb2.y, gb2.z, gb2.w};
    float bb[8] = {ba.x, ba.y, ba.z, ba.w, bb2.x, bb2.y, bb2.z, bb2.w};
    ushort4 yo[2];
    unsigned short* yp = (unsigned short*)yo;
#pragma unroll
    for (int k = 0; k < 8; ++k) yp[k] = f2bf((f[k] - mu) * rs * gg[k] + bb[k]);
    ((int4*)(y + (long long)row * D_MODEL))[t] = *(int4*)yo;
}

// ============ gated = silu(g) * groupnorm(ret), all bf16 (g strided) ============
__global__ __launch_bounds__(256) void gate_bf16(const unsigned short* __restrict__ ret,
                                                 const unsigned short* __restrict__ g,
                                                 int gstride,
                                                 unsigned short* __restrict__ out) {
    int row = blockIdx.x * 4 + (threadIdx.x >> 6);
    int t = threadIdx.x & 63;
    int4 rv4 = ((const int4*)(ret + (long long)row * D_MODEL))[t];
    const unsigned short* ru = (const unsigned short*)&rv4;
    float f[8];
#pragma unroll
    for (int k = 0; k < 8; ++k) f[k] = bf2f(ru[k]);
    float s = 0.f, s2 = 0.f;
#pragma unroll
    for (int k = 0; k < 8; ++k) { s += f[k]; s2 += f[k] * f[k]; }
#pragma unroll
    for (int off = 32; off > 0; off >>= 1) {
        s += __shfl_down(s, off);
        s2 += __shfl_down(s2, off);
    }
    s = __shfl(s, 0); s2 = __shfl(s2, 0);
    float mu = s * (1.f / D_MODEL);
    float var = s2 * (1.f / D_MODEL) - mu * mu;
    float rs = rsqrtf(var + 1e-6f);
    int4 gv4 = ((const int4*)(g + (long long)row * gstride))[t];
    const unsigned short* gu = (const unsigned short*)&gv4;
    ushort4 o[2];
    unsigned short* op = (unsigned short*)o;
#pragma unroll
    for (int k = 0; k < 8; ++k) {
        float x = bf2f(gu[k]);
        op[k] = f2bf(x * sigm(x) * (f[k] - mu) * rs);
    }
    ((int4*)(out + (long long)row * D_MODEL))[t] = *(int4*)o;
}

// ============ pooled = sum_rows (h + dlast): two-stage ============
__global__ __launch_bounds__(256) void pool_s1(const unsigned short* __restrict__ h,
                                               const unsigned short* __restrict__ d,
                                               float* __restrict__ partial) {
    int b = blockIdx.x >> 4, g = blockIdx.x & 15;
    long long base = ((long long)b * SEQ + g * 64) * D_MODEL;
    int cw = (threadIdx.x & 63) * 8;
    int rg = threadIdx.x >> 6;
    float a[8] = {};
    for (int r = rg; r < 64; r += 4) {
        long long o = base + (long long)r * D_MODEL + cw;
        int4 hv = *(const int4*)&h[o];
        int4 dv = *(const int4*)&d[o];
        const unsigned short* hp = (const unsigned short*)&hv;
        const unsigned short* dp = (const unsigned short*)&dv;
#pragma unroll
        for (int j = 0; j < 8; ++j) a[j] += bf2f(hp[j]) + bf2f(dp[j]);
    }
    __shared__ float red[4][512];
#pragma unroll
    for (int j = 0; j < 8; ++j) red[rg][cw + j] = a[j];
    __syncthreads();
#pragma unroll
    for (int cc = 0; cc < 2; ++cc) {
        int c = threadIdx.x * 2 + cc;
        partial[(long long)blockIdx.x * D_MODEL + c] =
            red[0][c] + red[1][c] + red[2][c] + red[3][c];
    }
}

__global__ __launch_bounds__(256) void pool_s2(const float* __restrict__ partial,
                                               float* __restrict__ pooled) {
    int idx = blockIdx.x * 256 + threadIdx.x;  // 0..8191
    int b = idx >> 9, c = idx & 511;
    float s = 0.f;
#pragma unroll
    for (int g = 0; g < 16; ++g) s += partial[(long long)(b * 16 + g) * D_MODEL + c];
    pooled[idx] = s;
}

__global__ __launch_bounds__(64) void readout_kernel(const float* __restrict__ pooled,
                                                     const float* __restrict__ Wro,
                                                     const float* __restrict__ bro,
                                                     float* __restrict__ out) {
    int bo = blockIdx.x;
    int b = bo >> 1, o = bo & 1;
    int t = threadIdx.x;
    float s = 0.f;
    for (int i = t; i < D_MODEL; i += 64) s += pooled[b * D_MODEL + i] * Wro[i * 2 + o];
#pragma unroll
    for (int off = 32; off > 0; off >>= 1) s += __shfl_down(s, off);
    if (t == 0) out[b * 2 + o] = s + bro[o];
}

extern "C" void kernel_launch(void* const* d_in, const int* in_sizes, int n_in,
                              void* d_out, int out_size, void* d_ws, size_t ws_size,
                              hipStream_t stream) {
    const float* x = (const float*)d_in[0];
    const float* Wq = (const float*)d_in[1];
    const float* Wk = (const float*)d_in[2];
    const float* Wv = (const float*)d_in[3];
    const float* Wg = (const float*)d_in[4];
    const float* Wo = (const float*)d_in[5];
    const float* ln1_g = (const float*)d_in[6];
    const float* ln1_b = (const float*)d_in[7];
    const float* ln2_g = (const float*)d_in[8];
    const float* ln2_b = (const float*)d_in[9];
    const float* W1 = (const float*)d_in[10];
    const float* b1 = (const float*)d_in[11];
    const float* W2 = (const float*)d_in[12];
    const float* b2 = (const float*)d_in[13];
    const float* Wro = (const float*)d_in[14];
    const float* bro = (const float*)d_in[15];
    float* out = (float*)d_out;

    const long long NE = (long long)NROWS * D_MODEL;  // 8,388,608
    const long long dd = (long long)D_MODEL * D_MODEL;

    unsigned short* h = (unsigned short*)d_ws;   // NE
    unsigned short* y = h + NE;                  // NE
    unsigned short* qkvg = y + NE;               // 4*NE  [16384][2048]
    unsigned short* vT = qkvg + 4 * NE;          // NE    [16][512][1024]
    unsigned short* gated = vT;                  // alias (vT dead after ret GEMM)
    unsigned short* ret = vT + NE;               // NE    (also ffn-delta buffer)
    unsigned short* sg = ret + NE;               // 2*NE  scores / attn-delta / ffn-hidden
    float* pooled = (float*)(sg + 2 * NE);       // 8192 f32
    float* partial = pooled + 8192;              // 256*512 f32
    unsigned short* wts = (unsigned short*)(partial + 256 * 512);
    unsigned short* WqkvgT = wts;                          // [L][2048][512]
    unsigned short* WoT = WqkvgT + 2 * 4 * dd;             // [L][512][512]
    unsigned short* W1T = WoT + 2 * dd;                    // [L][1024][512]
    unsigned short* W2T = W1T + 2 * (long long)D_MODEL * HID;  // [L][512][1024]

    dim3 blk(256);
    conv_x<<<NE / 1024, blk, 0, stream>>>(x, h);
    wconv_all<<<dim3(16, 16, 14), blk, 0, stream>>>(Wq, Wk, Wv, Wg, Wo, W1, W2,
                                                    WqkvgT, WoT, W1T, W2T);

    for (int l = 0; l < 2; l++) {
        if (l == 0)
            ln_fuse<0><<<NROWS / 4, blk, 0, stream>>>(h, nullptr, ln1_g, ln1_b, nullptr, y);
        else
            ln_fuse<1><<<NROWS / 4, blk, 0, stream>>>(h, ret, ln1_g + l * D_MODEL,
                                                      ln1_b + l * D_MODEL, h, y);
        // qkvg = y @ [Wq|Wk|Wv|Wg]
        gemm256p<0><<<512, 512, 0, stream>>>(
            (const short*)y, (const short*)(WqkvgT + (long long)l * 4 * dd), nullptr, qkvg,
            512, 512, 512, 2048, 8);
        vtrans<<<dim3(8, 16, BATCH), blk, 0, stream>>>(qkvg + 1024, vT, 2048);
        pdecay<<<dim3(8, 8, BATCH), blk, 0, stream>>>(
            (const short*)qkvg, (const short*)(qkvg + 512), sg, 2048, (long long)SEQ * 2048);
        // ret = scores @ v  (K truncated at diagonal)
        pgemm64<0><<<dim3(8, 8, BATCH), blk, 0, stream>>>(
            (const short*)sg, (const short*)vT, nullptr, ret,
            SEQ, SEQ, SEQ, 512,
            (long long)SEQ * SEQ, (long long)D_MODEL * SEQ, (long long)SEQ * D_MODEL, 1);
        gate_bf16<<<NROWS / 4, blk, 0, stream>>>(ret, qkvg + 1536, 2048, gated);
        // attn delta = gated @ Wo  -> sg
        pgemm64<0><<<dim3(8, 128), blk, 0, stream>>>(
            (const short*)gated, (const short*)(WoT + l * dd), nullptr, sg,
            512, 512, 512, 512, 0, 0, 0, 0);
        // h += attn delta; y = LN2(h)
        ln_fuse<1><<<NROWS / 4, blk, 0, stream>>>(h, sg, ln2_g + l * D_MODEL,
                                                  ln2_b + l * D_MODEL, h, y);
        // hidden = gelu(y @ W1 + b1)
        gemm256p<2><<<256, 512, 0, stream>>>(
            (const short*)y, (const short*)(W1T + (long long)l * D_MODEL * HID),
            b1 + l * HID, sg, 512, 512, 512, HID, 4);
        // ffn delta = hidden @ W2 + b2 -> ret buffer
        pgemm64<1><<<dim3(8, 128), blk, 0, stream>>>(
            (const short*)sg, (const short*)(W2T + (long long)l * HID * D_MODEL),
            b2 + l * D_MODEL, ret, HID, HID, HID, 512, 0, 0, 0, 0);
    }

    pool_s1<<<256, blk, 0, stream>>>(h, ret, partial);
    pool_s2<<<32, blk, 0, stream>>>(partial, pooled);
    readout_kernel<<<32, 64, 0, stream>>>(pooled, Wro, bro, out);
}

// Round 9
// 526.609 us; speedup vs baseline: 6.2296x; 1.0109x over previous
//
#include <hip/hip_runtime.h>
#include <hip/hip_bf16.h>

// RetNet 2-layer forward. All-bf16 dataflow.
// MFMA GEMMs: ring-4 LDS, one barrier/K-step, counted vmcnt, conflict-free swizzle,
// and per-step READ||MFMA interleave (4 sub-groups pinned by sched_barrier).

#define D_MODEL 512
#define SEQ 1024
#define BATCH 16
#define NROWS (BATCH * SEQ)          // 16384
#define HID 1024
#define LOG2_GAMMA (-0.04580368961f)  // log2(0.96875)
#define KSCALE (0.044194173824f)      // 512^-0.5

typedef __attribute__((ext_vector_type(8))) short bf16x8;
typedef __attribute__((ext_vector_type(4))) float f32x4;

__device__ inline unsigned short f2bf(float x) {
    union { float f; unsigned u; } uu; uu.f = x;
    unsigned r = uu.u + 0x7fff + ((uu.u >> 16) & 1);
    return (unsigned short)(r >> 16);
}
__device__ inline float bf2f(unsigned short x) {
    union { unsigned u; float f; } uu; uu.u = ((unsigned)x) << 16; return uu.f;
}

__device__ inline void gload_lds16(const void* g, void* l) {
    __builtin_amdgcn_global_load_lds(
        (const __attribute__((address_space(1))) void*)g,
        (__attribute__((address_space(3))) void*)l, 16, 0, 0);
}

__device__ inline float sigm(float z) {
    return 1.f / (1.f + exp2f(z * -1.442695040888963f));
}
__device__ inline float gelu_fast(float x) {
    float y = 1.5957691216057308f * (x + 0.044715f * x * x * x);
    return x * sigm(y);
}

// ================== gemm256p: C[M,N] = A[M,K] @ B[N,K]^T, bf16 out ==================
template <int EPI>
__global__ __launch_bounds__(512, 2) void gemm256p(
    const short* __restrict__ A, const short* __restrict__ B,
    const float* __restrict__ bias, unsigned short* __restrict__ C,
    int K, int lda, int ldb, int ldc, int nbx) {
    __shared__ __align__(16) short smem[4 * 16384];
    const int tid = threadIdx.x;
    const int lane = tid & 63;
    const int wid = tid >> 6;
    const int wm = wid >> 2, wn = wid & 3;
    const int cpx = gridDim.x >> 3;
    const int wg = ((int)blockIdx.x & 7) * cpx + ((int)blockIdx.x >> 3);
    const int m0 = (wg / nbx) * 256;
    const int n0 = (wg % nbx) * 256;

    const int srow = tid >> 2;
    const int scol = (((tid & 3) ^ ((tid >> 3) & 3)) * 8);
    auto stage = [&](int slot, int t) {
        int k0 = t * 32;
#pragma unroll
        for (int r = 0; r < 2; ++r) {
            gload_lds16(A + (long long)(m0 + r * 128 + srow) * lda + k0 + scol,
                        &smem[slot * 16384 + r * 4096 + wid * 512]);
            gload_lds16(B + (long long)(n0 + r * 128 + srow) * ldb + k0 + scol,
                        &smem[slot * 16384 + 8192 + r * 4096 + wid * 512]);
        }
    };

    const int NT = K >> 5;
    f32x4 acc[8][4] = {};
    const int sw8 = (((lane >> 4) ^ ((lane >> 1) & 3)) * 8);
    const int aoff = (wm * 128 + (lane & 15)) * 32 + sw8;
    const int boff = 8192 + (wn * 64 + (lane & 15)) * 32 + sw8;

    bf16x8 aR0[8], bR0[4], aR1[8], bR1[4];
    stage(0, 0); stage(1, 1); stage(2, 2);
    asm volatile("s_waitcnt vmcnt(8)" ::: "memory");
    __builtin_amdgcn_s_barrier();
#pragma unroll
    for (int m = 0; m < 8; ++m) aR0[m] = *(const bf16x8*)&smem[aoff + m * 512];
#pragma unroll
    for (int n = 0; n < 4; ++n) bR0[n] = *(const bf16x8*)&smem[boff + n * 512];

#define STEP256(T, AC, BC, AN, BN2)                                                   \
    {                                                                                 \
        int t = (T);                                                                  \
        if (t + 3 < NT) stage((t + 3) & 3, t + 3);                                    \
        if (t + 3 < NT)      asm volatile("s_waitcnt vmcnt(8)" ::: "memory");         \
        else if (t + 2 < NT) asm volatile("s_waitcnt vmcnt(4)" ::: "memory");         \
        else if (t + 1 < NT) asm volatile("s_waitcnt vmcnt(0)" ::: "memory");         \
        __builtin_amdgcn_s_barrier();                                                 \
        const int sb = ((t + 1) & 3) * 16384;                                         \
        const bool pre = (t + 1 < NT);                                                \
        _Pragma("unroll")                                                             \
        for (int q = 0; q < 4; ++q) {                                                 \
            if (pre) {                                                                \
                AN[2 * q] = *(const bf16x8*)&smem[sb + aoff + (2 * q) * 512];          \
                AN[2 * q + 1] = *(const bf16x8*)&smem[sb + aoff + (2 * q + 1) * 512];  \
                BN2[q] = *(const bf16x8*)&smem[sb + boff + q * 512];                   \
            }                                                                         \
            __builtin_amdgcn_s_setprio(1);                                            \
            _Pragma("unroll")                                                         \
            for (int n = 0; n < 4; ++n) {                                             \
                acc[2 * q][n] = __builtin_amdgcn_mfma_f32_16x16x32_bf16(AC[2 * q], BC[n], acc[2 * q][n], 0, 0, 0); \
                acc[2 * q + 1][n] = __builtin_amdgcn_mfma_f32_16x16x32_bf16(AC[2 * q + 1], BC[n], acc[2 * q + 1][n], 0, 0, 0); \
            }                                                                         \
            __builtin_amdgcn_s_setprio(0);                                            \
            __builtin_amdgcn_sched_barrier(0);                                        \
        }                                                                             \
        asm volatile("s_waitcnt lgkmcnt(0)" ::: "memory");                            \
        __builtin_amdgcn_sched_barrier(0);                                            \
    }

    for (int tt = 0; tt < NT; tt += 2) {
        STEP256(tt, aR0, bR0, aR1, bR1)
        STEP256(tt + 1, aR1, bR1, aR0, bR0)
    }
#undef STEP256

    // ---- epilogue via LDS, vector stores ----
    const int ocol = lane & 15;
    const int orow4 = (lane >> 4) * 4;
    float bv[4];
    if (EPI == 2) {
#pragma unroll
        for (int n = 0; n < 4; ++n) bv[n] = bias[n0 + wn * 64 + n * 16 + ocol];
    }
#pragma unroll 1
    for (int half = 0; half < 2; ++half) {
        __syncthreads();
        if (wm == half) {
#pragma unroll
            for (int m = 0; m < 8; ++m)
#pragma unroll
                for (int n = 0; n < 4; ++n)
#pragma unroll
                    for (int rj = 0; rj < 4; ++rj) {
                        int lr = m * 16 + orow4 + rj;
                        int lc = wn * 64 + n * 16 + ocol;
                        float v = acc[m][n][rj];
                        if (EPI == 2) v = gelu_fast(v + bv[n]);
                        smem[lr * 256 + lc] = (short)f2bf(v);
                    }
        }
        __syncthreads();
#pragma unroll
        for (int p = 0; p < 8; ++p) {
            int s = p * 512 + tid;
            int row = s >> 5;
            int cc = (s & 31) * 8;
            *(int4*)&C[(long long)(m0 + half * 128 + row) * ldc + n0 + cc] =
                *(const int4*)&smem[row * 256 + cc];
        }
    }
}

// ================== pgemm64: BM=128, BN=64, 4 waves, ring-4 (48KB) ==================
template <int EPI>
__global__ __launch_bounds__(256, 4) void pgemm64(
    const short* __restrict__ A, const short* __restrict__ B,
    const float* __restrict__ bias, unsigned short* __restrict__ C,
    int K, int lda, int ldb, int ldc,
    long long sA, long long sB, long long sC, int tri) {
    __shared__ __align__(16) short smem[4 * 6144];
    const int tid = threadIdx.x;
    const int lane = tid & 63;
    const int wid = tid >> 6;
    const int wr = wid;
    const int m0 = blockIdx.y * 128, n0 = blockIdx.x * 64;
    A += (long long)blockIdx.z * sA;
    B += (long long)blockIdx.z * sB;

    int Keff = K;
    if (tri) { int km = m0 + 128; if (km < Keff) Keff = km; }
    const int NT = Keff >> 5;

    auto stage = [&](int slot, int t) {
        int k0 = t * 32;
#pragma unroll
        for (int it = 0; it < 2; ++it) {
            int c = it * 256 + tid;
            int rr = c >> 2;
            int cc = ((c & 3) ^ ((c >> 3) & 3)) * 8;
            gload_lds16(A + (long long)(m0 + rr) * lda + k0 + cc,
                        &smem[slot * 6144 + (it * 256 + wid * 64) * 8]);
        }
        {
            int c = tid;
            int rr = c >> 2;
            int cc = ((c & 3) ^ ((c >> 3) & 3)) * 8;
            gload_lds16(B + (long long)(n0 + rr) * ldb + k0 + cc,
                        &smem[slot * 6144 + 4096 + (wid * 64) * 8]);
        }
    };

    f32x4 acc[2][4] = {};
    const int sw8 = (((lane >> 4) ^ ((lane >> 1) & 3)) * 8);
    const int aoff = (wr * 32 + (lane & 15)) * 32 + sw8;
    const int boff = 4096 + ((lane & 15)) * 32 + sw8;

    bf16x8 aR0[2], bR0[4], aR1[2], bR1[4];
    stage(0, 0); stage(1, 1); stage(2, 2);
    asm volatile("s_waitcnt vmcnt(6)" ::: "memory");
    __builtin_amdgcn_s_barrier();
#pragma unroll
    for (int m = 0; m < 2; ++m) aR0[m] = *(const bf16x8*)&smem[aoff + m * 512];
#pragma unroll
    for (int n = 0; n < 4; ++n) bR0[n] = *(const bf16x8*)&smem[boff + n * 512];

#define STEP64(T, AC, BC, AN, BN2)                                                    \
    {                                                                                 \
        int t = (T);                                                                  \
        if (t + 3 < NT) stage((t + 3) & 3, t + 3);                                    \
        if (t + 3 < NT)      asm volatile("s_waitcnt vmcnt(6)" ::: "memory");         \
        else if (t + 2 < NT) asm volatile("s_waitcnt vmcnt(3)" ::: "memory");         \
        else if (t + 1 < NT) asm volatile("s_waitcnt vmcnt(0)" ::: "memory");         \
        __builtin_amdgcn_s_barrier();                                                 \
        const int sb = ((t + 1) & 3) * 6144;                                          \
        const bool pre = (t + 1 < NT);                                                \
        _Pragma("unroll")                                                             \
        for (int q = 0; q < 2; ++q) {                                                 \
            if (pre) {                                                                \
                AN[q] = *(const bf16x8*)&smem[sb + aoff + q * 512];                    \
                BN2[2 * q] = *(const bf16x8*)&smem[sb + boff + (2 * q) * 512];         \
                BN2[2 * q + 1] = *(const bf16x8*)&smem[sb + boff + (2 * q + 1) * 512]; \
            }                                                                         \
            __builtin_amdgcn_s_setprio(1);                                            \
            _Pragma("unroll")                                                         \
            for (int m = 0; m < 2; ++m) {                                             \
                acc[m][2 * q] = __builtin_amdgcn_mfma_f32_16x16x32_bf16(AC[m], BC[2 * q], acc[m][2 * q], 0, 0, 0); \
                acc[m][2 * q + 1] = __builtin_amdgcn_mfma_f32_16x16x32_bf16(AC[m], BC[2 * q + 1], acc[m][2 * q + 1], 0, 0, 0); \
            }                                                                         \
            __builtin_amdgcn_s_setprio(0);                                            \
            __builtin_amdgcn_sched_barrier(0);                                        \
        }                                                                             \
        asm volatile("s_waitcnt lgkmcnt(0)" ::: "memory");                            \
        __builtin_amdgcn_sched_barrier(0);                                            \
    }

    for (int tt = 0; tt < NT; tt += 2) {
        STEP64(tt, aR0, bR0, aR1, bR1)
        STEP64(tt + 1, aR1, bR1, aR0, bR0)
    }
#undef STEP64

    __syncthreads();
    const int orow = (lane >> 4) * 4;
    const int ocol = lane & 15;
    float bv[4];
    if (EPI >= 1) {
#pragma unroll
        for (int j = 0; j < 4; ++j) bv[j] = bias[n0 + j * 16 + ocol];
    }
#pragma unroll
    for (int i = 0; i < 2; ++i)
#pragma unroll
        for (int j = 0; j < 4; ++j)
#pragma unroll
            for (int rj = 0; rj < 4; ++rj) {
                int lrow = wr * 32 + i * 16 + orow + rj;
                int lcol = j * 16 + ocol;
                float val = acc[i][j][rj];
                if (EPI == 1) val += bv[j];
                if (EPI == 2) val = gelu_fast(val + bv[j]);
                smem[lrow * 64 + lcol] = (short)f2bf(val);
            }
    __syncthreads();
    const long long zoff = (long long)blockIdx.z * sC;
#pragma unroll
    for (int p = 0; p < 4; ++p) {
        int s = p * 256 + tid;
        int row = s >> 3;
        int cc = (s & 7) * 8;
        *(int4*)&C[zoff + (long long)(m0 + row) * ldc + n0 + cc] = *(const int4*)&smem[row * 64 + cc];
    }
}

// ====== pdecay: scores = (q k^T) * gamma^(n-m) * KSCALE, 128x128, ring-4 (64KB) ======
__global__ __launch_bounds__(256, 2) void pdecay(
    const short* __restrict__ Q, const short* __restrict__ Kp,
    unsigned short* __restrict__ S, int lda, long long sA) {
    if (blockIdx.x > blockIdx.y) return;
    const int q0 = blockIdx.y * 128;
    const int c0 = blockIdx.x * 128;
    unsigned short* Sb = S + (long long)blockIdx.z * SEQ * SEQ;
    __shared__ __align__(16) short smem[4 * 8192];
    const int tid = threadIdx.x;
    const int lane = tid & 63;
    const int wid = tid >> 6;
    const int wr = wid >> 1, wc = wid & 1;
    const short* Ab = Q + (long long)blockIdx.z * sA;
    const short* Bb = Kp + (long long)blockIdx.z * sA;

    auto stage = [&](int slot, int t) {
        int k0 = t * 32;
#pragma unroll
        for (int it = 0; it < 2; ++it) {
            int c = it * 256 + tid;
            int rr = c >> 2;
            int cc = ((c & 3) ^ ((c >> 3) & 3)) * 8;
            gload_lds16(Ab + (long long)(q0 + rr) * lda + k0 + cc,
                        &smem[slot * 8192 + (it * 256 + wid * 64) * 8]);
            gload_lds16(Bb + (long long)(c0 + rr) * lda + k0 + cc,
                        &smem[slot * 8192 + 4096 + (it * 256 + wid * 64) * 8]);
        }
    };

    const int NT = D_MODEL / 32;   // 16
    f32x4 acc[4][4] = {};
    const int sw8 = (((lane >> 4) ^ ((lane >> 1) & 3)) * 8);
    const int aoff = (wr * 64 + (lane & 15)) * 32 + sw8;
    const int boff = 4096 + (wc * 64 + (lane & 15)) * 32 + sw8;

    bf16x8 aR0[4], bR0[4], aR1[4], bR1[4];
    stage(0, 0); stage(1, 1); stage(2, 2);
    asm volatile("s_waitcnt vmcnt(8)" ::: "memory");
    __builtin_amdgcn_s_barrier();
#pragma unroll
    for (int m = 0; m < 4; ++m) aR0[m] = *(const bf16x8*)&smem[aoff + m * 512];
#pragma unroll
    for (int n = 0; n < 4; ++n) bR0[n] = *(const bf16x8*)&smem[boff + n * 512];

#define STEPD(T, AC, BC, AN, BN2)                                                     \
    {                                                                                 \
        int t = (T);                                                                  \
        if (t + 3 < NT) stage((t + 3) & 3, t + 3);                                    \
        if (t + 3 < NT)      asm volatile("s_waitcnt vmcnt(8)" ::: "memory");         \
        else if (t + 2 < NT) asm volatile("s_waitcnt vmcnt(4)" ::: "memory");         \
        else if (t + 1 < NT) asm volatile("s_waitcnt vmcnt(0)" ::: "memory");         \
        __builtin_amdgcn_s_barrier();                                                 \
        const int sb = ((t + 1) & 3) * 8192;                                          \
        const bool pre = (t + 1 < NT);                                                \
        _Pragma("unroll")                                                             \
        for (int q = 0; q < 4; ++q) {                                                 \
            if (pre) {                                                                \
                AN[q] = *(const bf16x8*)&smem[sb + aoff + q * 512];                    \
                BN2[q] = *(const bf16x8*)&smem[sb + boff + q * 512];                   \
            }                                                                         \
            __builtin_amdgcn_s_setprio(1);                                            \
            _Pragma("unroll")                                                         \
            for (int n = 0; n < 4; ++n)                                               \
                acc[q][n] = __builtin_amdgcn_mfma_f32_16x16x32_bf16(AC[q], BC[n], acc[q][n], 0, 0, 0); \
            __builtin_amdgcn_s_setprio(0);                                            \
            __builtin_amdgcn_sched_barrier(0);                                        \
        }                                                                             \
        asm volatile("s_waitcnt lgkmcnt(0)" ::: "memory");                            \
        __builtin_amdgcn_sched_barrier(0);                                            \
    }

    for (int tt = 0; tt < NT; tt += 2) {
        STEPD(tt, aR0, bR0, aR1, bR1)
        STEPD(tt + 1, aR1, bR1, aR0, bR0)
    }
#undef STEPD

    __syncthreads();
    const int orow = (lane >> 4) * 4;
    const int ocol = lane & 15;
#pragma unroll
    for (int i = 0; i < 4; ++i)
#pragma unroll
        for (int j = 0; j < 4; ++j)
#pragma unroll
            for (int rj = 0; rj < 4; ++rj) {
                int lrow = wr * 64 + i * 16 + orow + rj;
                int lcol = wc * 64 + j * 16 + ocol;
                int n = q0 + lrow, m = c0 + lcol;
                float w = (n >= m) ? exp2f((float)(n - m) * LOG2_GAMMA) * KSCALE : 0.f;
                smem[lrow * 128 + lcol] = (short)f2bf(acc[i][j][rj] * w);
            }
    __syncthreads();
#pragma unroll
    for (int p = 0; p < 8; ++p) {
        int s = p * 256 + tid;
        int row = s >> 4;
        int cc = (s & 15) * 8;
        *(int4*)&Sb[(long long)(q0 + row) * SEQ + c0 + cc] = *(const int4*)&smem[row * 128 + cc];
    }
}

// ============ fused weight convert+transpose ============
__global__ __launch_bounds__(256) void wconv_all(
    const float* __restrict__ Wq, const float* __restrict__ Wk,
    const float* __restrict__ Wv, const float* __restrict__ Wg,
    const float* __restrict__ Wo, const float* __restrict__ W1,
    const float* __restrict__ W2,
    unsigned short* __restrict__ WqkvgT, unsigned short* __restrict__ WoT,
    unsigned short* __restrict__ W1T, unsigned short* __restrict__ W2T) {
    const long long dd = 512LL * 512;
    int z = blockIdx.z;
    int l = z / 7, w = z % 7;
    const float* src; unsigned short* dst; int K, N;
    switch (w) {
        case 0: src = Wq + l * dd; dst = WqkvgT + (long long)l * 4 * dd; K = 512; N = 512; break;
        case 1: src = Wk + l * dd; dst = WqkvgT + (long long)l * 4 * dd + dd; K = 512; N = 512; break;
        case 2: src = Wv + l * dd; dst = WqkvgT + (long long)l * 4 * dd + 2 * dd; K = 512; N = 512; break;
        case 3: src = Wg + l * dd; dst = WqkvgT + (long long)l * 4 * dd + 3 * dd; K = 512; N = 512; break;
        case 4: src = Wo + l * dd; dst = WoT + l * dd; K = 512; N = 512; break;
        case 5: src = W1 + (long long)l * 512 * 1024; dst = W1T + (long long)l * 512 * 1024; K = 512; N = 1024; break;
        default: src = W2 + (long long)l * 1024 * 512; dst = W2T + (long long)l * 1024 * 512; K = 1024; N = 512; break;
    }
    if ((int)blockIdx.x >= N / 64 || (int)blockIdx.y >= K / 64) return;
    __shared__ unsigned short t[64][65];
    int n0 = blockIdx.x * 64, k0 = blockIdx.y * 64;
    int tx = threadIdx.x & 63, ty = threadIdx.x >> 6;
#pragma unroll
    for (int i = 0; i < 16; ++i)
        t[ty + i * 4][tx] = f2bf(src[(long long)(k0 + ty + i * 4) * N + n0 + tx]);
    __syncthreads();
#pragma unroll
    for (int i = 0; i < 16; ++i)
        dst[(long long)(n0 + ty + i * 4) * K + k0 + tx] = t[tx][ty + i * 4];
}

// ============ per-batch transpose: bf16 [SEQ][*stride slice] -> [D][SEQ] ============
__global__ __launch_bounds__(256) void vtrans(const unsigned short* __restrict__ in,
                                              unsigned short* __restrict__ out, int istride) {
    __shared__ unsigned short t[64][65];
    const unsigned short* pin = in + (long long)blockIdx.z * SEQ * istride;
    unsigned short* pout = out + (long long)blockIdx.z * D_MODEL * SEQ;
    int c0 = blockIdx.x * 64, r0 = blockIdx.y * 64;
    int tx = threadIdx.x & 63, ty = threadIdx.x >> 6;
#pragma unroll
    for (int i = 0; i < 16; ++i)
        t[ty + i * 4][tx] = pin[(long long)(r0 + ty + i * 4) * istride + c0 + tx];
    __syncthreads();
#pragma unroll
    for (int i = 0; i < 16; ++i)
        pout[(long long)(c0 + ty + i * 4) * SEQ + r0 + tx] = t[tx][ty + i * 4];
}

// ============ fused residual-add + LayerNorm, all bf16 ============
// MODE 0: y = LN(hin bf16)
// MODE 1: hn = hin+delta; hout=hn; y = LN(hn)
// MODE 2: hin is f32; hout = bf16(hin); y = LN(hin)
template <int MODE>
__global__ __launch_bounds__(256) void ln_fuse(
    const void* __restrict__ hin_v,
    const unsigned short* __restrict__ delta,
    const float* __restrict__ g, const float* __restrict__ b,
    unsigned short* __restrict__ hout,
    unsigned short* __restrict__ y) {
    int row = blockIdx.x * 4 + (threadIdx.x >> 6);
    int t = threadIdx.x & 63;
    float f[8];
    if (MODE == 2) {
        const float4* r4 = (const float4*)((const float*)hin_v + (long long)row * D_MODEL);
        float4 v0 = r4[2 * t], v1 = r4[2 * t + 1];
        f[0] = v0.x; f[1] = v0.y; f[2] = v0.z; f[3] = v0.w;
        f[4] = v1.x; f[5] = v1.y; f[6] = v1.z; f[7] = v1.w;
    } else {
        const unsigned short* hin = (const unsigned short*)hin_v;
        int4 hv = ((const int4*)(hin + (long long)row * D_MODEL))[t];
        const unsigned short* hu = (const unsigned short*)&hv;
#pragma unroll
        for (int k = 0; k < 8; ++k) f[k] = bf2f(hu[k]);
    }
    if (MODE == 1) {
        int4 dv = ((const int4*)(delta + (long long)row * D_MODEL))[t];
        const unsigned short* du = (const unsigned short*)&dv;
#pragma unroll
        for (int k = 0; k < 8; ++k) f[k] += bf2f(du[k]);
    }
    float s = 0.f, s2 = 0.f;
#pragma unroll
    for (int k = 0; k < 8; ++k) { s += f[k]; s2 += f[k] * f[k]; }
#pragma unroll
    for (int off = 32; off > 0; off >>= 1) {
        s += __shfl_down(s, off);
        s2 += __shfl_down(s2, off);
    }
    s = __shfl(s, 0); s2 = __shfl(s2, 0);
    float mu = s * (1.f / D_MODEL);
    float var = s2 * (1.f / D_MODEL) - mu * mu;
    float rs = rsqrtf(var + 1e-6f);
    if (MODE >= 1) {
        ushort4 ho[2];
        unsigned short* hp = (unsigned short*)ho;
#pragma unroll
        for (int k = 0; k < 8; ++k) hp[k] = f2bf(f[k]);
        ((int4*)(hout + (long long)row * D_MODEL))[t] = *(int4*)ho;
    }
    const float4* g4 = (const float4*)g;
    const float4* b4 = (const float4*)b;
    float4 ga = g4[2 * t], gb2 = g4[2 * t + 1];
    float4 ba = b4[2 * t], bb2 = b4[2 * t + 1];
    float gg[8] = {ga.x, ga.y, ga.z, ga.w, gb2.x, gb2.y, gb2.z, gb2.w};
    float bb[8] = {ba.x, ba.y, ba.z, ba.w, bb2.x, bb2.y, bb2.z, bb2.w};
    ushort4 yo[2];
    unsigned short* yp = (unsigned short*)yo;
#pragma unroll
    for (int k = 0; k < 8; ++k) yp[k] = f2bf((f[k] - mu) * rs * gg[k] + bb[k]);
    ((int4*)(y + (long long)row * D_MODEL))[t] = *(int4*)yo;
}

// ============ gated = silu(g) * groupnorm(ret), all bf16 (g strided) ============
__global__ __launch_bounds__(256) void gate_bf16(const unsigned short* __restrict__ ret,
                                                 const unsigned short* __restrict__ g,
                                                 int gstride,
                                                 unsigned short* __restrict__ out) {
    int row = blockIdx.x * 4 + (threadIdx.x >> 6);
    int t = threadIdx.x & 63;
    int4 rv4 = ((const int4*)(ret + (long long)row * D_MODEL))[t];
    const unsigned short* ru = (const unsigned short*)&rv4;
    float f[8];
#pragma unroll
    for (int k = 0; k < 8; ++k) f[k] = bf2f(ru[k]);
    float s = 0.f, s2 = 0.f;
#pragma unroll
    for (int k = 0; k < 8; ++k) { s += f[k]; s2 += f[k] * f[k]; }
#pragma unroll
    for (int off = 32; off > 0; off >>= 1) {
        s += __shfl_down(s, off);
        s2 += __shfl_down(s2, off);
    }
    s = __shfl(s, 0); s2 = __shfl(s2, 0);
    float mu = s * (1.f / D_MODEL);
    float var = s2 * (1.f / D_MODEL) - mu * mu;
    float rs = rsqrtf(var + 1e-6f);
    int4 gv4 = ((const int4*)(g + (long long)row * gstride))[t];
    const unsigned short* gu = (const unsigned short*)&gv4;
    ushort4 o[2];
    unsigned short* op = (unsigned short*)o;
#pragma unroll
    for (int k = 0; k < 8; ++k) {
        float x = bf2f(gu[k]);
        op[k] = f2bf(x * sigm(x) * (f[k] - mu) * rs);
    }
    ((int4*)(out + (long long)row * D_MODEL))[t] = *(int4*)o;
}

// ============ pooled = sum_rows (h + dlast): two-stage ============
__global__ __launch_bounds__(256) void pool_s1(const unsigned short* __restrict__ h,
                                               const unsigned short* __restrict__ d,
                                               float* __restrict__ partial) {
    int b = blockIdx.x >> 4, g = blockIdx.x & 15;
    long long base = ((long long)b * SEQ + g * 64) * D_MODEL;
    int cw = (threadIdx.x & 63) * 8;
    int rg = threadIdx.x >> 6;
    float a[8] = {};
    for (int r = rg; r < 64; r += 4) {
        long long o = base + (long long)r * D_MODEL + cw;
        int4 hv = *(const int4*)&h[o];
        int4 dv = *(const int4*)&d[o];
        const unsigned short* hp = (const unsigned short*)&hv;
        const unsigned short* dp = (const unsigned short*)&dv;
#pragma unroll
        for (int j = 0; j < 8; ++j) a[j] += bf2f(hp[j]) + bf2f(dp[j]);
    }
    __shared__ float red[4][512];
#pragma unroll
    for (int j = 0; j < 8; ++j) red[rg][cw + j] = a[j];
    __syncthreads();
#pragma unroll
    for (int cc = 0; cc < 2; ++cc) {
        int c = threadIdx.x * 2 + cc;
        partial[(long long)blockIdx.x * D_MODEL + c] =
            red[0][c] + red[1][c] + red[2][c] + red[3][c];
    }
}

__global__ __launch_bounds__(256) void pool_s2(const float* __restrict__ partial,
                                               float* __restrict__ pooled) {
    int idx = blockIdx.x * 256 + threadIdx.x;  // 0..8191
    int b = idx >> 9, c = idx & 511;
    float s = 0.f;
#pragma unroll
    for (int g = 0; g < 16; ++g) s += partial[(long long)(b * 16 + g) * D_MODEL + c];
    pooled[idx] = s;
}

__global__ __launch_bounds__(64) void readout_kernel(const float* __restrict__ pooled,
                                                     const float* __restrict__ Wro,
                                                     const float* __restrict__ bro,
                                                     float* __restrict__ out) {
    int bo = blockIdx.x;
    int b = bo >> 1, o = bo & 1;
    int t = threadIdx.x;
    float s = 0.f;
    for (int i = t; i < D_MODEL; i += 64) s += pooled[b * D_MODEL + i] * Wro[i * 2 + o];
#pragma unroll
    for (int off = 32; off > 0; off >>= 1) s += __shfl_down(s, off);
    if (t == 0) out[b * 2 + o] = s + bro[o];
}

extern "C" void kernel_launch(void* const* d_in, const int* in_sizes, int n_in,
                              void* d_out, int out_size, void* d_ws, size_t ws_size,
                              hipStream_t stream) {
    const float* x = (const float*)d_in[0];
    const float* Wq = (const float*)d_in[1];
    const float* Wk = (const float*)d_in[2];
    const float* Wv = (const float*)d_in[3];
    const float* Wg = (const float*)d_in[4];
    const float* Wo = (const float*)d_in[5];
    const float* ln1_g = (const float*)d_in[6];
    const float* ln1_b = (const float*)d_in[7];
    const float* ln2_g = (const float*)d_in[8];
    const float* ln2_b = (const float*)d_in[9];
    const float* W1 = (const float*)d_in[10];
    const float* b1 = (const float*)d_in[11];
    const float* W2 = (const float*)d_in[12];
    const float* b2 = (const float*)d_in[13];
    const float* Wro = (const float*)d_in[14];
    const float* bro = (const float*)d_in[15];
    float* out = (float*)d_out;

    const long long NE = (long long)NROWS * D_MODEL;  // 8,388,608
    const long long dd = (long long)D_MODEL * D_MODEL;

    unsigned short* h = (unsigned short*)d_ws;   // NE
    unsigned short* y = h + NE;                  // NE
    unsigned short* qkvg = y + NE;               // 4*NE  [16384][2048]
    unsigned short* vT = qkvg + 4 * NE;          // NE    [16][512][1024]
    unsigned short* gated = vT;                  // alias (vT dead after ret GEMM)
    unsigned short* ret = vT + NE;               // NE    (also ffn-delta buffer)
    unsigned short* sg = ret + NE;               // 2*NE  scores / attn-delta / ffn-hidden
    float* pooled = (float*)(sg + 2 * NE);       // 8192 f32
    float* partial = pooled + 8192;              // 256*512 f32
    unsigned short* wts = (unsigned short*)(partial + 256 * 512);
    unsigned short* WqkvgT = wts;                          // [L][2048][512]
    unsigned short* WoT = WqkvgT + 2 * 4 * dd;             // [L][512][512]
    unsigned short* W1T = WoT + 2 * dd;                    // [L][1024][512]
    unsigned short* W2T = W1T + 2 * (long long)D_MODEL * HID;  // [L][512][1024]

    dim3 blk(256);
    wconv_all<<<dim3(16, 16, 14), blk, 0, stream>>>(Wq, Wk, Wv, Wg, Wo, W1, W2,
                                                    WqkvgT, WoT, W1T, W2T);

    for (int l = 0; l < 2; l++) {
        if (l == 0)
            ln_fuse<2><<<NROWS / 4, blk, 0, stream>>>(x, nullptr, ln1_g, ln1_b, h, y);
        else
            ln_fuse<1><<<NROWS / 4, blk, 0, stream>>>(h, ret, ln1_g + l * D_MODEL,
                                                      ln1_b + l * D_MODEL, h, y);
        // qkvg = y @ [Wq|Wk|Wv|Wg]
        gemm256p<0><<<512, 512, 0, stream>>>(
            (const short*)y, (const short*)(WqkvgT + (long long)l * 4 * dd), nullptr, qkvg,
            512, 512, 512, 2048, 8);
        vtrans<<<dim3(8, 16, BATCH), blk, 0, stream>>>(qkvg + 1024, vT, 2048);
        pdecay<<<dim3(8, 8, BATCH), blk, 0, stream>>>(
            (const short*)qkvg, (const short*)(qkvg + 512), sg, 2048, (long long)SEQ * 2048);
        // ret = scores @ v  (K truncated at diagonal)
        pgemm64<0><<<dim3(8, 8, BATCH), blk, 0, stream>>>(
            (const short*)sg, (const short*)vT, nullptr, ret,
            SEQ, SEQ, SEQ, 512,
            (long long)SEQ * SEQ, (long long)D_MODEL * SEQ, (long long)SEQ * D_MODEL, 1);
        gate_bf16<<<NROWS / 4, blk, 0, stream>>>(ret, qkvg + 1536, 2048, gated);
        // attn delta = gated @ Wo  -> sg
        pgemm64<0><<<dim3(8, 128), blk, 0, stream>>>(
            (const short*)gated, (const short*)(WoT + l * dd), nullptr, sg,
            512, 512, 512, 512, 0, 0, 0, 0);
        // h += attn delta; y = LN2(h)
        ln_fuse<1><<<NROWS / 4, blk, 0, stream>>>(h, sg, ln2_g + l * D_MODEL,
                                                  ln2_b + l * D_MODEL, h, y);
        // hidden = gelu(y @ W1 + b1)
        gemm256p<2><<<256, 512, 0, stream>>>(
            (const short*)y, (const short*)(W1T + (long long)l * D_MODEL * HID),
            b1 + l * HID, sg, 512, 512, 512, HID, 4);
        // ffn delta = hidden @ W2 + b2 -> ret buffer
        pgemm64<1><<<dim3(8, 128), blk, 0, stream>>>(
            (const short*)sg, (const short*)(W2T + (long long)l * HID * D_MODEL),
            b2 + l * D_MODEL, ret, HID, HID, HID, 512, 0, 0, 0, 0);
    }

    pool_s1<<<256, blk, 0, stream>>>(h, ret, partial);
    pool_s2<<<32, blk, 0, stream>>>(partial, pooled);
    readout_kernel<<<32, 64, 0, stream>>>(pooled, Wro, bro, out);
}

// Round 10
// 522.479 us; speedup vs baseline: 6.2789x; 1.0079x over previous
//
#include <hip/hip_runtime.h>
#include <hip/hip_bf16.h>

// RetNet 2-layer forward. All-bf16 dataflow.
// MFMA GEMMs: ring-4 LDS, one barrier/K-step, counted vmcnt, conflict-free swizzle.
// New: decay band-limit (tile-distance<=3), vtrans fused into qkvg epilogue.

#define D_MODEL 512
#define SEQ 1024
#define BATCH 16
#define NROWS (BATCH * SEQ)          // 16384
#define HID 1024
#define LOG2_GAMMA (-0.04580368961f)  // log2(0.96875)
#define KSCALE (0.044194173824f)      // 512^-0.5

typedef __attribute__((ext_vector_type(8))) short bf16x8;
typedef __attribute__((ext_vector_type(4))) float f32x4;

__device__ inline unsigned short f2bf(float x) {
    union { float f; unsigned u; } uu; uu.f = x;
    unsigned r = uu.u + 0x7fff + ((uu.u >> 16) & 1);
    return (unsigned short)(r >> 16);
}
__device__ inline float bf2f(unsigned short x) {
    union { unsigned u; float f; } uu; uu.u = ((unsigned)x) << 16; return uu.f;
}

__device__ inline void gload_lds16(const void* g, void* l) {
    __builtin_amdgcn_global_load_lds(
        (const __attribute__((address_space(1))) void*)g,
        (__attribute__((address_space(3))) void*)l, 16, 0, 0);
}

__device__ inline float sigm(float z) {
    return 1.f / (1.f + exp2f(z * -1.442695040888963f));
}
__device__ inline float gelu_fast(float x) {
    float y = 1.5957691216057308f * (x + 0.044715f * x * x * x);
    return x * sigm(y);
}

// ================== gemm256p: C[M,N] = A[M,K] @ B[N,K]^T, bf16 out ==================
// VT=1: n-tiles covering cols [1024,1536) write TRANSPOSED to vTp ([b][512][1024]).
template <int EPI, int VT>
__global__ __launch_bounds__(512, 2) void gemm256p(
    const short* __restrict__ A, const short* __restrict__ B,
    const float* __restrict__ bias, unsigned short* __restrict__ C,
    int K, int lda, int ldb, int ldc, int nbx,
    unsigned short* __restrict__ vTp) {
    __shared__ __align__(16) short smem[4 * 16384];
    const int tid = threadIdx.x;
    const int lane = tid & 63;
    const int wid = tid >> 6;
    const int wm = wid >> 2, wn = wid & 3;
    const int cpx = gridDim.x >> 3;
    const int wg = ((int)blockIdx.x & 7) * cpx + ((int)blockIdx.x >> 3);
    const int m0 = (wg / nbx) * 256;
    const int n0 = (wg % nbx) * 256;

    const int srow = tid >> 2;
    const int scol = (((tid & 3) ^ ((tid >> 3) & 3)) * 8);
    auto stage = [&](int slot, int t) {
        int k0 = t * 32;
#pragma unroll
        for (int r = 0; r < 2; ++r) {
            gload_lds16(A + (long long)(m0 + r * 128 + srow) * lda + k0 + scol,
                        &smem[slot * 16384 + r * 4096 + wid * 512]);
            gload_lds16(B + (long long)(n0 + r * 128 + srow) * ldb + k0 + scol,
                        &smem[slot * 16384 + 8192 + r * 4096 + wid * 512]);
        }
    };

    const int NT = K >> 5;
    f32x4 acc[8][4] = {};
    const int sw8 = (((lane >> 4) ^ ((lane >> 1) & 3)) * 8);
    const int aoff = (wm * 128 + (lane & 15)) * 32 + sw8;
    const int boff = 8192 + (wn * 64 + (lane & 15)) * 32 + sw8;

    bf16x8 aR0[8], bR0[4], aR1[8], bR1[4];
    stage(0, 0); stage(1, 1); stage(2, 2);
    asm volatile("s_waitcnt vmcnt(8)" ::: "memory");
    __builtin_amdgcn_s_barrier();
#pragma unroll
    for (int m = 0; m < 8; ++m) aR0[m] = *(const bf16x8*)&smem[aoff + m * 512];
#pragma unroll
    for (int n = 0; n < 4; ++n) bR0[n] = *(const bf16x8*)&smem[boff + n * 512];

#define STEP256(T, AC, BC, AN, BN2)                                                   \
    {                                                                                 \
        int t = (T);                                                                  \
        if (t + 3 < NT) stage((t + 3) & 3, t + 3);                                    \
        if (t + 3 < NT)      asm volatile("s_waitcnt vmcnt(8)" ::: "memory");         \
        else if (t + 2 < NT) asm volatile("s_waitcnt vmcnt(4)" ::: "memory");         \
        else if (t + 1 < NT) asm volatile("s_waitcnt vmcnt(0)" ::: "memory");         \
        __builtin_amdgcn_s_barrier();                                                 \
        const int sb = ((t + 1) & 3) * 16384;                                         \
        const bool pre = (t + 1 < NT);                                                \
        _Pragma("unroll")                                                             \
        for (int q = 0; q < 4; ++q) {                                                 \
            if (pre) {                                                                \
                AN[2 * q] = *(const bf16x8*)&smem[sb + aoff + (2 * q) * 512];          \
                AN[2 * q + 1] = *(const bf16x8*)&smem[sb + aoff + (2 * q + 1) * 512];  \
                BN2[q] = *(const bf16x8*)&smem[sb + boff + q * 512];                   \
            }                                                                         \
            __builtin_amdgcn_s_setprio(1);                                            \
            _Pragma("unroll")                                                         \
            for (int n = 0; n < 4; ++n) {                                             \
                acc[2 * q][n] = __builtin_amdgcn_mfma_f32_16x16x32_bf16(AC[2 * q], BC[n], acc[2 * q][n], 0, 0, 0); \
                acc[2 * q + 1][n] = __builtin_amdgcn_mfma_f32_16x16x32_bf16(AC[2 * q + 1], BC[n], acc[2 * q + 1][n], 0, 0, 0); \
            }                                                                         \
            __builtin_amdgcn_s_setprio(0);                                            \
            __builtin_amdgcn_sched_barrier(0);                                        \
        }                                                                             \
        asm volatile("s_waitcnt lgkmcnt(0)" ::: "memory");                            \
        __builtin_amdgcn_sched_barrier(0);                                            \
    }

    for (int tt = 0; tt < NT; tt += 2) {
        STEP256(tt, aR0, bR0, aR1, bR1)
        STEP256(tt + 1, aR1, bR1, aR0, bR0)
    }
#undef STEP256

    const int ocol = lane & 15;
    const int orow4 = (lane >> 4) * 4;
    const bool isv = VT && (n0 >= 1024) && (n0 < 1536);
    if (isv) {
        // transposed epilogue -> vT[b][d][s]
        const int dbase = n0 - 1024;
        const int b = m0 >> 10;
        const int s0g = m0 & 1023;
        unsigned short* vTb = vTp + ((long long)b * 512 + dbase) * 1024 + s0g;
#pragma unroll 1
        for (int half = 0; half < 2; ++half) {
            __syncthreads();
            if (wm == half) {
#pragma unroll
                for (int m = 0; m < 8; ++m)
#pragma unroll
                    for (int n = 0; n < 4; ++n)
#pragma unroll
                        for (int rj = 0; rj < 4; ++rj) {
                            int lr = m * 16 + orow4 + rj;
                            int lc = wn * 64 + n * 16 + ocol;
                            smem[lc * 136 + lr] = (short)f2bf(acc[m][n][rj]);
                        }
            }
            __syncthreads();
#pragma unroll
            for (int p = 0; p < 8; ++p) {
                int idx = p * 512 + tid;
                int d = idx >> 4;
                int s8 = (idx & 15) * 8;
                *(int4*)&vTb[(long long)d * 1024 + half * 128 + s8] =
                    *(const int4*)&smem[d * 136 + s8];
            }
        }
        return;
    }
    float bv[4];
    if (EPI == 2) {
#pragma unroll
        for (int n = 0; n < 4; ++n) bv[n] = bias[n0 + wn * 64 + n * 16 + ocol];
    }
#pragma unroll 1
    for (int half = 0; half < 2; ++half) {
        __syncthreads();
        if (wm == half) {
#pragma unroll
            for (int m = 0; m < 8; ++m)
#pragma unroll
                for (int n = 0; n < 4; ++n)
#pragma unroll
                    for (int rj = 0; rj < 4; ++rj) {
                        int lr = m * 16 + orow4 + rj;
                        int lc = wn * 64 + n * 16 + ocol;
                        float v = acc[m][n][rj];
                        if (EPI == 2) v = gelu_fast(v + bv[n]);
                        smem[lr * 256 + lc] = (short)f2bf(v);
                    }
        }
        __syncthreads();
#pragma unroll
        for (int p = 0; p < 8; ++p) {
            int s = p * 512 + tid;
            int row = s >> 5;
            int cc = (s & 31) * 8;
            *(int4*)&C[(long long)(m0 + half * 128 + row) * ldc + n0 + cc] =
                *(const int4*)&smem[row * 256 + cc];
        }
    }
}

// ================== pgemm64: BM=128, BN=64, 4 waves, ring-4 (48KB) ==================
// tri: 0 full K; 1 K in [0, m0+128); 2 K in [max(0,m0-384), m0+128)  (banded retention)
template <int EPI>
__global__ __launch_bounds__(256, 4) void pgemm64(
    const short* __restrict__ A, const short* __restrict__ B,
    const float* __restrict__ bias, unsigned short* __restrict__ C,
    int K, int lda, int ldb, int ldc,
    long long sA, long long sB, long long sC, int tri) {
    __shared__ __align__(16) short smem[4 * 6144];
    const int tid = threadIdx.x;
    const int lane = tid & 63;
    const int wid = tid >> 6;
    const int wr = wid;
    const int m0 = blockIdx.y * 128, n0 = blockIdx.x * 64;
    A += (long long)blockIdx.z * sA;
    B += (long long)blockIdx.z * sB;

    int Keff = K;
    int kstart = 0;
    if (tri) { int km = m0 + 128; if (km < Keff) Keff = km; }
    if (tri == 2) { int ks = m0 - 384; if (ks > 0) kstart = ks; }
    const int NT = (Keff - kstart) >> 5;

    auto stage = [&](int slot, int t) {
        int k0 = kstart + t * 32;
#pragma unroll
        for (int it = 0; it < 2; ++it) {
            int c = it * 256 + tid;
            int rr = c >> 2;
            int cc = ((c & 3) ^ ((c >> 3) & 3)) * 8;
            gload_lds16(A + (long long)(m0 + rr) * lda + k0 + cc,
                        &smem[slot * 6144 + (it * 256 + wid * 64) * 8]);
        }
        {
            int c = tid;
            int rr = c >> 2;
            int cc = ((c & 3) ^ ((c >> 3) & 3)) * 8;
            gload_lds16(B + (long long)(n0 + rr) * ldb + k0 + cc,
                        &smem[slot * 6144 + 4096 + (wid * 64) * 8]);
        }
    };

    f32x4 acc[2][4] = {};
    const int sw8 = (((lane >> 4) ^ ((lane >> 1) & 3)) * 8);
    const int aoff = (wr * 32 + (lane & 15)) * 32 + sw8;
    const int boff = 4096 + ((lane & 15)) * 32 + sw8;

    bf16x8 aR0[2], bR0[4], aR1[2], bR1[4];
    stage(0, 0); stage(1, 1); stage(2, 2);
    asm volatile("s_waitcnt vmcnt(6)" ::: "memory");
    __builtin_amdgcn_s_barrier();
#pragma unroll
    for (int m = 0; m < 2; ++m) aR0[m] = *(const bf16x8*)&smem[aoff + m * 512];
#pragma unroll
    for (int n = 0; n < 4; ++n) bR0[n] = *(const bf16x8*)&smem[boff + n * 512];

#define STEP64(T, AC, BC, AN, BN2)                                                    \
    {                                                                                 \
        int t = (T);                                                                  \
        if (t + 3 < NT) stage((t + 3) & 3, t + 3);                                    \
        if (t + 3 < NT)      asm volatile("s_waitcnt vmcnt(6)" ::: "memory");         \
        else if (t + 2 < NT) asm volatile("s_waitcnt vmcnt(3)" ::: "memory");         \
        else if (t + 1 < NT) asm volatile("s_waitcnt vmcnt(0)" ::: "memory");         \
        __builtin_amdgcn_s_barrier();                                                 \
        const int sb = ((t + 1) & 3) * 6144;                                          \
        const bool pre = (t + 1 < NT);                                                \
        _Pragma("unroll")                                                             \
        for (int q = 0; q < 2; ++q) {                                                 \
            if (pre) {                                                                \
                AN[q] = *(const bf16x8*)&smem[sb + aoff + q * 512];                    \
                BN2[2 * q] = *(const bf16x8*)&smem[sb + boff + (2 * q) * 512];         \
                BN2[2 * q + 1] = *(const bf16x8*)&smem[sb + boff + (2 * q + 1) * 512]; \
            }                                                                         \
            __builtin_amdgcn_s_setprio(1);                                            \
            _Pragma("unroll")                                                         \
            for (int m = 0; m < 2; ++m) {                                             \
                acc[m][2 * q] = __builtin_amdgcn_mfma_f32_16x16x32_bf16(AC[m], BC[2 * q], acc[m][2 * q], 0, 0, 0); \
                acc[m][2 * q + 1] = __builtin_amdgcn_mfma_f32_16x16x32_bf16(AC[m], BC[2 * q + 1], acc[m][2 * q + 1], 0, 0, 0); \
            }                                                                         \
            __builtin_amdgcn_s_setprio(0);                                            \
            __builtin_amdgcn_sched_barrier(0);                                        \
        }                                                                             \
        asm volatile("s_waitcnt lgkmcnt(0)" ::: "memory");                            \
        __builtin_amdgcn_sched_barrier(0);                                            \
    }

    for (int tt = 0; tt < NT; tt += 2) {
        STEP64(tt, aR0, bR0, aR1, bR1)
        STEP64(tt + 1, aR1, bR1, aR0, bR0)
    }
#undef STEP64

    __syncthreads();
    const int orow = (lane >> 4) * 4;
    const int ocol = lane & 15;
    float bv[4];
    if (EPI >= 1) {
#pragma unroll
        for (int j = 0; j < 4; ++j) bv[j] = bias[n0 + j * 16 + ocol];
    }
#pragma unroll
    for (int i = 0; i < 2; ++i)
#pragma unroll
        for (int j = 0; j < 4; ++j)
#pragma unroll
            for (int rj = 0; rj < 4; ++rj) {
                int lrow = wr * 32 + i * 16 + orow + rj;
                int lcol = j * 16 + ocol;
                float val = acc[i][j][rj];
                if (EPI == 1) val += bv[j];
                if (EPI == 2) val = gelu_fast(val + bv[j]);
                smem[lrow * 64 + lcol] = (short)f2bf(val);
            }
    __syncthreads();
    const long long zoff = (long long)blockIdx.z * sC;
#pragma unroll
    for (int p = 0; p < 4; ++p) {
        int s = p * 256 + tid;
        int row = s >> 3;
        int cc = (s & 7) * 8;
        *(int4*)&C[zoff + (long long)(m0 + row) * ldc + n0 + cc] = *(const int4*)&smem[row * 64 + cc];
    }
}

// ====== pdecay: scores = (q k^T) * gamma^(n-m) * KSCALE, banded (dist<=3 tiles) ======
__global__ __launch_bounds__(256, 2) void pdecay(
    const short* __restrict__ Q, const short* __restrict__ Kp,
    unsigned short* __restrict__ S, int lda, long long sA) {
    if (blockIdx.x > blockIdx.y) return;
    if (blockIdx.y > blockIdx.x + 3) return;   // gamma^385 ~ 5e-6: negligible
    const int q0 = blockIdx.y * 128;
    const int c0 = blockIdx.x * 128;
    unsigned short* Sb = S + (long long)blockIdx.z * SEQ * SEQ;
    __shared__ __align__(16) short smem[4 * 8192];
    const int tid = threadIdx.x;
    const int lane = tid & 63;
    const int wid = tid >> 6;
    const int wr = wid >> 1, wc = wid & 1;
    const short* Ab = Q + (long long)blockIdx.z * sA;
    const short* Bb = Kp + (long long)blockIdx.z * sA;

    auto stage = [&](int slot, int t) {
        int k0 = t * 32;
#pragma unroll
        for (int it = 0; it < 2; ++it) {
            int c = it * 256 + tid;
            int rr = c >> 2;
            int cc = ((c & 3) ^ ((c >> 3) & 3)) * 8;
            gload_lds16(Ab + (long long)(q0 + rr) * lda + k0 + cc,
                        &smem[slot * 8192 + (it * 256 + wid * 64) * 8]);
            gload_lds16(Bb + (long long)(c0 + rr) * lda + k0 + cc,
                        &smem[slot * 8192 + 4096 + (it * 256 + wid * 64) * 8]);
        }
    };

    const int NT = D_MODEL / 32;   // 16
    f32x4 acc[4][4] = {};
    const int sw8 = (((lane >> 4) ^ ((lane >> 1) & 3)) * 8);
    const int aoff = (wr * 64 + (lane & 15)) * 32 + sw8;
    const int boff = 4096 + (wc * 64 + (lane & 15)) * 32 + sw8;

    bf16x8 aR0[4], bR0[4], aR1[4], bR1[4];
    stage(0, 0); stage(1, 1); stage(2, 2);
    asm volatile("s_waitcnt vmcnt(8)" ::: "memory");
    __builtin_amdgcn_s_barrier();
#pragma unroll
    for (int m = 0; m < 4; ++m) aR0[m] = *(const bf16x8*)&smem[aoff + m * 512];
#pragma unroll
    for (int n = 0; n < 4; ++n) bR0[n] = *(const bf16x8*)&smem[boff + n * 512];

#define STEPD(T, AC, BC, AN, BN2)                                                     \
    {                                                                                 \
        int t = (T);                                                                  \
        if (t + 3 < NT) stage((t + 3) & 3, t + 3);                                    \
        if (t + 3 < NT)      asm volatile("s_waitcnt vmcnt(8)" ::: "memory");         \
        else if (t + 2 < NT) asm volatile("s_waitcnt vmcnt(4)" ::: "memory");         \
        else if (t + 1 < NT) asm volatile("s_waitcnt vmcnt(0)" ::: "memory");         \
        __builtin_amdgcn_s_barrier();                                                 \
        const int sb = ((t + 1) & 3) * 8192;                                          \
        const bool pre = (t + 1 < NT);                                                \
        _Pragma("unroll")                                                             \
        for (int q = 0; q < 4; ++q) {                                                 \
            if (pre) {                                                                \
                AN[q] = *(const bf16x8*)&smem[sb + aoff + q * 512];                    \
                BN2[q] = *(const bf16x8*)&smem[sb + boff + q * 512];                   \
            }                                                                         \
            __builtin_amdgcn_s_setprio(1);                                            \
            _Pragma("unroll")                                                         \
            for (int n = 0; n < 4; ++n)                                               \
                acc[q][n] = __builtin_amdgcn_mfma_f32_16x16x32_bf16(AC[q], BC[n], acc[q][n], 0, 0, 0); \
            __builtin_amdgcn_s_setprio(0);                                            \
            __builtin_amdgcn_sched_barrier(0);                                        \
        }                                                                             \
        asm volatile("s_waitcnt lgkmcnt(0)" ::: "memory");                            \
        __builtin_amdgcn_sched_barrier(0);                                            \
    }

    for (int tt = 0; tt < NT; tt += 2) {
        STEPD(tt, aR0, bR0, aR1, bR1)
        STEPD(tt + 1, aR1, bR1, aR0, bR0)
    }
#undef STEPD

    __syncthreads();
    const int orow = (lane >> 4) * 4;
    const int ocol = lane & 15;
#pragma unroll
    for (int i = 0; i < 4; ++i)
#pragma unroll
        for (int j = 0; j < 4; ++j)
#pragma unroll
            for (int rj = 0; rj < 4; ++rj) {
                int lrow = wr * 64 + i * 16 + orow + rj;
                int lcol = wc * 64 + j * 16 + ocol;
                int n = q0 + lrow, m = c0 + lcol;
                float w = (n >= m) ? exp2f((float)(n - m) * LOG2_GAMMA) * KSCALE : 0.f;
                smem[lrow * 128 + lcol] = (short)f2bf(acc[i][j][rj] * w);
            }
    __syncthreads();
#pragma unroll
    for (int p = 0; p < 8; ++p) {
        int s = p * 256 + tid;
        int row = s >> 4;
        int cc = (s & 15) * 8;
        *(int4*)&Sb[(long long)(q0 + row) * SEQ + c0 + cc] = *(const int4*)&smem[row * 128 + cc];
    }
}

// ============ fused weight convert+transpose ============
__global__ __launch_bounds__(256) void wconv_all(
    const float* __restrict__ Wq, const float* __restrict__ Wk,
    const float* __restrict__ Wv, const float* __restrict__ Wg,
    const float* __restrict__ Wo, const float* __restrict__ W1,
    const float* __restrict__ W2,
    unsigned short* __restrict__ WqkvgT, unsigned short* __restrict__ WoT,
    unsigned short* __restrict__ W1T, unsigned short* __restrict__ W2T) {
    const long long dd = 512LL * 512;
    int z = blockIdx.z;
    int l = z / 7, w = z % 7;
    const float* src; unsigned short* dst; int K, N;
    switch (w) {
        case 0: src = Wq + l * dd; dst = WqkvgT + (long long)l * 4 * dd; K = 512; N = 512; break;
        case 1: src = Wk + l * dd; dst = WqkvgT + (long long)l * 4 * dd + dd; K = 512; N = 512; break;
        case 2: src = Wv + l * dd; dst = WqkvgT + (long long)l * 4 * dd + 2 * dd; K = 512; N = 512; break;
        case 3: src = Wg + l * dd; dst = WqkvgT + (long long)l * 4 * dd + 3 * dd; K = 512; N = 512; break;
        case 4: src = Wo + l * dd; dst = WoT + l * dd; K = 512; N = 512; break;
        case 5: src = W1 + (long long)l * 512 * 1024; dst = W1T + (long long)l * 512 * 1024; K = 512; N = 1024; break;
        default: src = W2 + (long long)l * 1024 * 512; dst = W2T + (long long)l * 1024 * 512; K = 1024; N = 512; break;
    }
    if ((int)blockIdx.x >= N / 64 || (int)blockIdx.y >= K / 64) return;
    __shared__ unsigned short t[64][65];
    int n0 = blockIdx.x * 64, k0 = blockIdx.y * 64;
    int tx = threadIdx.x & 63, ty = threadIdx.x >> 6;
#pragma unroll
    for (int i = 0; i < 16; ++i)
        t[ty + i * 4][tx] = f2bf(src[(long long)(k0 + ty + i * 4) * N + n0 + tx]);
    __syncthreads();
#pragma unroll
    for (int i = 0; i < 16; ++i)
        dst[(long long)(n0 + ty + i * 4) * K + k0 + tx] = t[tx][ty + i * 4];
}

// ============ fused residual-add + LayerNorm, all bf16 ============
template <int MODE>
__global__ __launch_bounds__(256) void ln_fuse(
    const void* __restrict__ hin_v,
    const unsigned short* __restrict__ delta,
    const float* __restrict__ g, const float* __restrict__ b,
    unsigned short* __restrict__ hout,
    unsigned short* __restrict__ y) {
    int row = blockIdx.x * 4 + (threadIdx.x >> 6);
    int t = threadIdx.x & 63;
    float f[8];
    if (MODE == 2) {
        const float4* r4 = (const float4*)((const float*)hin_v + (long long)row * D_MODEL);
        float4 v0 = r4[2 * t], v1 = r4[2 * t + 1];
        f[0] = v0.x; f[1] = v0.y; f[2] = v0.z; f[3] = v0.w;
        f[4] = v1.x; f[5] = v1.y; f[6] = v1.z; f[7] = v1.w;
    } else {
        const unsigned short* hin = (const unsigned short*)hin_v;
        int4 hv = ((const int4*)(hin + (long long)row * D_MODEL))[t];
        const unsigned short* hu = (const unsigned short*)&hv;
#pragma unroll
        for (int k = 0; k < 8; ++k) f[k] = bf2f(hu[k]);
    }
    if (MODE == 1) {
        int4 dv = ((const int4*)(delta + (long long)row * D_MODEL))[t];
        const unsigned short* du = (const unsigned short*)&dv;
#pragma unroll
        for (int k = 0; k < 8; ++k) f[k] += bf2f(du[k]);
    }
    float s = 0.f, s2 = 0.f;
#pragma unroll
    for (int k = 0; k < 8; ++k) { s += f[k]; s2 += f[k] * f[k]; }
#pragma unroll
    for (int off = 32; off > 0; off >>= 1) {
        s += __shfl_down(s, off);
        s2 += __shfl_down(s2, off);
    }
    s = __shfl(s, 0); s2 = __shfl(s2, 0);
    float mu = s * (1.f / D_MODEL);
    float var = s2 * (1.f / D_MODEL) - mu * mu;
    float rs = rsqrtf(var + 1e-6f);
    if (MODE >= 1) {
        ushort4 ho[2];
        unsigned short* hp = (unsigned short*)ho;
#pragma unroll
        for (int k = 0; k < 8; ++k) hp[k] = f2bf(f[k]);
        ((int4*)(hout + (long long)row * D_MODEL))[t] = *(int4*)ho;
    }
    const float4* g4 = (const float4*)g;
    const float4* b4 = (const float4*)b;
    float4 ga = g4[2 * t], gb2 = g4[2 * t + 1];
    float4 ba = b4[2 * t], bb2 = b4[2 * t + 1];
    float gg[8] = {ga.x, ga.y, ga.z, ga.w, gb2.x, gb2.y, gb2.z, gb2.w};
    float bb[8] = {ba.x, ba.y, ba.z, ba.w, bb2.x, bb2.y, bb2.z, bb2.w};
    ushort4 yo[2];
    unsigned short* yp = (unsigned short*)yo;
#pragma unroll
    for (int k = 0; k < 8; ++k) yp[k] = f2bf((f[k] - mu) * rs * gg[k] + bb[k]);
    ((int4*)(y + (long long)row * D_MODEL))[t] = *(int4*)yo;
}

// ============ gated = silu(g) * groupnorm(ret), all bf16 (g strided) ============
__global__ __launch_bounds__(256) void gate_bf16(const unsigned short* __restrict__ ret,
                                                 const unsigned short* __restrict__ g,
                                                 int gstride,
                                                 unsigned short* __restrict__ out) {
    int row = blockIdx.x * 4 + (threadIdx.x >> 6);
    int t = threadIdx.x & 63;
    int4 rv4 = ((const int4*)(ret + (long long)row * D_MODEL))[t];
    const unsigned short* ru = (const unsigned short*)&rv4;
    float f[8];
#pragma unroll
    for (int k = 0; k < 8; ++k) f[k] = bf2f(ru[k]);
    float s = 0.f, s2 = 0.f;
#pragma unroll
    for (int k = 0; k < 8; ++k) { s += f[k]; s2 += f[k] * f[k]; }
#pragma unroll
    for (int off = 32; off > 0; off >>= 1) {
        s += __shfl_down(s, off);
        s2 += __shfl_down(s2, off);
    }
    s = __shfl(s, 0); s2 = __shfl(s2, 0);
    float mu = s * (1.f / D_MODEL);
    float var = s2 * (1.f / D_MODEL) - mu * mu;
    float rs = rsqrtf(var + 1e-6f);
    int4 gv4 = ((const int4*)(g + (long long)row * gstride))[t];
    const unsigned short* gu = (const unsigned short*)&gv4;
    ushort4 o[2];
    unsigned short* op = (unsigned short*)o;
#pragma unroll
    for (int k = 0; k < 8; ++k) {
        float x = bf2f(gu[k]);
        op[k] = f2bf(x * sigm(x) * (f[k] - mu) * rs);
    }
    ((int4*)(out + (long long)row * D_MODEL))[t] = *(int4*)o;
}

// ============ pooled = sum_rows (h + dlast): two-stage ============
__global__ __launch_bounds__(256) void pool_s1(const unsigned short* __restrict__ h,
                                               const unsigned short* __restrict__ d,
                                               float* __restrict__ partial) {
    int b = blockIdx.x >> 4, g = blockIdx.x & 15;
    long long base = ((long long)b * SEQ + g * 64) * D_MODEL;
    int cw = (threadIdx.x & 63) * 8;
    int rg = threadIdx.x >> 6;
    float a[8] = {};
    for (int r = rg; r < 64; r += 4) {
        long long o = base + (long long)r * D_MODEL + cw;
        int4 hv = *(const int4*)&h[o];
        int4 dv = *(const int4*)&d[o];
        const unsigned short* hp = (const unsigned short*)&hv;
        const unsigned short* dp = (const unsigned short*)&dv;
#pragma unroll
        for (int j = 0; j < 8; ++j) a[j] += bf2f(hp[j]) + bf2f(dp[j]);
    }
    __shared__ float red[4][512];
#pragma unroll
    for (int j = 0; j < 8; ++j) red[rg][cw + j] = a[j];
    __syncthreads();
#pragma unroll
    for (int cc = 0; cc < 2; ++cc) {
        int c = threadIdx.x * 2 + cc;
        partial[(long long)blockIdx.x * D_MODEL + c] =
            red[0][c] + red[1][c] + red[2][c] + red[3][c];
    }
}

__global__ __launch_bounds__(256) void pool_s2(const float* __restrict__ partial,
                                               float* __restrict__ pooled) {
    int idx = blockIdx.x * 256 + threadIdx.x;  // 0..8191
    int b = idx >> 9, c = idx & 511;
    float s = 0.f;
#pragma unroll
    for (int g = 0; g < 16; ++g) s += partial[(long long)(b * 16 + g) * D_MODEL + c];
    pooled[idx] = s;
}

__global__ __launch_bounds__(64) void readout_kernel(const float* __restrict__ pooled,
                                                     const float* __restrict__ Wro,
                                                     const float* __restrict__ bro,
                                                     float* __restrict__ out) {
    int bo = blockIdx.x;
    int b = bo >> 1, o = bo & 1;
    int t = threadIdx.x;
    float s = 0.f;
    for (int i = t; i < D_MODEL; i += 64) s += pooled[b * D_MODEL + i] * Wro[i * 2 + o];
#pragma unroll
    for (int off = 32; off > 0; off >>= 1) s += __shfl_down(s, off);
    if (t == 0) out[b * 2 + o] = s + bro[o];
}

extern "C" void kernel_launch(void* const* d_in, const int* in_sizes, int n_in,
                              void* d_out, int out_size, void* d_ws, size_t ws_size,
                              hipStream_t stream) {
    const float* x = (const float*)d_in[0];
    const float* Wq = (const float*)d_in[1];
    const float* Wk = (const float*)d_in[2];
    const float* Wv = (const float*)d_in[3];
    const float* Wg = (const float*)d_in[4];
    const float* Wo = (const float*)d_in[5];
    const float* ln1_g = (const float*)d_in[6];
    const float* ln1_b = (const float*)d_in[7];
    const float* ln2_g = (const float*)d_in[8];
    const float* ln2_b = (const float*)d_in[9];
    const float* W1 = (const float*)d_in[10];
    const float* b1 = (const float*)d_in[11];
    const float* W2 = (const float*)d_in[12];
    const float* b2 = (const float*)d_in[13];
    const float* Wro = (const float*)d_in[14];
    const float* bro = (const float*)d_in[15];
    float* out = (float*)d_out;

    const long long NE = (long long)NROWS * D_MODEL;  // 8,388,608
    const long long dd = (long long)D_MODEL * D_MODEL;

    unsigned short* h = (unsigned short*)d_ws;   // NE
    unsigned short* y = h + NE;                  // NE
    unsigned short* qkvg = y + NE;               // 4*NE  [16384][2048]
    unsigned short* vT = qkvg + 4 * NE;          // NE    [16][512][1024]
    unsigned short* gated = vT;                  // alias (vT dead after ret GEMM)
    unsigned short* ret = vT + NE;               // NE    (also ffn-delta buffer)
    unsigned short* sg = ret + NE;               // 2*NE  scores / attn-delta / ffn-hidden
    float* pooled = (float*)(sg + 2 * NE);       // 8192 f32
    float* partial = pooled + 8192;              // 256*512 f32
    unsigned short* wts = (unsigned short*)(partial + 256 * 512);
    unsigned short* WqkvgT = wts;                          // [L][2048][512]
    unsigned short* WoT = WqkvgT + 2 * 4 * dd;             // [L][512][512]
    unsigned short* W1T = WoT + 2 * dd;                    // [L][1024][512]
    unsigned short* W2T = W1T + 2 * (long long)D_MODEL * HID;  // [L][512][1024]

    dim3 blk(256);
    wconv_all<<<dim3(16, 16, 14), blk, 0, stream>>>(Wq, Wk, Wv, Wg, Wo, W1, W2,
                                                    WqkvgT, WoT, W1T, W2T);

    for (int l = 0; l < 2; l++) {
        if (l == 0)
            ln_fuse<2><<<NROWS / 4, blk, 0, stream>>>(x, nullptr, ln1_g, ln1_b, h, y);
        else
            ln_fuse<1><<<NROWS / 4, blk, 0, stream>>>(h, ret, ln1_g + l * D_MODEL,
                                                      ln1_b + l * D_MODEL, h, y);
        // qkvg = y @ [Wq|Wk|Wv|Wg]; v-tiles write transposed into vT directly
        gemm256p<0, 1><<<512, 512, 0, stream>>>(
            (const short*)y, (const short*)(WqkvgT + (long long)l * 4 * dd), nullptr, qkvg,
            512, 512, 512, 2048, 8, vT);
        pdecay<<<dim3(8, 8, BATCH), blk, 0, stream>>>(
            (const short*)qkvg, (const short*)(qkvg + 512), sg, 2048, (long long)SEQ * 2048);
        // ret = scores @ v  (banded K window)
        pgemm64<0><<<dim3(8, 8, BATCH), blk, 0, stream>>>(
            (const short*)sg, (const short*)vT, nullptr, ret,
            SEQ, SEQ, SEQ, 512,
            (long long)SEQ * SEQ, (long long)D_MODEL * SEQ, (long long)SEQ * D_MODEL, 2);
        gate_bf16<<<NROWS / 4, blk, 0, stream>>>(ret, qkvg + 1536, 2048, gated);
        // attn delta = gated @ Wo  -> sg
        pgemm64<0><<<dim3(8, 128), blk, 0, stream>>>(
            (const short*)gated, (const short*)(WoT + l * dd), nullptr, sg,
            512, 512, 512, 512, 0, 0, 0, 0);
        // h += attn delta; y = LN2(h)
        ln_fuse<1><<<NROWS / 4, blk, 0, stream>>>(h, sg, ln2_g + l * D_MODEL,
                                                  ln2_b + l * D_MODEL, h, y);
        // hidden = gelu(y @ W1 + b1)
        gemm256p<2, 0><<<256, 512, 0, stream>>>(
            (const short*)y, (const short*)(W1T + (long long)l * D_MODEL * HID),
            b1 + l * HID, sg, 512, 512, 512, HID, 4, nullptr);
        // ffn delta = hidden @ W2 + b2 -> ret buffer
        pgemm64<1><<<dim3(8, 128), blk, 0, stream>>>(
            (const short*)sg, (const short*)(W2T + (long long)l * HID * D_MODEL),
            b2 + l * D_MODEL, ret, HID, HID, HID, 512, 0, 0, 0, 0);
    }

    pool_s1<<<256, blk, 0, stream>>>(h, ret, partial);
    pool_s2<<<32, blk, 0, stream>>>(partial, pooled);
    readout_kernel<<<32, 64, 0, stream>>>(pooled, Wro, bro, out);
}

// Round 11
// 486.291 us; speedup vs baseline: 6.7461x; 1.0744x over previous
//
#include <hip/hip_runtime.h>
#include <hip/hip_bf16.h>

// RetNet 2-layer forward. All-bf16 dataflow.
// MFMA GEMMs: ring-4 LDS, one barrier/K-step, counted vmcnt, conflict-free swizzle.
// Banded decay (tile-distance<=3) in pdecay + windowed K in ret GEMM.
// vT via standalone transpose kernel (fused epilogue regressed: R10 post-mortem).

#define D_MODEL 512
#define SEQ 1024
#define BATCH 16
#define NROWS (BATCH * SEQ)          // 16384
#define HID 1024
#define LOG2_GAMMA (-0.04580368961f)  // log2(0.96875)
#define KSCALE (0.044194173824f)      // 512^-0.5

typedef __attribute__((ext_vector_type(8))) short bf16x8;
typedef __attribute__((ext_vector_type(4))) float f32x4;

__device__ inline unsigned short f2bf(float x) {
    union { float f; unsigned u; } uu; uu.f = x;
    unsigned r = uu.u + 0x7fff + ((uu.u >> 16) & 1);
    return (unsigned short)(r >> 16);
}
__device__ inline float bf2f(unsigned short x) {
    union { unsigned u; float f; } uu; uu.u = ((unsigned)x) << 16; return uu.f;
}

__device__ inline void gload_lds16(const void* g, void* l) {
    __builtin_amdgcn_global_load_lds(
        (const __attribute__((address_space(1))) void*)g,
        (__attribute__((address_space(3))) void*)l, 16, 0, 0);
}

__device__ inline float sigm(float z) {
    return 1.f / (1.f + exp2f(z * -1.442695040888963f));
}
__device__ inline float gelu_fast(float x) {
    float y = 1.5957691216057308f * (x + 0.044715f * x * x * x);
    return x * sigm(y);
}

// ================== gemm256p: C[M,N] = A[M,K] @ B[N,K]^T, bf16 out ==================
template <int EPI>
__global__ __launch_bounds__(512, 2) void gemm256p(
    const short* __restrict__ A, const short* __restrict__ B,
    const float* __restrict__ bias, unsigned short* __restrict__ C,
    int K, int lda, int ldb, int ldc, int nbx) {
    __shared__ __align__(16) short smem[4 * 16384];
    const int tid = threadIdx.x;
    const int lane = tid & 63;
    const int wid = tid >> 6;
    const int wm = wid >> 2, wn = wid & 3;
    const int cpx = gridDim.x >> 3;
    const int wg = ((int)blockIdx.x & 7) * cpx + ((int)blockIdx.x >> 3);
    const int m0 = (wg / nbx) * 256;
    const int n0 = (wg % nbx) * 256;

    const int srow = tid >> 2;
    const int scol = (((tid & 3) ^ ((tid >> 3) & 3)) * 8);
    auto stage = [&](int slot, int t) {
        int k0 = t * 32;
#pragma unroll
        for (int r = 0; r < 2; ++r) {
            gload_lds16(A + (long long)(m0 + r * 128 + srow) * lda + k0 + scol,
                        &smem[slot * 16384 + r * 4096 + wid * 512]);
            gload_lds16(B + (long long)(n0 + r * 128 + srow) * ldb + k0 + scol,
                        &smem[slot * 16384 + 8192 + r * 4096 + wid * 512]);
        }
    };

    const int NT = K >> 5;
    f32x4 acc[8][4] = {};
    const int sw8 = (((lane >> 4) ^ ((lane >> 1) & 3)) * 8);
    const int aoff = (wm * 128 + (lane & 15)) * 32 + sw8;
    const int boff = 8192 + (wn * 64 + (lane & 15)) * 32 + sw8;

    bf16x8 aR0[8], bR0[4], aR1[8], bR1[4];
    stage(0, 0); stage(1, 1); stage(2, 2);
    asm volatile("s_waitcnt vmcnt(8)" ::: "memory");
    __builtin_amdgcn_s_barrier();
#pragma unroll
    for (int m = 0; m < 8; ++m) aR0[m] = *(const bf16x8*)&smem[aoff + m * 512];
#pragma unroll
    for (int n = 0; n < 4; ++n) bR0[n] = *(const bf16x8*)&smem[boff + n * 512];

#define STEP256(T, AC, BC, AN, BN2)                                                   \
    {                                                                                 \
        int t = (T);                                                                  \
        if (t + 3 < NT) stage((t + 3) & 3, t + 3);                                    \
        if (t + 3 < NT)      asm volatile("s_waitcnt vmcnt(8)" ::: "memory");         \
        else if (t + 2 < NT) asm volatile("s_waitcnt vmcnt(4)" ::: "memory");         \
        else if (t + 1 < NT) asm volatile("s_waitcnt vmcnt(0)" ::: "memory");         \
        __builtin_amdgcn_s_barrier();                                                 \
        const int sb = ((t + 1) & 3) * 16384;                                         \
        const bool pre = (t + 1 < NT);                                                \
        _Pragma("unroll")                                                             \
        for (int q = 0; q < 4; ++q) {                                                 \
            if (pre) {                                                                \
                AN[2 * q] = *(const bf16x8*)&smem[sb + aoff + (2 * q) * 512];          \
                AN[2 * q + 1] = *(const bf16x8*)&smem[sb + aoff + (2 * q + 1) * 512];  \
                BN2[q] = *(const bf16x8*)&smem[sb + boff + q * 512];                   \
            }                                                                         \
            __builtin_amdgcn_s_setprio(1);                                            \
            _Pragma("unroll")                                                         \
            for (int n = 0; n < 4; ++n) {                                             \
                acc[2 * q][n] = __builtin_amdgcn_mfma_f32_16x16x32_bf16(AC[2 * q], BC[n], acc[2 * q][n], 0, 0, 0); \
                acc[2 * q + 1][n] = __builtin_amdgcn_mfma_f32_16x16x32_bf16(AC[2 * q + 1], BC[n], acc[2 * q + 1][n], 0, 0, 0); \
            }                                                                         \
            __builtin_amdgcn_s_setprio(0);                                            \
            __builtin_amdgcn_sched_barrier(0);                                        \
        }                                                                             \
        asm volatile("s_waitcnt lgkmcnt(0)" ::: "memory");                            \
        __builtin_amdgcn_sched_barrier(0);                                            \
    }

    for (int tt = 0; tt < NT; tt += 2) {
        STEP256(tt, aR0, bR0, aR1, bR1)
        STEP256(tt + 1, aR1, bR1, aR0, bR0)
    }
#undef STEP256

    // ---- epilogue via LDS, vector stores ----
    const int ocol = lane & 15;
    const int orow4 = (lane >> 4) * 4;
    float bv[4];
    if (EPI == 2) {
#pragma unroll
        for (int n = 0; n < 4; ++n) bv[n] = bias[n0 + wn * 64 + n * 16 + ocol];
    }
#pragma unroll 1
    for (int half = 0; half < 2; ++half) {
        __syncthreads();
        if (wm == half) {
#pragma unroll
            for (int m = 0; m < 8; ++m)
#pragma unroll
                for (int n = 0; n < 4; ++n)
#pragma unroll
                    for (int rj = 0; rj < 4; ++rj) {
                        int lr = m * 16 + orow4 + rj;
                        int lc = wn * 64 + n * 16 + ocol;
                        float v = acc[m][n][rj];
                        if (EPI == 2) v = gelu_fast(v + bv[n]);
                        smem[lr * 256 + lc] = (short)f2bf(v);
                    }
        }
        __syncthreads();
#pragma unroll
        for (int p = 0; p < 8; ++p) {
            int s = p * 512 + tid;
            int row = s >> 5;
            int cc = (s & 31) * 8;
            *(int4*)&C[(long long)(m0 + half * 128 + row) * ldc + n0 + cc] =
                *(const int4*)&smem[row * 256 + cc];
        }
    }
}

// ================== pgemm64: BM=128, BN=64, 4 waves, ring-4 (48KB) ==================
// tri: 0 full K; 1 K in [0, m0+128); 2 K in [max(0,m0-384), m0+128)  (banded retention)
template <int EPI>
__global__ __launch_bounds__(256, 4) void pgemm64(
    const short* __restrict__ A, const short* __restrict__ B,
    const float* __restrict__ bias, unsigned short* __restrict__ C,
    int K, int lda, int ldb, int ldc,
    long long sA, long long sB, long long sC, int tri) {
    __shared__ __align__(16) short smem[4 * 6144];
    const int tid = threadIdx.x;
    const int lane = tid & 63;
    const int wid = tid >> 6;
    const int wr = wid;
    const int m0 = blockIdx.y * 128, n0 = blockIdx.x * 64;
    A += (long long)blockIdx.z * sA;
    B += (long long)blockIdx.z * sB;

    int Keff = K;
    int kstart = 0;
    if (tri) { int km = m0 + 128; if (km < Keff) Keff = km; }
    if (tri == 2) { int ks = m0 - 384; if (ks > 0) kstart = ks; }
    const int NT = (Keff - kstart) >> 5;

    auto stage = [&](int slot, int t) {
        int k0 = kstart + t * 32;
#pragma unroll
        for (int it = 0; it < 2; ++it) {
            int c = it * 256 + tid;
            int rr = c >> 2;
            int cc = ((c & 3) ^ ((c >> 3) & 3)) * 8;
            gload_lds16(A + (long long)(m0 + rr) * lda + k0 + cc,
                        &smem[slot * 6144 + (it * 256 + wid * 64) * 8]);
        }
        {
            int c = tid;
            int rr = c >> 2;
            int cc = ((c & 3) ^ ((c >> 3) & 3)) * 8;
            gload_lds16(B + (long long)(n0 + rr) * ldb + k0 + cc,
                        &smem[slot * 6144 + 4096 + (wid * 64) * 8]);
        }
    };

    f32x4 acc[2][4] = {};
    const int sw8 = (((lane >> 4) ^ ((lane >> 1) & 3)) * 8);
    const int aoff = (wr * 32 + (lane & 15)) * 32 + sw8;
    const int boff = 4096 + ((lane & 15)) * 32 + sw8;

    bf16x8 aR0[2], bR0[4], aR1[2], bR1[4];
    stage(0, 0); stage(1, 1); stage(2, 2);
    asm volatile("s_waitcnt vmcnt(6)" ::: "memory");
    __builtin_amdgcn_s_barrier();
#pragma unroll
    for (int m = 0; m < 2; ++m) aR0[m] = *(const bf16x8*)&smem[aoff + m * 512];
#pragma unroll
    for (int n = 0; n < 4; ++n) bR0[n] = *(const bf16x8*)&smem[boff + n * 512];

#define STEP64(T, AC, BC, AN, BN2)                                                    \
    {                                                                                 \
        int t = (T);                                                                  \
        if (t + 3 < NT) stage((t + 3) & 3, t + 3);                                    \
        if (t + 3 < NT)      asm volatile("s_waitcnt vmcnt(6)" ::: "memory");         \
        else if (t + 2 < NT) asm volatile("s_waitcnt vmcnt(3)" ::: "memory");         \
        else if (t + 1 < NT) asm volatile("s_waitcnt vmcnt(0)" ::: "memory");         \
        __builtin_amdgcn_s_barrier();                                                 \
        const int sb = ((t + 1) & 3) * 6144;                                          \
        const bool pre = (t + 1 < NT);                                                \
        _Pragma("unroll")                                                             \
        for (int q = 0; q < 2; ++q) {                                                 \
            if (pre) {                                                                \
                AN[q] = *(const bf16x8*)&smem[sb + aoff + q * 512];                    \
                BN2[2 * q] = *(const bf16x8*)&smem[sb + boff + (2 * q) * 512];         \
                BN2[2 * q + 1] = *(const bf16x8*)&smem[sb + boff + (2 * q + 1) * 512]; \
            }                                                                         \
            __builtin_amdgcn_s_setprio(1);                                            \
            _Pragma("unroll")                                                         \
            for (int m = 0; m < 2; ++m) {                                             \
                acc[m][2 * q] = __builtin_amdgcn_mfma_f32_16x16x32_bf16(AC[m], BC[2 * q], acc[m][2 * q], 0, 0, 0); \
                acc[m][2 * q + 1] = __builtin_amdgcn_mfma_f32_16x16x32_bf16(AC[m], BC[2 * q + 1], acc[m][2 * q + 1], 0, 0, 0); \
            }                                                                         \
            __builtin_amdgcn_s_setprio(0);                                            \
            __builtin_amdgcn_sched_barrier(0);                                        \
        }                                                                             \
        asm volatile("s_waitcnt lgkmcnt(0)" ::: "memory");                            \
        __builtin_amdgcn_sched_barrier(0);                                            \
    }

    for (int tt = 0; tt < NT; tt += 2) {
        STEP64(tt, aR0, bR0, aR1, bR1)
        STEP64(tt + 1, aR1, bR1, aR0, bR0)
    }
#undef STEP64

    __syncthreads();
    const int orow = (lane >> 4) * 4;
    const int ocol = lane & 15;
    float bv[4];
    if (EPI >= 1) {
#pragma unroll
        for (int j = 0; j < 4; ++j) bv[j] = bias[n0 + j * 16 + ocol];
    }
#pragma unroll
    for (int i = 0; i < 2; ++i)
#pragma unroll
        for (int j = 0; j < 4; ++j)
#pragma unroll
            for (int rj = 0; rj < 4; ++rj) {
                int lrow = wr * 32 + i * 16 + orow + rj;
                int lcol = j * 16 + ocol;
                float val = acc[i][j][rj];
                if (EPI == 1) val += bv[j];
                if (EPI == 2) val = gelu_fast(val + bv[j]);
                smem[lrow * 64 + lcol] = (short)f2bf(val);
            }
    __syncthreads();
    const long long zoff = (long long)blockIdx.z * sC;
#pragma unroll
    for (int p = 0; p < 4; ++p) {
        int s = p * 256 + tid;
        int row = s >> 3;
        int cc = (s & 7) * 8;
        *(int4*)&C[zoff + (long long)(m0 + row) * ldc + n0 + cc] = *(const int4*)&smem[row * 64 + cc];
    }
}

// ====== pdecay: scores = (q k^T) * gamma^(n-m) * KSCALE, banded (dist<=3 tiles) ======
__global__ __launch_bounds__(256, 2) void pdecay(
    const short* __restrict__ Q, const short* __restrict__ Kp,
    unsigned short* __restrict__ S, int lda, long long sA) {
    if (blockIdx.x > blockIdx.y) return;
    if (blockIdx.y > blockIdx.x + 3) return;   // gamma^385 ~ 5e-6: negligible
    const int q0 = blockIdx.y * 128;
    const int c0 = blockIdx.x * 128;
    unsigned short* Sb = S + (long long)blockIdx.z * SEQ * SEQ;
    __shared__ __align__(16) short smem[4 * 8192];
    const int tid = threadIdx.x;
    const int lane = tid & 63;
    const int wid = tid >> 6;
    const int wr = wid >> 1, wc = wid & 1;
    const short* Ab = Q + (long long)blockIdx.z * sA;
    const short* Bb = Kp + (long long)blockIdx.z * sA;

    auto stage = [&](int slot, int t) {
        int k0 = t * 32;
#pragma unroll
        for (int it = 0; it < 2; ++it) {
            int c = it * 256 + tid;
            int rr = c >> 2;
            int cc = ((c & 3) ^ ((c >> 3) & 3)) * 8;
            gload_lds16(Ab + (long long)(q0 + rr) * lda + k0 + cc,
                        &smem[slot * 8192 + (it * 256 + wid * 64) * 8]);
            gload_lds16(Bb + (long long)(c0 + rr) * lda + k0 + cc,
                        &smem[slot * 8192 + 4096 + (it * 256 + wid * 64) * 8]);
        }
    };

    const int NT = D_MODEL / 32;   // 16
    f32x4 acc[4][4] = {};
    const int sw8 = (((lane >> 4) ^ ((lane >> 1) & 3)) * 8);
    const int aoff = (wr * 64 + (lane & 15)) * 32 + sw8;
    const int boff = 4096 + (wc * 64 + (lane & 15)) * 32 + sw8;

    bf16x8 aR0[4], bR0[4], aR1[4], bR1[4];
    stage(0, 0); stage(1, 1); stage(2, 2);
    asm volatile("s_waitcnt vmcnt(8)" ::: "memory");
    __builtin_amdgcn_s_barrier();
#pragma unroll
    for (int m = 0; m < 4; ++m) aR0[m] = *(const bf16x8*)&smem[aoff + m * 512];
#pragma unroll
    for (int n = 0; n < 4; ++n) bR0[n] = *(const bf16x8*)&smem[boff + n * 512];

#define STEPD(T, AC, BC, AN, BN2)                                                     \
    {                                                                                 \
        int t = (T);                                                                  \
        if (t + 3 < NT) stage((t + 3) & 3, t + 3);                                    \
        if (t + 3 < NT)      asm volatile("s_waitcnt vmcnt(8)" ::: "memory");         \
        else if (t + 2 < NT) asm volatile("s_waitcnt vmcnt(4)" ::: "memory");         \
        else if (t + 1 < NT) asm volatile("s_waitcnt vmcnt(0)" ::: "memory");         \
        __builtin_amdgcn_s_barrier();                                                 \
        const int sb = ((t + 1) & 3) * 8192;                                          \
        const bool pre = (t + 1 < NT);                                                \
        _Pragma("unroll")                                                             \
        for (int q = 0; q < 4; ++q) {                                                 \
            if (pre) {                                                                \
                AN[q] = *(const bf16x8*)&smem[sb + aoff + q * 512];                    \
                BN2[q] = *(const bf16x8*)&smem[sb + boff + q * 512];                   \
            }                                                                         \
            __builtin_amdgcn_s_setprio(1);                                            \
            _Pragma("unroll")                                                         \
            for (int n = 0; n < 4; ++n)                                               \
                acc[q][n] = __builtin_amdgcn_mfma_f32_16x16x32_bf16(AC[q], BC[n], acc[q][n], 0, 0, 0); \
            __builtin_amdgcn_s_setprio(0);                                            \
            __builtin_amdgcn_sched_barrier(0);                                        \
        }                                                                             \
        asm volatile("s_waitcnt lgkmcnt(0)" ::: "memory");                            \
        __builtin_amdgcn_sched_barrier(0);                                            \
    }

    for (int tt = 0; tt < NT; tt += 2) {
        STEPD(tt, aR0, bR0, aR1, bR1)
        STEPD(tt + 1, aR1, bR1, aR0, bR0)
    }
#undef STEPD

    __syncthreads();
    const int orow = (lane >> 4) * 4;
    const int ocol = lane & 15;
#pragma unroll
    for (int i = 0; i < 4; ++i)
#pragma unroll
        for (int j = 0; j < 4; ++j)
#pragma unroll
            for (int rj = 0; rj < 4; ++rj) {
                int lrow = wr * 64 + i * 16 + orow + rj;
                int lcol = wc * 64 + j * 16 + ocol;
                int n = q0 + lrow, m = c0 + lcol;
                float w = (n >= m) ? exp2f((float)(n - m) * LOG2_GAMMA) * KSCALE : 0.f;
                smem[lrow * 128 + lcol] = (short)f2bf(acc[i][j][rj] * w);
            }
    __syncthreads();
#pragma unroll
    for (int p = 0; p < 8; ++p) {
        int s = p * 256 + tid;
        int row = s >> 4;
        int cc = (s & 15) * 8;
        *(int4*)&Sb[(long long)(q0 + row) * SEQ + c0 + cc] = *(const int4*)&smem[row * 128 + cc];
    }
}

// ============ fused weight convert+transpose ============
__global__ __launch_bounds__(256) void wconv_all(
    const float* __restrict__ Wq, const float* __restrict__ Wk,
    const float* __restrict__ Wv, const float* __restrict__ Wg,
    const float* __restrict__ Wo, const float* __restrict__ W1,
    const float* __restrict__ W2,
    unsigned short* __restrict__ WqkvgT, unsigned short* __restrict__ WoT,
    unsigned short* __restrict__ W1T, unsigned short* __restrict__ W2T) {
    const long long dd = 512LL * 512;
    int z = blockIdx.z;
    int l = z / 7, w = z % 7;
    const float* src; unsigned short* dst; int K, N;
    switch (w) {
        case 0: src = Wq + l * dd; dst = WqkvgT + (long long)l * 4 * dd; K = 512; N = 512; break;
        case 1: src = Wk + l * dd; dst = WqkvgT + (long long)l * 4 * dd + dd; K = 512; N = 512; break;
        case 2: src = Wv + l * dd; dst = WqkvgT + (long long)l * 4 * dd + 2 * dd; K = 512; N = 512; break;
        case 3: src = Wg + l * dd; dst = WqkvgT + (long long)l * 4 * dd + 3 * dd; K = 512; N = 512; break;
        case 4: src = Wo + l * dd; dst = WoT + l * dd; K = 512; N = 512; break;
        case 5: src = W1 + (long long)l * 512 * 1024; dst = W1T + (long long)l * 512 * 1024; K = 512; N = 1024; break;
        default: src = W2 + (long long)l * 1024 * 512; dst = W2T + (long long)l * 1024 * 512; K = 1024; N = 512; break;
    }
    if ((int)blockIdx.x >= N / 64 || (int)blockIdx.y >= K / 64) return;
    __shared__ unsigned short t[64][65];
    int n0 = blockIdx.x * 64, k0 = blockIdx.y * 64;
    int tx = threadIdx.x & 63, ty = threadIdx.x >> 6;
#pragma unroll
    for (int i = 0; i < 16; ++i)
        t[ty + i * 4][tx] = f2bf(src[(long long)(k0 + ty + i * 4) * N + n0 + tx]);
    __syncthreads();
#pragma unroll
    for (int i = 0; i < 16; ++i)
        dst[(long long)(n0 + ty + i * 4) * K + k0 + tx] = t[tx][ty + i * 4];
}

// ============ per-batch transpose: bf16 [SEQ][*stride slice] -> [D][SEQ] ============
__global__ __launch_bounds__(256) void vtrans(const unsigned short* __restrict__ in,
                                              unsigned short* __restrict__ out, int istride) {
    __shared__ unsigned short t[64][65];
    const unsigned short* pin = in + (long long)blockIdx.z * SEQ * istride;
    unsigned short* pout = out + (long long)blockIdx.z * D_MODEL * SEQ;
    int c0 = blockIdx.x * 64, r0 = blockIdx.y * 64;
    int tx = threadIdx.x & 63, ty = threadIdx.x >> 6;
#pragma unroll
    for (int i = 0; i < 16; ++i)
        t[ty + i * 4][tx] = pin[(long long)(r0 + ty + i * 4) * istride + c0 + tx];
    __syncthreads();
#pragma unroll
    for (int i = 0; i < 16; ++i)
        pout[(long long)(c0 + ty + i * 4) * SEQ + r0 + tx] = t[tx][ty + i * 4];
}

// ============ fused residual-add + LayerNorm, all bf16 ============
template <int MODE>
__global__ __launch_bounds__(256) void ln_fuse(
    const void* __restrict__ hin_v,
    const unsigned short* __restrict__ delta,
    const float* __restrict__ g, const float* __restrict__ b,
    unsigned short* __restrict__ hout,
    unsigned short* __restrict__ y) {
    int row = blockIdx.x * 4 + (threadIdx.x >> 6);
    int t = threadIdx.x & 63;
    float f[8];
    if (MODE == 2) {
        const float4* r4 = (const float4*)((const float*)hin_v + (long long)row * D_MODEL);
        float4 v0 = r4[2 * t], v1 = r4[2 * t + 1];
        f[0] = v0.x; f[1] = v0.y; f[2] = v0.z; f[3] = v0.w;
        f[4] = v1.x; f[5] = v1.y; f[6] = v1.z; f[7] = v1.w;
    } else {
        const unsigned short* hin = (const unsigned short*)hin_v;
        int4 hv = ((const int4*)(hin + (long long)row * D_MODEL))[t];
        const unsigned short* hu = (const unsigned short*)&hv;
#pragma unroll
        for (int k = 0; k < 8; ++k) f[k] = bf2f(hu[k]);
    }
    if (MODE == 1) {
        int4 dv = ((const int4*)(delta + (long long)row * D_MODEL))[t];
        const unsigned short* du = (const unsigned short*)&dv;
#pragma unroll
        for (int k = 0; k < 8; ++k) f[k] += bf2f(du[k]);
    }
    float s = 0.f, s2 = 0.f;
#pragma unroll
    for (int k = 0; k < 8; ++k) { s += f[k]; s2 += f[k] * f[k]; }
#pragma unroll
    for (int off = 32; off > 0; off >>= 1) {
        s += __shfl_down(s, off);
        s2 += __shfl_down(s2, off);
    }
    s = __shfl(s, 0); s2 = __shfl(s2, 0);
    float mu = s * (1.f / D_MODEL);
    float var = s2 * (1.f / D_MODEL) - mu * mu;
    float rs = rsqrtf(var + 1e-6f);
    if (MODE >= 1) {
        ushort4 ho[2];
        unsigned short* hp = (unsigned short*)ho;
#pragma unroll
        for (int k = 0; k < 8; ++k) hp[k] = f2bf(f[k]);
        ((int4*)(hout + (long long)row * D_MODEL))[t] = *(int4*)ho;
    }
    const float4* g4 = (const float4*)g;
    const float4* b4 = (const float4*)b;
    float4 ga = g4[2 * t], gb2 = g4[2 * t + 1];
    float4 ba = b4[2 * t], bb2 = b4[2 * t + 1];
    float gg[8] = {ga.x, ga.y, ga.z, ga.w, gb2.x, gb2.y, gb2.z, gb2.w};
    float bb[8] = {ba.x, ba.y, ba.z, ba.w, bb2.x, bb2.y, bb2.z, bb2.w};
    ushort4 yo[2];
    unsigned short* yp = (unsigned short*)yo;
#pragma unroll
    for (int k = 0; k < 8; ++k) yp[k] = f2bf((f[k] - mu) * rs * gg[k] + bb[k]);
    ((int4*)(y + (long long)row * D_MODEL))[t] = *(int4*)yo;
}

// ============ gated = silu(g) * groupnorm(ret), all bf16 (g strided) ============
__global__ __launch_bounds__(256) void gate_bf16(const unsigned short* __restrict__ ret,
                                                 const unsigned short* __restrict__ g,
                                                 int gstride,
                                                 unsigned short* __restrict__ out) {
    int row = blockIdx.x * 4 + (threadIdx.x >> 6);
    int t = threadIdx.x & 63;
    int4 rv4 = ((const int4*)(ret + (long long)row * D_MODEL))[t];
    const unsigned short* ru = (const unsigned short*)&rv4;
    float f[8];
#pragma unroll
    for (int k = 0; k < 8; ++k) f[k] = bf2f(ru[k]);
    float s = 0.f, s2 = 0.f;
#pragma unroll
    for (int k = 0; k < 8; ++k) { s += f[k]; s2 += f[k] * f[k]; }
#pragma unroll
    for (int off = 32; off > 0; off >>= 1) {
        s += __shfl_down(s, off);
        s2 += __shfl_down(s2, off);
    }
    s = __shfl(s, 0); s2 = __shfl(s2, 0);
    float mu = s * (1.f / D_MODEL);
    float var = s2 * (1.f / D_MODEL) - mu * mu;
    float rs = rsqrtf(var + 1e-6f);
    int4 gv4 = ((const int4*)(g + (long long)row * gstride))[t];
    const unsigned short* gu = (const unsigned short*)&gv4;
    ushort4 o[2];
    unsigned short* op = (unsigned short*)o;
#pragma unroll
    for (int k = 0; k < 8; ++k) {
        float x = bf2f(gu[k]);
        op[k] = f2bf(x * sigm(x) * (f[k] - mu) * rs);
    }
    ((int4*)(out + (long long)row * D_MODEL))[t] = *(int4*)o;
}

// ============ pooled = sum_rows (h + dlast): two-stage ============
__global__ __launch_bounds__(256) void pool_s1(const unsigned short* __restrict__ h,
                                               const unsigned short* __restrict__ d,
                                               float* __restrict__ partial) {
    int b = blockIdx.x >> 4, g = blockIdx.x & 15;
    long long base = ((long long)b * SEQ + g * 64) * D_MODEL;
    int cw = (threadIdx.x & 63) * 8;
    int rg = threadIdx.x >> 6;
    float a[8] = {};
    for (int r = rg; r < 64; r += 4) {
        long long o = base + (long long)r * D_MODEL + cw;
        int4 hv = *(const int4*)&h[o];
        int4 dv = *(const int4*)&d[o];
        const unsigned short* hp = (const unsigned short*)&hv;
        const unsigned short* dp = (const unsigned short*)&dv;
#pragma unroll
        for (int j = 0; j < 8; ++j) a[j] += bf2f(hp[j]) + bf2f(dp[j]);
    }
    __shared__ float red[4][512];
#pragma unroll
    for (int j = 0; j < 8; ++j) red[rg][cw + j] = a[j];
    __syncthreads();
#pragma unroll
    for (int cc = 0; cc < 2; ++cc) {
        int c = threadIdx.x * 2 + cc;
        partial[(long long)blockIdx.x * D_MODEL + c] =
            red[0][c] + red[1][c] + red[2][c] + red[3][c];
    }
}

__global__ __launch_bounds__(256) void pool_s2(const float* __restrict__ partial,
                                               float* __restrict__ pooled) {
    int idx = blockIdx.x * 256 + threadIdx.x;  // 0..8191
    int b = idx >> 9, c = idx & 511;
    float s = 0.f;
#pragma unroll
    for (int g = 0; g < 16; ++g) s += partial[(long long)(b * 16 + g) * D_MODEL + c];
    pooled[idx] = s;
}

__global__ __launch_bounds__(64) void readout_kernel(const float* __restrict__ pooled,
                                                     const float* __restrict__ Wro,
                                                     const float* __restrict__ bro,
                                                     float* __restrict__ out) {
    int bo = blockIdx.x;
    int b = bo >> 1, o = bo & 1;
    int t = threadIdx.x;
    float s = 0.f;
    for (int i = t; i < D_MODEL; i += 64) s += pooled[b * D_MODEL + i] * Wro[i * 2 + o];
#pragma unroll
    for (int off = 32; off > 0; off >>= 1) s += __shfl_down(s, off);
    if (t == 0) out[b * 2 + o] = s + bro[o];
}

extern "C" void kernel_launch(void* const* d_in, const int* in_sizes, int n_in,
                              void* d_out, int out_size, void* d_ws, size_t ws_size,
                              hipStream_t stream) {
    const float* x = (const float*)d_in[0];
    const float* Wq = (const float*)d_in[1];
    const float* Wk = (const float*)d_in[2];
    const float* Wv = (const float*)d_in[3];
    const float* Wg = (const float*)d_in[4];
    const float* Wo = (const float*)d_in[5];
    const float* ln1_g = (const float*)d_in[6];
    const float* ln1_b = (const float*)d_in[7];
    const float* ln2_g = (const float*)d_in[8];
    const float* ln2_b = (const float*)d_in[9];
    const float* W1 = (const float*)d_in[10];
    const float* b1 = (const float*)d_in[11];
    const float* W2 = (const float*)d_in[12];
    const float* b2 = (const float*)d_in[13];
    const float* Wro = (const float*)d_in[14];
    const float* bro = (const float*)d_in[15];
    float* out = (float*)d_out;

    const long long NE = (long long)NROWS * D_MODEL;  // 8,388,608
    const long long dd = (long long)D_MODEL * D_MODEL;

    unsigned short* h = (unsigned short*)d_ws;   // NE
    unsigned short* y = h + NE;                  // NE
    unsigned short* qkvg = y + NE;               // 4*NE  [16384][2048]
    unsigned short* vT = qkvg + 4 * NE;          // NE    [16][512][1024]
    unsigned short* gated = vT;                  // alias (vT dead after ret GEMM)
    unsigned short* ret = vT + NE;               // NE    (also ffn-delta buffer)
    unsigned short* sg = ret + NE;               // 2*NE  scores / attn-delta / ffn-hidden
    float* pooled = (float*)(sg + 2 * NE);       // 8192 f32
    float* partial = pooled + 8192;              // 256*512 f32
    unsigned short* wts = (unsigned short*)(partial + 256 * 512);
    unsigned short* WqkvgT = wts;                          // [L][2048][512]
    unsigned short* WoT = WqkvgT + 2 * 4 * dd;             // [L][512][512]
    unsigned short* W1T = WoT + 2 * dd;                    // [L][1024][512]
    unsigned short* W2T = W1T + 2 * (long long)D_MODEL * HID;  // [L][512][1024]

    dim3 blk(256);
    wconv_all<<<dim3(16, 16, 14), blk, 0, stream>>>(Wq, Wk, Wv, Wg, Wo, W1, W2,
                                                    WqkvgT, WoT, W1T, W2T);

    for (int l = 0; l < 2; l++) {
        if (l == 0)
            ln_fuse<2><<<NROWS / 4, blk, 0, stream>>>(x, nullptr, ln1_g, ln1_b, h, y);
        else
            ln_fuse<1><<<NROWS / 4, blk, 0, stream>>>(h, ret, ln1_g + l * D_MODEL,
                                                      ln1_b + l * D_MODEL, h, y);
        // qkvg = y @ [Wq|Wk|Wv|Wg]
        gemm256p<0><<<512, 512, 0, stream>>>(
            (const short*)y, (const short*)(WqkvgT + (long long)l * 4 * dd), nullptr, qkvg,
            512, 512, 512, 2048, 8);
        vtrans<<<dim3(8, 16, BATCH), blk, 0, stream>>>(qkvg + 1024, vT, 2048);
        pdecay<<<dim3(8, 8, BATCH), blk, 0, stream>>>(
            (const short*)qkvg, (const short*)(qkvg + 512), sg, 2048, (long long)SEQ * 2048);
        // ret = scores @ v  (banded K window)
        pgemm64<0><<<dim3(8, 8, BATCH), blk, 0, stream>>>(
            (const short*)sg, (const short*)vT, nullptr, ret,
            SEQ, SEQ, SEQ, 512,
            (long long)SEQ * SEQ, (long long)D_MODEL * SEQ, (long long)SEQ * D_MODEL, 2);
        gate_bf16<<<NROWS / 4, blk, 0, stream>>>(ret, qkvg + 1536, 2048, gated);
        // attn delta = gated @ Wo  -> sg
        pgemm64<0><<<dim3(8, 128), blk, 0, stream>>>(
            (const short*)gated, (const short*)(WoT + l * dd), nullptr, sg,
            512, 512, 512, 512, 0, 0, 0, 0);
        // h += attn delta; y = LN2(h)
        ln_fuse<1><<<NROWS / 4, blk, 0, stream>>>(h, sg, ln2_g + l * D_MODEL,
                                                  ln2_b + l * D_MODEL, h, y);
        // hidden = gelu(y @ W1 + b1)
        gemm256p<2><<<256, 512, 0, stream>>>(
            (const short*)y, (const short*)(W1T + (long long)l * D_MODEL * HID),
            b1 + l * HID, sg, 512, 512, 512, HID, 4);
        // ffn delta = hidden @ W2 + b2 -> ret buffer
        pgemm64<1><<<dim3(8, 128), blk, 0, stream>>>(
            (const short*)sg, (const short*)(W2T + (long long)l * HID * D_MODEL),
            b2 + l * D_MODEL, ret, HID, HID, HID, 512, 0, 0, 0, 0);
    }

    pool_s1<<<256, blk, 0, stream>>>(h, ret, partial);
    pool_s2<<<32, blk, 0, stream>>>(partial, pooled);
    readout_kernel<<<32, 64, 0, stream>>>(pooled, Wro, bro, out);
}

// Round 12
// 443.350 us; speedup vs baseline: 7.3995x; 1.0969x over previous
//
#include <hip/hip_runtime.h>
#include <hip/hip_bf16.h>

// RetNet 2-layer forward. All-bf16 dataflow.
// MFMA GEMMs: ring-4 LDS, one barrier/K-step, counted vmcnt, conflict-free swizzle.
// Banded decay (tile-distance<=3). pgemm128: 128x128 tile (pdecay geometry) for
// ret/Wo/FF2 (replaces BN=64 tile: R11 post-mortem — low MFMA density).

#define D_MODEL 512
#define SEQ 1024
#define BATCH 16
#define NROWS (BATCH * SEQ)          // 16384
#define HID 1024
#define LOG2_GAMMA (-0.04580368961f)  // log2(0.96875)
#define KSCALE (0.044194173824f)      // 512^-0.5

typedef __attribute__((ext_vector_type(8))) short bf16x8;
typedef __attribute__((ext_vector_type(4))) float f32x4;

__device__ inline unsigned short f2bf(float x) {
    union { float f; unsigned u; } uu; uu.f = x;
    unsigned r = uu.u + 0x7fff + ((uu.u >> 16) & 1);
    return (unsigned short)(r >> 16);
}
__device__ inline float bf2f(unsigned short x) {
    union { unsigned u; float f; } uu; uu.u = ((unsigned)x) << 16; return uu.f;
}

__device__ inline void gload_lds16(const void* g, void* l) {
    __builtin_amdgcn_global_load_lds(
        (const __attribute__((address_space(1))) void*)g,
        (__attribute__((address_space(3))) void*)l, 16, 0, 0);
}

__device__ inline float sigm(float z) {
    return 1.f / (1.f + exp2f(z * -1.442695040888963f));
}
__device__ inline float gelu_fast(float x) {
    float y = 1.5957691216057308f * (x + 0.044715f * x * x * x);
    return x * sigm(y);
}

// ================== gemm256p: C[M,N] = A[M,K] @ B[N,K]^T, bf16 out ==================
template <int EPI>
__global__ __launch_bounds__(512, 2) void gemm256p(
    const short* __restrict__ A, const short* __restrict__ B,
    const float* __restrict__ bias, unsigned short* __restrict__ C,
    int K, int lda, int ldb, int ldc, int nbx) {
    __shared__ __align__(16) short smem[4 * 16384];
    const int tid = threadIdx.x;
    const int lane = tid & 63;
    const int wid = tid >> 6;
    const int wm = wid >> 2, wn = wid & 3;
    const int cpx = gridDim.x >> 3;
    const int wg = ((int)blockIdx.x & 7) * cpx + ((int)blockIdx.x >> 3);
    const int m0 = (wg / nbx) * 256;
    const int n0 = (wg % nbx) * 256;

    const int srow = tid >> 2;
    const int scol = (((tid & 3) ^ ((tid >> 3) & 3)) * 8);
    auto stage = [&](int slot, int t) {
        int k0 = t * 32;
#pragma unroll
        for (int r = 0; r < 2; ++r) {
            gload_lds16(A + (long long)(m0 + r * 128 + srow) * lda + k0 + scol,
                        &smem[slot * 16384 + r * 4096 + wid * 512]);
            gload_lds16(B + (long long)(n0 + r * 128 + srow) * ldb + k0 + scol,
                        &smem[slot * 16384 + 8192 + r * 4096 + wid * 512]);
        }
    };

    const int NT = K >> 5;
    f32x4 acc[8][4] = {};
    const int sw8 = (((lane >> 4) ^ ((lane >> 1) & 3)) * 8);
    const int aoff = (wm * 128 + (lane & 15)) * 32 + sw8;
    const int boff = 8192 + (wn * 64 + (lane & 15)) * 32 + sw8;

    bf16x8 aR0[8], bR0[4], aR1[8], bR1[4];
    stage(0, 0); stage(1, 1); stage(2, 2);
    asm volatile("s_waitcnt vmcnt(8)" ::: "memory");
    __builtin_amdgcn_s_barrier();
#pragma unroll
    for (int m = 0; m < 8; ++m) aR0[m] = *(const bf16x8*)&smem[aoff + m * 512];
#pragma unroll
    for (int n = 0; n < 4; ++n) bR0[n] = *(const bf16x8*)&smem[boff + n * 512];

#define STEP256(T, AC, BC, AN, BN2)                                                   \
    {                                                                                 \
        int t = (T);                                                                  \
        if (t + 3 < NT) stage((t + 3) & 3, t + 3);                                    \
        if (t + 3 < NT)      asm volatile("s_waitcnt vmcnt(8)" ::: "memory");         \
        else if (t + 2 < NT) asm volatile("s_waitcnt vmcnt(4)" ::: "memory");         \
        else if (t + 1 < NT) asm volatile("s_waitcnt vmcnt(0)" ::: "memory");         \
        __builtin_amdgcn_s_barrier();                                                 \
        const int sb = ((t + 1) & 3) * 16384;                                         \
        const bool pre = (t + 1 < NT);                                                \
        _Pragma("unroll")                                                             \
        for (int q = 0; q < 4; ++q) {                                                 \
            if (pre) {                                                                \
                AN[2 * q] = *(const bf16x8*)&smem[sb + aoff + (2 * q) * 512];          \
                AN[2 * q + 1] = *(const bf16x8*)&smem[sb + aoff + (2 * q + 1) * 512];  \
                BN2[q] = *(const bf16x8*)&smem[sb + boff + q * 512];                   \
            }                                                                         \
            __builtin_amdgcn_s_setprio(1);                                            \
            _Pragma("unroll")                                                         \
            for (int n = 0; n < 4; ++n) {                                             \
                acc[2 * q][n] = __builtin_amdgcn_mfma_f32_16x16x32_bf16(AC[2 * q], BC[n], acc[2 * q][n], 0, 0, 0); \
                acc[2 * q + 1][n] = __builtin_amdgcn_mfma_f32_16x16x32_bf16(AC[2 * q + 1], BC[n], acc[2 * q + 1][n], 0, 0, 0); \
            }                                                                         \
            __builtin_amdgcn_s_setprio(0);                                            \
            __builtin_amdgcn_sched_barrier(0);                                        \
        }                                                                             \
        asm volatile("s_waitcnt lgkmcnt(0)" ::: "memory");                            \
        __builtin_amdgcn_sched_barrier(0);                                            \
    }

    for (int tt = 0; tt < NT; tt += 2) {
        STEP256(tt, aR0, bR0, aR1, bR1)
        STEP256(tt + 1, aR1, bR1, aR0, bR0)
    }
#undef STEP256

    // ---- epilogue via LDS, vector stores ----
    const int ocol = lane & 15;
    const int orow4 = (lane >> 4) * 4;
    float bv[4];
    if (EPI == 2) {
#pragma unroll
        for (int n = 0; n < 4; ++n) bv[n] = bias[n0 + wn * 64 + n * 16 + ocol];
    }
#pragma unroll 1
    for (int half = 0; half < 2; ++half) {
        __syncthreads();
        if (wm == half) {
#pragma unroll
            for (int m = 0; m < 8; ++m)
#pragma unroll
                for (int n = 0; n < 4; ++n)
#pragma unroll
                    for (int rj = 0; rj < 4; ++rj) {
                        int lr = m * 16 + orow4 + rj;
                        int lc = wn * 64 + n * 16 + ocol;
                        float v = acc[m][n][rj];
                        if (EPI == 2) v = gelu_fast(v + bv[n]);
                        smem[lr * 256 + lc] = (short)f2bf(v);
                    }
        }
        __syncthreads();
#pragma unroll
        for (int p = 0; p < 8; ++p) {
            int s = p * 512 + tid;
            int row = s >> 5;
            int cc = (s & 31) * 8;
            *(int4*)&C[(long long)(m0 + half * 128 + row) * ldc + n0 + cc] =
                *(const int4*)&smem[row * 256 + cc];
        }
    }
}

// ========== pgemm128: BM=128, BN=128, 4 waves (2x2), ring-4 (64KB), 2 blk/CU ==========
// EPI: 0 plain, 1 acc+bias, 2 gelu(acc+bias).
// tri: 0 full K; 1 K in [0, m0+128); 2 K in [max(0,m0-384), m0+128)  (banded retention)
template <int EPI>
__global__ __launch_bounds__(256, 2) void pgemm128(
    const short* __restrict__ A, const short* __restrict__ B,
    const float* __restrict__ bias, unsigned short* __restrict__ C,
    int K, int lda, int ldb, int ldc,
    long long sA, long long sB, long long sC, int tri) {
    __shared__ __align__(16) short smem[4 * 8192];
    const int tid = threadIdx.x;
    const int lane = tid & 63;
    const int wid = tid >> 6;
    const int wr = wid >> 1, wc = wid & 1;
    const int m0 = blockIdx.y * 128, n0 = blockIdx.x * 128;
    A += (long long)blockIdx.z * sA;
    B += (long long)blockIdx.z * sB;

    int Keff = K;
    int kstart = 0;
    if (tri) { int km = m0 + 128; if (km < Keff) Keff = km; }
    if (tri == 2) { int ks = m0 - 384; if (ks > 0) kstart = ks; }
    const int NT = (Keff - kstart) >> 5;

    auto stage = [&](int slot, int t) {
        int k0 = kstart + t * 32;
#pragma unroll
        for (int it = 0; it < 2; ++it) {
            int c = it * 256 + tid;
            int rr = c >> 2;
            int cc = ((c & 3) ^ ((c >> 3) & 3)) * 8;
            gload_lds16(A + (long long)(m0 + rr) * lda + k0 + cc,
                        &smem[slot * 8192 + (it * 256 + wid * 64) * 8]);
            gload_lds16(B + (long long)(n0 + rr) * ldb + k0 + cc,
                        &smem[slot * 8192 + 4096 + (it * 256 + wid * 64) * 8]);
        }
    };

    f32x4 acc[4][4] = {};
    const int sw8 = (((lane >> 4) ^ ((lane >> 1) & 3)) * 8);
    const int aoff = (wr * 64 + (lane & 15)) * 32 + sw8;
    const int boff = 4096 + (wc * 64 + (lane & 15)) * 32 + sw8;

    bf16x8 aR0[4], bR0[4], aR1[4], bR1[4];
    stage(0, 0); stage(1, 1); stage(2, 2);
    asm volatile("s_waitcnt vmcnt(8)" ::: "memory");
    __builtin_amdgcn_s_barrier();
#pragma unroll
    for (int m = 0; m < 4; ++m) aR0[m] = *(const bf16x8*)&smem[aoff + m * 512];
#pragma unroll
    for (int n = 0; n < 4; ++n) bR0[n] = *(const bf16x8*)&smem[boff + n * 512];

#define STEPP(T, AC, BC, AN, BN2)                                                     \
    {                                                                                 \
        int t = (T);                                                                  \
        if (t + 3 < NT) stage((t + 3) & 3, t + 3);                                    \
        if (t + 3 < NT)      asm volatile("s_waitcnt vmcnt(8)" ::: "memory");         \
        else if (t + 2 < NT) asm volatile("s_waitcnt vmcnt(4)" ::: "memory");         \
        else if (t + 1 < NT) asm volatile("s_waitcnt vmcnt(0)" ::: "memory");         \
        __builtin_amdgcn_s_barrier();                                                 \
        const int sb = ((t + 1) & 3) * 8192;                                          \
        const bool pre = (t + 1 < NT);                                                \
        _Pragma("unroll")                                                             \
        for (int q = 0; q < 4; ++q) {                                                 \
            if (pre) {                                                                \
                AN[q] = *(const bf16x8*)&smem[sb + aoff + q * 512];                    \
                BN2[q] = *(const bf16x8*)&smem[sb + boff + q * 512];                   \
            }                                                                         \
            __builtin_amdgcn_s_setprio(1);                                            \
            _Pragma("unroll")                                                         \
            for (int n = 0; n < 4; ++n)                                               \
                acc[q][n] = __builtin_amdgcn_mfma_f32_16x16x32_bf16(AC[q], BC[n], acc[q][n], 0, 0, 0); \
            __builtin_amdgcn_s_setprio(0);                                            \
            __builtin_amdgcn_sched_barrier(0);                                        \
        }                                                                             \
        asm volatile("s_waitcnt lgkmcnt(0)" ::: "memory");                            \
        __builtin_amdgcn_sched_barrier(0);                                            \
    }

    for (int tt = 0; tt < NT; tt += 2) {
        STEPP(tt, aR0, bR0, aR1, bR1)
        STEPP(tt + 1, aR1, bR1, aR0, bR0)
    }
#undef STEPP

    __syncthreads();
    const int orow = (lane >> 4) * 4;
    const int ocol = lane & 15;
    float bv[4];
    if (EPI >= 1) {
#pragma unroll
        for (int j = 0; j < 4; ++j) bv[j] = bias[n0 + wc * 64 + j * 16 + ocol];
    }
#pragma unroll
    for (int i = 0; i < 4; ++i)
#pragma unroll
        for (int j = 0; j < 4; ++j)
#pragma unroll
            for (int rj = 0; rj < 4; ++rj) {
                int lrow = wr * 64 + i * 16 + orow + rj;
                int lcol = wc * 64 + j * 16 + ocol;
                float val = acc[i][j][rj];
                if (EPI == 1) val += bv[j];
                if (EPI == 2) val = gelu_fast(val + bv[j]);
                smem[lrow * 128 + lcol] = (short)f2bf(val);
            }
    __syncthreads();
    const long long zoff = (long long)blockIdx.z * sC;
#pragma unroll
    for (int p = 0; p < 8; ++p) {
        int s = p * 256 + tid;
        int row = s >> 4;
        int cc = (s & 15) * 8;
        *(int4*)&C[zoff + (long long)(m0 + row) * ldc + n0 + cc] = *(const int4*)&smem[row * 128 + cc];
    }
}

// ====== pdecay: scores = (q k^T) * gamma^(n-m) * KSCALE, banded (dist<=3 tiles) ======
__global__ __launch_bounds__(256, 2) void pdecay(
    const short* __restrict__ Q, const short* __restrict__ Kp,
    unsigned short* __restrict__ S, int lda, long long sA) {
    if (blockIdx.x > blockIdx.y) return;
    if (blockIdx.y > blockIdx.x + 3) return;   // gamma^385 ~ 5e-6: negligible
    const int q0 = blockIdx.y * 128;
    const int c0 = blockIdx.x * 128;
    unsigned short* Sb = S + (long long)blockIdx.z * SEQ * SEQ;
    __shared__ __align__(16) short smem[4 * 8192];
    const int tid = threadIdx.x;
    const int lane = tid & 63;
    const int wid = tid >> 6;
    const int wr = wid >> 1, wc = wid & 1;
    const short* Ab = Q + (long long)blockIdx.z * sA;
    const short* Bb = Kp + (long long)blockIdx.z * sA;

    auto stage = [&](int slot, int t) {
        int k0 = t * 32;
#pragma unroll
        for (int it = 0; it < 2; ++it) {
            int c = it * 256 + tid;
            int rr = c >> 2;
            int cc = ((c & 3) ^ ((c >> 3) & 3)) * 8;
            gload_lds16(Ab + (long long)(q0 + rr) * lda + k0 + cc,
                        &smem[slot * 8192 + (it * 256 + wid * 64) * 8]);
            gload_lds16(Bb + (long long)(c0 + rr) * lda + k0 + cc,
                        &smem[slot * 8192 + 4096 + (it * 256 + wid * 64) * 8]);
        }
    };

    const int NT = D_MODEL / 32;   // 16
    f32x4 acc[4][4] = {};
    const int sw8 = (((lane >> 4) ^ ((lane >> 1) & 3)) * 8);
    const int aoff = (wr * 64 + (lane & 15)) * 32 + sw8;
    const int boff = 4096 + (wc * 64 + (lane & 15)) * 32 + sw8;

    bf16x8 aR0[4], bR0[4], aR1[4], bR1[4];
    stage(0, 0); stage(1, 1); stage(2, 2);
    asm volatile("s_waitcnt vmcnt(8)" ::: "memory");
    __builtin_amdgcn_s_barrier();
#pragma unroll
    for (int m = 0; m < 4; ++m) aR0[m] = *(const bf16x8*)&smem[aoff + m * 512];
#pragma unroll
    for (int n = 0; n < 4; ++n) bR0[n] = *(const bf16x8*)&smem[boff + n * 512];

#define STEPD(T, AC, BC, AN, BN2)                                                     \
    {                                                                                 \
        int t = (T);                                                                  \
        if (t + 3 < NT) stage((t + 3) & 3, t + 3);                                    \
        if (t + 3 < NT)      asm volatile("s_waitcnt vmcnt(8)" ::: "memory");         \
        else if (t + 2 < NT) asm volatile("s_waitcnt vmcnt(4)" ::: "memory");         \
        else if (t + 1 < NT) asm volatile("s_waitcnt vmcnt(0)" ::: "memory");         \
        __builtin_amdgcn_s_barrier();                                                 \
        const int sb = ((t + 1) & 3) * 8192;                                          \
        const bool pre = (t + 1 < NT);                                                \
        _Pragma("unroll")                                                             \
        for (int q = 0; q < 4; ++q) {                                                 \
            if (pre) {                                                                \
                AN[q] = *(const bf16x8*)&smem[sb + aoff + q * 512];                    \
                BN2[q] = *(const bf16x8*)&smem[sb + boff + q * 512];                   \
            }                                                                         \
            __builtin_amdgcn_s_setprio(1);                                            \
            _Pragma("unroll")                                                         \
            for (int n = 0; n < 4; ++n)                                               \
                acc[q][n] = __builtin_amdgcn_mfma_f32_16x16x32_bf16(AC[q], BC[n], acc[q][n], 0, 0, 0); \
            __builtin_amdgcn_s_setprio(0);                                            \
            __builtin_amdgcn_sched_barrier(0);                                        \
        }                                                                             \
        asm volatile("s_waitcnt lgkmcnt(0)" ::: "memory");                            \
        __builtin_amdgcn_sched_barrier(0);                                            \
    }

    for (int tt = 0; tt < NT; tt += 2) {
        STEPD(tt, aR0, bR0, aR1, bR1)
        STEPD(tt + 1, aR1, bR1, aR0, bR0)
    }
#undef STEPD

    __syncthreads();
    const int orow = (lane >> 4) * 4;
    const int ocol = lane & 15;
#pragma unroll
    for (int i = 0; i < 4; ++i)
#pragma unroll
        for (int j = 0; j < 4; ++j)
#pragma unroll
            for (int rj = 0; rj < 4; ++rj) {
                int lrow = wr * 64 + i * 16 + orow + rj;
                int lcol = wc * 64 + j * 16 + ocol;
                int n = q0 + lrow, m = c0 + lcol;
                float w = (n >= m) ? exp2f((float)(n - m) * LOG2_GAMMA) * KSCALE : 0.f;
                smem[lrow * 128 + lcol] = (short)f2bf(acc[i][j][rj] * w);
            }
    __syncthreads();
#pragma unroll
    for (int p = 0; p < 8; ++p) {
        int s = p * 256 + tid;
        int row = s >> 4;
        int cc = (s & 15) * 8;
        *(int4*)&Sb[(long long)(q0 + row) * SEQ + c0 + cc] = *(const int4*)&smem[row * 128 + cc];
    }
}

// ============ fused weight convert+transpose ============
__global__ __launch_bounds__(256) void wconv_all(
    const float* __restrict__ Wq, const float* __restrict__ Wk,
    const float* __restrict__ Wv, const float* __restrict__ Wg,
    const float* __restrict__ Wo, const float* __restrict__ W1,
    const float* __restrict__ W2,
    unsigned short* __restrict__ WqkvgT, unsigned short* __restrict__ WoT,
    unsigned short* __restrict__ W1T, unsigned short* __restrict__ W2T) {
    const long long dd = 512LL * 512;
    int z = blockIdx.z;
    int l = z / 7, w = z % 7;
    const float* src; unsigned short* dst; int K, N;
    switch (w) {
        case 0: src = Wq + l * dd; dst = WqkvgT + (long long)l * 4 * dd; K = 512; N = 512; break;
        case 1: src = Wk + l * dd; dst = WqkvgT + (long long)l * 4 * dd + dd; K = 512; N = 512; break;
        case 2: src = Wv + l * dd; dst = WqkvgT + (long long)l * 4 * dd + 2 * dd; K = 512; N = 512; break;
        case 3: src = Wg + l * dd; dst = WqkvgT + (long long)l * 4 * dd + 3 * dd; K = 512; N = 512; break;
        case 4: src = Wo + l * dd; dst = WoT + l * dd; K = 512; N = 512; break;
        case 5: src = W1 + (long long)l * 512 * 1024; dst = W1T + (long long)l * 512 * 1024; K = 512; N = 1024; break;
        default: src = W2 + (long long)l * 1024 * 512; dst = W2T + (long long)l * 1024 * 512; K = 1024; N = 512; break;
    }
    if ((int)blockIdx.x >= N / 64 || (int)blockIdx.y >= K / 64) return;
    __shared__ unsigned short t[64][65];
    int n0 = blockIdx.x * 64, k0 = blockIdx.y * 64;
    int tx = threadIdx.x & 63, ty = threadIdx.x >> 6;
#pragma unroll
    for (int i = 0; i < 16; ++i)
        t[ty + i * 4][tx] = f2bf(src[(long long)(k0 + ty + i * 4) * N + n0 + tx]);
    __syncthreads();
#pragma unroll
    for (int i = 0; i < 16; ++i)
        dst[(long long)(n0 + ty + i * 4) * K + k0 + tx] = t[tx][ty + i * 4];
}

// ============ per-batch transpose: bf16 [SEQ][*stride slice] -> [D][SEQ] ============
__global__ __launch_bounds__(256) void vtrans(const unsigned short* __restrict__ in,
                                              unsigned short* __restrict__ out, int istride) {
    __shared__ unsigned short t[64][65];
    const unsigned short* pin = in + (long long)blockIdx.z * SEQ * istride;
    unsigned short* pout = out + (long long)blockIdx.z * D_MODEL * SEQ;
    int c0 = blockIdx.x * 64, r0 = blockIdx.y * 64;
    int tx = threadIdx.x & 63, ty = threadIdx.x >> 6;
#pragma unroll
    for (int i = 0; i < 16; ++i)
        t[ty + i * 4][tx] = pin[(long long)(r0 + ty + i * 4) * istride + c0 + tx];
    __syncthreads();
#pragma unroll
    for (int i = 0; i < 16; ++i)
        pout[(long long)(c0 + ty + i * 4) * SEQ + r0 + tx] = t[tx][ty + i * 4];
}

// ============ fused residual-add + LayerNorm, all bf16 ============
template <int MODE>
__global__ __launch_bounds__(256) void ln_fuse(
    const void* __restrict__ hin_v,
    const unsigned short* __restrict__ delta,
    const float* __restrict__ g, const float* __restrict__ b,
    unsigned short* __restrict__ hout,
    unsigned short* __restrict__ y) {
    int row = blockIdx.x * 4 + (threadIdx.x >> 6);
    int t = threadIdx.x & 63;
    float f[8];
    if (MODE == 2) {
        const float4* r4 = (const float4*)((const float*)hin_v + (long long)row * D_MODEL);
        float4 v0 = r4[2 * t], v1 = r4[2 * t + 1];
        f[0] = v0.x; f[1] = v0.y; f[2] = v0.z; f[3] = v0.w;
        f[4] = v1.x; f[5] = v1.y; f[6] = v1.z; f[7] = v1.w;
    } else {
        const unsigned short* hin = (const unsigned short*)hin_v;
        int4 hv = ((const int4*)(hin + (long long)row * D_MODEL))[t];
        const unsigned short* hu = (const unsigned short*)&hv;
#pragma unroll
        for (int k = 0; k < 8; ++k) f[k] = bf2f(hu[k]);
    }
    if (MODE == 1) {
        int4 dv = ((const int4*)(delta + (long long)row * D_MODEL))[t];
        const unsigned short* du = (const unsigned short*)&dv;
#pragma unroll
        for (int k = 0; k < 8; ++k) f[k] += bf2f(du[k]);
    }
    float s = 0.f, s2 = 0.f;
#pragma unroll
    for (int k = 0; k < 8; ++k) { s += f[k]; s2 += f[k] * f[k]; }
#pragma unroll
    for (int off = 32; off > 0; off >>= 1) {
        s += __shfl_down(s, off);
        s2 += __shfl_down(s2, off);
    }
    s = __shfl(s, 0); s2 = __shfl(s2, 0);
    float mu = s * (1.f / D_MODEL);
    float var = s2 * (1.f / D_MODEL) - mu * mu;
    float rs = rsqrtf(var + 1e-6f);
    if (MODE >= 1) {
        ushort4 ho[2];
        unsigned short* hp = (unsigned short*)ho;
#pragma unroll
        for (int k = 0; k < 8; ++k) hp[k] = f2bf(f[k]);
        ((int4*)(hout + (long long)row * D_MODEL))[t] = *(int4*)ho;
    }
    const float4* g4 = (const float4*)g;
    const float4* b4 = (const float4*)b;
    float4 ga = g4[2 * t], gb2 = g4[2 * t + 1];
    float4 ba = b4[2 * t], bb2 = b4[2 * t + 1];
    float gg[8] = {ga.x, ga.y, ga.z, ga.w, gb2.x, gb2.y, gb2.z, gb2.w};
    float bb[8] = {ba.x, ba.y, ba.z, ba.w, bb2.x, bb2.y, bb2.z, bb2.w};
    ushort4 yo[2];
    unsigned short* yp = (unsigned short*)yo;
#pragma unroll
    for (int k = 0; k < 8; ++k) yp[k] = f2bf((f[k] - mu) * rs * gg[k] + bb[k]);
    ((int4*)(y + (long long)row * D_MODEL))[t] = *(int4*)yo;
}

// ============ gated = silu(g) * groupnorm(ret), all bf16 (g strided) ============
__global__ __launch_bounds__(256) void gate_bf16(const unsigned short* __restrict__ ret,
                                                 const unsigned short* __restrict__ g,
                                                 int gstride,
                                                 unsigned short* __restrict__ out) {
    int row = blockIdx.x * 4 + (threadIdx.x >> 6);
    int t = threadIdx.x & 63;
    int4 rv4 = ((const int4*)(ret + (long long)row * D_MODEL))[t];
    const unsigned short* ru = (const unsigned short*)&rv4;
    float f[8];
#pragma unroll
    for (int k = 0; k < 8; ++k) f[k] = bf2f(ru[k]);
    float s = 0.f, s2 = 0.f;
#pragma unroll
    for (int k = 0; k < 8; ++k) { s += f[k]; s2 += f[k] * f[k]; }
#pragma unroll
    for (int off = 32; off > 0; off >>= 1) {
        s += __shfl_down(s, off);
        s2 += __shfl_down(s2, off);
    }
    s = __shfl(s, 0); s2 = __shfl(s2, 0);
    float mu = s * (1.f / D_MODEL);
    float var = s2 * (1.f / D_MODEL) - mu * mu;
    float rs = rsqrtf(var + 1e-6f);
    int4 gv4 = ((const int4*)(g + (long long)row * gstride))[t];
    const unsigned short* gu = (const unsigned short*)&gv4;
    ushort4 o[2];
    unsigned short* op = (unsigned short*)o;
#pragma unroll
    for (int k = 0; k < 8; ++k) {
        float x = bf2f(gu[k]);
        op[k] = f2bf(x * sigm(x) * (f[k] - mu) * rs);
    }
    ((int4*)(out + (long long)row * D_MODEL))[t] = *(int4*)o;
}

// ============ pooled = sum_rows (h + dlast): two-stage ============
__global__ __launch_bounds__(256) void pool_s1(const unsigned short* __restrict__ h,
                                               const unsigned short* __restrict__ d,
                                               float* __restrict__ partial) {
    int b = blockIdx.x >> 4, g = blockIdx.x & 15;
    long long base = ((long long)b * SEQ + g * 64) * D_MODEL;
    int cw = (threadIdx.x & 63) * 8;
    int rg = threadIdx.x >> 6;
    float a[8] = {};
    for (int r = rg; r < 64; r += 4) {
        long long o = base + (long long)r * D_MODEL + cw;
        int4 hv = *(const int4*)&h[o];
        int4 dv = *(const int4*)&d[o];
        const unsigned short* hp = (const unsigned short*)&hv;
        const unsigned short* dp = (const unsigned short*)&dv;
#pragma unroll
        for (int j = 0; j < 8; ++j) a[j] += bf2f(hp[j]) + bf2f(dp[j]);
    }
    __shared__ float red[4][512];
#pragma unroll
    for (int j = 0; j < 8; ++j) red[rg][cw + j] = a[j];
    __syncthreads();
#pragma unroll
    for (int cc = 0; cc < 2; ++cc) {
        int c = threadIdx.x * 2 + cc;
        partial[(long long)blockIdx.x * D_MODEL + c] =
            red[0][c] + red[1][c] + red[2][c] + red[3][c];
    }
}

__global__ __launch_bounds__(256) void pool_s2(const float* __restrict__ partial,
                                               float* __restrict__ pooled) {
    int idx = blockIdx.x * 256 + threadIdx.x;  // 0..8191
    int b = idx >> 9, c = idx & 511;
    float s = 0.f;
#pragma unroll
    for (int g = 0; g < 16; ++g) s += partial[(long long)(b * 16 + g) * D_MODEL + c];
    pooled[idx] = s;
}

__global__ __launch_bounds__(64) void readout_kernel(const float* __restrict__ pooled,
                                                     const float* __restrict__ Wro,
                                                     const float* __restrict__ bro,
                                                     float* __restrict__ out) {
    int bo = blockIdx.x;
    int b = bo >> 1, o = bo & 1;
    int t = threadIdx.x;
    float s = 0.f;
    for (int i = t; i < D_MODEL; i += 64) s += pooled[b * D_MODEL + i] * Wro[i * 2 + o];
#pragma unroll
    for (int off = 32; off > 0; off >>= 1) s += __shfl_down(s, off);
    if (t == 0) out[b * 2 + o] = s + bro[o];
}

extern "C" void kernel_launch(void* const* d_in, const int* in_sizes, int n_in,
                              void* d_out, int out_size, void* d_ws, size_t ws_size,
                              hipStream_t stream) {
    const float* x = (const float*)d_in[0];
    const float* Wq = (const float*)d_in[1];
    const float* Wk = (const float*)d_in[2];
    const float* Wv = (const float*)d_in[3];
    const float* Wg = (const float*)d_in[4];
    const float* Wo = (const float*)d_in[5];
    const float* ln1_g = (const float*)d_in[6];
    const float* ln1_b = (const float*)d_in[7];
    const float* ln2_g = (const float*)d_in[8];
    const float* ln2_b = (const float*)d_in[9];
    const float* W1 = (const float*)d_in[10];
    const float* b1 = (const float*)d_in[11];
    const float* W2 = (const float*)d_in[12];
    const float* b2 = (const float*)d_in[13];
    const float* Wro = (const float*)d_in[14];
    const float* bro = (const float*)d_in[15];
    float* out = (float*)d_out;

    const long long NE = (long long)NROWS * D_MODEL;  // 8,388,608
    const long long dd = (long long)D_MODEL * D_MODEL;

    unsigned short* h = (unsigned short*)d_ws;   // NE
    unsigned short* y = h + NE;                  // NE
    unsigned short* qkvg = y + NE;               // 4*NE  [16384][2048]
    unsigned short* vT = qkvg + 4 * NE;          // NE    [16][512][1024]
    unsigned short* gated = vT;                  // alias (vT dead after ret GEMM)
    unsigned short* ret = vT + NE;               // NE    (also ffn-delta buffer)
    unsigned short* sg = ret + NE;               // 2*NE  scores / attn-delta / ffn-hidden
    float* pooled = (float*)(sg + 2 * NE);       // 8192 f32
    float* partial = pooled + 8192;              // 256*512 f32
    unsigned short* wts = (unsigned short*)(partial + 256 * 512);
    unsigned short* WqkvgT = wts;                          // [L][2048][512]
    unsigned short* WoT = WqkvgT + 2 * 4 * dd;             // [L][512][512]
    unsigned short* W1T = WoT + 2 * dd;                    // [L][1024][512]
    unsigned short* W2T = W1T + 2 * (long long)D_MODEL * HID;  // [L][512][1024]

    dim3 blk(256);
    wconv_all<<<dim3(16, 16, 14), blk, 0, stream>>>(Wq, Wk, Wv, Wg, Wo, W1, W2,
                                                    WqkvgT, WoT, W1T, W2T);

    for (int l = 0; l < 2; l++) {
        if (l == 0)
            ln_fuse<2><<<NROWS / 4, blk, 0, stream>>>(x, nullptr, ln1_g, ln1_b, h, y);
        else
            ln_fuse<1><<<NROWS / 4, blk, 0, stream>>>(h, ret, ln1_g + l * D_MODEL,
                                                      ln1_b + l * D_MODEL, h, y);
        // qkvg = y @ [Wq|Wk|Wv|Wg]
        gemm256p<0><<<512, 512, 0, stream>>>(
            (const short*)y, (const short*)(WqkvgT + (long long)l * 4 * dd), nullptr, qkvg,
            512, 512, 512, 2048, 8);
        vtrans<<<dim3(8, 16, BATCH), blk, 0, stream>>>(qkvg + 1024, vT, 2048);
        pdecay<<<dim3(8, 8, BATCH), blk, 0, stream>>>(
            (const short*)qkvg, (const short*)(qkvg + 512), sg, 2048, (long long)SEQ * 2048);
        // ret = scores @ v  (banded K window)
        pgemm128<0><<<dim3(4, 8, BATCH), blk, 0, stream>>>(
            (const short*)sg, (const short*)vT, nullptr, ret,
            SEQ, SEQ, SEQ, 512,
            (long long)SEQ * SEQ, (long long)D_MODEL * SEQ, (long long)SEQ * D_MODEL, 2);
        gate_bf16<<<NROWS / 4, blk, 0, stream>>>(ret, qkvg + 1536, 2048, gated);
        // attn delta = gated @ Wo  -> sg
        pgemm128<0><<<dim3(4, 128), blk, 0, stream>>>(
            (const short*)gated, (const short*)(WoT + l * dd), nullptr, sg,
            512, 512, 512, 512, 0, 0, 0, 0);
        // h += attn delta; y = LN2(h)
        ln_fuse<1><<<NROWS / 4, blk, 0, stream>>>(h, sg, ln2_g + l * D_MODEL,
                                                  ln2_b + l * D_MODEL, h, y);
        // hidden = gelu(y @ W1 + b1)
        gemm256p<2><<<256, 512, 0, stream>>>(
            (const short*)y, (const short*)(W1T + (long long)l * D_MODEL * HID),
            b1 + l * HID, sg, 512, 512, 512, HID, 4);
        // ffn delta = hidden @ W2 + b2 -> ret buffer
        pgemm128<1><<<dim3(4, 128), blk, 0, stream>>>(
            (const short*)sg, (const short*)(W2T + (long long)l * HID * D_MODEL),
            b2 + l * D_MODEL, ret, HID, HID, HID, 512, 0, 0, 0, 0);
    }

    pool_s1<<<256, blk, 0, stream>>>(h, ret, partial);
    pool_s2<<<32, blk, 0, stream>>>(partial, pooled);
    readout_kernel<<<32, 64, 0, stream>>>(pooled, Wro, bro, out);
}

// Round 13
// 436.582 us; speedup vs baseline: 7.5142x; 1.0155x over previous
//
#include <hip/hip_runtime.h>
#include <hip/hip_bf16.h>

// RetNet 2-layer forward. All-bf16 dataflow.
// MFMA GEMMs: ring-4 LDS, one barrier/K-step, counted vmcnt, conflict-free swizzle.
// Banded decay (tile-distance<=2; gamma^257~2.8e-4). pgemm128 for ret/Wo/FF2.

#define D_MODEL 512
#define SEQ 1024
#define BATCH 16
#define NROWS (BATCH * SEQ)          // 16384
#define HID 1024
#define LOG2_GAMMA (-0.04580368961f)  // log2(0.96875)
#define KSCALE (0.044194173824f)      // 512^-0.5

typedef __attribute__((ext_vector_type(8))) short bf16x8;
typedef __attribute__((ext_vector_type(4))) float f32x4;

__device__ inline unsigned short f2bf(float x) {
    union { float f; unsigned u; } uu; uu.f = x;
    unsigned r = uu.u + 0x7fff + ((uu.u >> 16) & 1);
    return (unsigned short)(r >> 16);
}
__device__ inline float bf2f(unsigned short x) {
    union { unsigned u; float f; } uu; uu.u = ((unsigned)x) << 16; return uu.f;
}

__device__ inline void gload_lds16(const void* g, void* l) {
    __builtin_amdgcn_global_load_lds(
        (const __attribute__((address_space(1))) void*)g,
        (__attribute__((address_space(3))) void*)l, 16, 0, 0);
}

__device__ inline float sigm(float z) {
    return 1.f / (1.f + exp2f(z * -1.442695040888963f));
}
__device__ inline float gelu_fast(float x) {
    float y = 1.5957691216057308f * (x + 0.044715f * x * x * x);
    return x * sigm(y);
}

// ================== gemm256p: C[M,N] = A[M,K] @ B[N,K]^T, bf16 out ==================
template <int EPI>
__global__ __launch_bounds__(512, 2) void gemm256p(
    const short* __restrict__ A, const short* __restrict__ B,
    const float* __restrict__ bias, unsigned short* __restrict__ C,
    int K, int lda, int ldb, int ldc, int nbx) {
    __shared__ __align__(16) short smem[4 * 16384];
    const int tid = threadIdx.x;
    const int lane = tid & 63;
    const int wid = tid >> 6;
    const int wm = wid >> 2, wn = wid & 3;
    const int cpx = gridDim.x >> 3;
    const int wg = ((int)blockIdx.x & 7) * cpx + ((int)blockIdx.x >> 3);
    const int m0 = (wg / nbx) * 256;
    const int n0 = (wg % nbx) * 256;

    const int srow = tid >> 2;
    const int scol = (((tid & 3) ^ ((tid >> 3) & 3)) * 8);
    auto stage = [&](int slot, int t) {
        int k0 = t * 32;
#pragma unroll
        for (int r = 0; r < 2; ++r) {
            gload_lds16(A + (long long)(m0 + r * 128 + srow) * lda + k0 + scol,
                        &smem[slot * 16384 + r * 4096 + wid * 512]);
            gload_lds16(B + (long long)(n0 + r * 128 + srow) * ldb + k0 + scol,
                        &smem[slot * 16384 + 8192 + r * 4096 + wid * 512]);
        }
    };

    const int NT = K >> 5;
    f32x4 acc[8][4] = {};
    const int sw8 = (((lane >> 4) ^ ((lane >> 1) & 3)) * 8);
    const int aoff = (wm * 128 + (lane & 15)) * 32 + sw8;
    const int boff = 8192 + (wn * 64 + (lane & 15)) * 32 + sw8;

    bf16x8 aR0[8], bR0[4], aR1[8], bR1[4];
    stage(0, 0); stage(1, 1); stage(2, 2);
    asm volatile("s_waitcnt vmcnt(8)" ::: "memory");
    __builtin_amdgcn_s_barrier();
#pragma unroll
    for (int m = 0; m < 8; ++m) aR0[m] = *(const bf16x8*)&smem[aoff + m * 512];
#pragma unroll
    for (int n = 0; n < 4; ++n) bR0[n] = *(const bf16x8*)&smem[boff + n * 512];

#define STEP256(T, AC, BC, AN, BN2)                                                   \
    {                                                                                 \
        int t = (T);                                                                  \
        if (t + 3 < NT) stage((t + 3) & 3, t + 3);                                    \
        if (t + 3 < NT)      asm volatile("s_waitcnt vmcnt(8)" ::: "memory");         \
        else if (t + 2 < NT) asm volatile("s_waitcnt vmcnt(4)" ::: "memory");         \
        else if (t + 1 < NT) asm volatile("s_waitcnt vmcnt(0)" ::: "memory");         \
        __builtin_amdgcn_s_barrier();                                                 \
        const int sb = ((t + 1) & 3) * 16384;                                         \
        const bool pre = (t + 1 < NT);                                                \
        _Pragma("unroll")                                                             \
        for (int q = 0; q < 4; ++q) {                                                 \
            if (pre) {                                                                \
                AN[2 * q] = *(const bf16x8*)&smem[sb + aoff + (2 * q) * 512];          \
                AN[2 * q + 1] = *(const bf16x8*)&smem[sb + aoff + (2 * q + 1) * 512];  \
                BN2[q] = *(const bf16x8*)&smem[sb + boff + q * 512];                   \
            }                                                                         \
            __builtin_amdgcn_s_setprio(1);                                            \
            _Pragma("unroll")                                                         \
            for (int n = 0; n < 4; ++n) {                                             \
                acc[2 * q][n] = __builtin_amdgcn_mfma_f32_16x16x32_bf16(AC[2 * q], BC[n], acc[2 * q][n], 0, 0, 0); \
                acc[2 * q + 1][n] = __builtin_amdgcn_mfma_f32_16x16x32_bf16(AC[2 * q + 1], BC[n], acc[2 * q + 1][n], 0, 0, 0); \
            }                                                                         \
            __builtin_amdgcn_s_setprio(0);                                            \
            __builtin_amdgcn_sched_barrier(0);                                        \
        }                                                                             \
        asm volatile("s_waitcnt lgkmcnt(0)" ::: "memory");                            \
        __builtin_amdgcn_sched_barrier(0);                                            \
    }

    for (int tt = 0; tt < NT; tt += 2) {
        STEP256(tt, aR0, bR0, aR1, bR1)
        STEP256(tt + 1, aR1, bR1, aR0, bR0)
    }
#undef STEP256

    // ---- epilogue via LDS, vector stores ----
    const int ocol = lane & 15;
    const int orow4 = (lane >> 4) * 4;
    float bv[4];
    if (EPI == 2) {
#pragma unroll
        for (int n = 0; n < 4; ++n) bv[n] = bias[n0 + wn * 64 + n * 16 + ocol];
    }
#pragma unroll 1
    for (int half = 0; half < 2; ++half) {
        __syncthreads();
        if (wm == half) {
#pragma unroll
            for (int m = 0; m < 8; ++m)
#pragma unroll
                for (int n = 0; n < 4; ++n)
#pragma unroll
                    for (int rj = 0; rj < 4; ++rj) {
                        int lr = m * 16 + orow4 + rj;
                        int lc = wn * 64 + n * 16 + ocol;
                        float v = acc[m][n][rj];
                        if (EPI == 2) v = gelu_fast(v + bv[n]);
                        smem[lr * 256 + lc] = (short)f2bf(v);
                    }
        }
        __syncthreads();
#pragma unroll
        for (int p = 0; p < 8; ++p) {
            int s = p * 512 + tid;
            int row = s >> 5;
            int cc = (s & 31) * 8;
            *(int4*)&C[(long long)(m0 + half * 128 + row) * ldc + n0 + cc] =
                *(const int4*)&smem[row * 256 + cc];
        }
    }
}

// ========== pgemm128: BM=128, BN=128, 4 waves (2x2), ring-4 (64KB), 2 blk/CU ==========
// EPI: 0 plain, 1 acc+bias, 2 gelu(acc+bias).
// tri: 0 full K; 1 K in [0, m0+128); 2 K in [max(0,m0-256), m0+128)  (banded retention)
template <int EPI>
__global__ __launch_bounds__(256, 2) void pgemm128(
    const short* __restrict__ A, const short* __restrict__ B,
    const float* __restrict__ bias, unsigned short* __restrict__ C,
    int K, int lda, int ldb, int ldc,
    long long sA, long long sB, long long sC, int tri) {
    __shared__ __align__(16) short smem[4 * 8192];
    const int tid = threadIdx.x;
    const int lane = tid & 63;
    const int wid = tid >> 6;
    const int wr = wid >> 1, wc = wid & 1;
    const int m0 = blockIdx.y * 128, n0 = blockIdx.x * 128;
    A += (long long)blockIdx.z * sA;
    B += (long long)blockIdx.z * sB;

    int Keff = K;
    int kstart = 0;
    if (tri) { int km = m0 + 128; if (km < Keff) Keff = km; }
    if (tri == 2) { int ks = m0 - 256; if (ks > 0) kstart = ks; }
    const int NT = (Keff - kstart) >> 5;

    auto stage = [&](int slot, int t) {
        int k0 = kstart + t * 32;
#pragma unroll
        for (int it = 0; it < 2; ++it) {
            int c = it * 256 + tid;
            int rr = c >> 2;
            int cc = ((c & 3) ^ ((c >> 3) & 3)) * 8;
            gload_lds16(A + (long long)(m0 + rr) * lda + k0 + cc,
                        &smem[slot * 8192 + (it * 256 + wid * 64) * 8]);
            gload_lds16(B + (long long)(n0 + rr) * ldb + k0 + cc,
                        &smem[slot * 8192 + 4096 + (it * 256 + wid * 64) * 8]);
        }
    };

    f32x4 acc[4][4] = {};
    const int sw8 = (((lane >> 4) ^ ((lane >> 1) & 3)) * 8);
    const int aoff = (wr * 64 + (lane & 15)) * 32 + sw8;
    const int boff = 4096 + (wc * 64 + (lane & 15)) * 32 + sw8;

    bf16x8 aR0[4], bR0[4], aR1[4], bR1[4];
    stage(0, 0); stage(1, 1); stage(2, 2);
    asm volatile("s_waitcnt vmcnt(8)" ::: "memory");
    __builtin_amdgcn_s_barrier();
#pragma unroll
    for (int m = 0; m < 4; ++m) aR0[m] = *(const bf16x8*)&smem[aoff + m * 512];
#pragma unroll
    for (int n = 0; n < 4; ++n) bR0[n] = *(const bf16x8*)&smem[boff + n * 512];

#define STEPP(T, AC, BC, AN, BN2)                                                     \
    {                                                                                 \
        int t = (T);                                                                  \
        if (t + 3 < NT) stage((t + 3) & 3, t + 3);                                    \
        if (t + 3 < NT)      asm volatile("s_waitcnt vmcnt(8)" ::: "memory");         \
        else if (t + 2 < NT) asm volatile("s_waitcnt vmcnt(4)" ::: "memory");         \
        else if (t + 1 < NT) asm volatile("s_waitcnt vmcnt(0)" ::: "memory");         \
        __builtin_amdgcn_s_barrier();                                                 \
        const int sb = ((t + 1) & 3) * 8192;                                          \
        const bool pre = (t + 1 < NT);                                                \
        _Pragma("unroll")                                                             \
        for (int q = 0; q < 4; ++q) {                                                 \
            if (pre) {                                                                \
                AN[q] = *(const bf16x8*)&smem[sb + aoff + q * 512];                    \
                BN2[q] = *(const bf16x8*)&smem[sb + boff + q * 512];                   \
            }                                                                         \
            __builtin_amdgcn_s_setprio(1);                                            \
            _Pragma("unroll")                                                         \
            for (int n = 0; n < 4; ++n)                                               \
                acc[q][n] = __builtin_amdgcn_mfma_f32_16x16x32_bf16(AC[q], BC[n], acc[q][n], 0, 0, 0); \
            __builtin_amdgcn_s_setprio(0);                                            \
            __builtin_amdgcn_sched_barrier(0);                                        \
        }                                                                             \
        asm volatile("s_waitcnt lgkmcnt(0)" ::: "memory");                            \
        __builtin_amdgcn_sched_barrier(0);                                            \
    }

    for (int tt = 0; tt < NT; tt += 2) {
        STEPP(tt, aR0, bR0, aR1, bR1)
        STEPP(tt + 1, aR1, bR1, aR0, bR0)
    }
#undef STEPP

    __syncthreads();
    const int orow = (lane >> 4) * 4;
    const int ocol = lane & 15;
    float bv[4];
    if (EPI >= 1) {
#pragma unroll
        for (int j = 0; j < 4; ++j) bv[j] = bias[n0 + wc * 64 + j * 16 + ocol];
    }
#pragma unroll
    for (int i = 0; i < 4; ++i)
#pragma unroll
        for (int j = 0; j < 4; ++j)
#pragma unroll
            for (int rj = 0; rj < 4; ++rj) {
                int lrow = wr * 64 + i * 16 + orow + rj;
                int lcol = wc * 64 + j * 16 + ocol;
                float val = acc[i][j][rj];
                if (EPI == 1) val += bv[j];
                if (EPI == 2) val = gelu_fast(val + bv[j]);
                smem[lrow * 128 + lcol] = (short)f2bf(val);
            }
    __syncthreads();
    const long long zoff = (long long)blockIdx.z * sC;
#pragma unroll
    for (int p = 0; p < 8; ++p) {
        int s = p * 256 + tid;
        int row = s >> 4;
        int cc = (s & 15) * 8;
        *(int4*)&C[zoff + (long long)(m0 + row) * ldc + n0 + cc] = *(const int4*)&smem[row * 128 + cc];
    }
}

// ====== pdecay: scores = (q k^T) * gamma^(n-m) * KSCALE, banded (dist<=2 tiles) ======
__global__ __launch_bounds__(256, 2) void pdecay(
    const short* __restrict__ Q, const short* __restrict__ Kp,
    unsigned short* __restrict__ S, int lda, long long sA) {
    if (blockIdx.x > blockIdx.y) return;
    if (blockIdx.y > blockIdx.x + 2) return;   // gamma^257 ~ 2.8e-4: negligible
    const int q0 = blockIdx.y * 128;
    const int c0 = blockIdx.x * 128;
    unsigned short* Sb = S + (long long)blockIdx.z * SEQ * SEQ;
    __shared__ __align__(16) short smem[4 * 8192];
    const int tid = threadIdx.x;
    const int lane = tid & 63;
    const int wid = tid >> 6;
    const int wr = wid >> 1, wc = wid & 1;
    const short* Ab = Q + (long long)blockIdx.z * sA;
    const short* Bb = Kp + (long long)blockIdx.z * sA;

    auto stage = [&](int slot, int t) {
        int k0 = t * 32;
#pragma unroll
        for (int it = 0; it < 2; ++it) {
            int c = it * 256 + tid;
            int rr = c >> 2;
            int cc = ((c & 3) ^ ((c >> 3) & 3)) * 8;
            gload_lds16(Ab + (long long)(q0 + rr) * lda + k0 + cc,
                        &smem[slot * 8192 + (it * 256 + wid * 64) * 8]);
            gload_lds16(Bb + (long long)(c0 + rr) * lda + k0 + cc,
                        &smem[slot * 8192 + 4096 + (it * 256 + wid * 64) * 8]);
        }
    };

    const int NT = D_MODEL / 32;   // 16
    f32x4 acc[4][4] = {};
    const int sw8 = (((lane >> 4) ^ ((lane >> 1) & 3)) * 8);
    const int aoff = (wr * 64 + (lane & 15)) * 32 + sw8;
    const int boff = 4096 + (wc * 64 + (lane & 15)) * 32 + sw8;

    bf16x8 aR0[4], bR0[4], aR1[4], bR1[4];
    stage(0, 0); stage(1, 1); stage(2, 2);
    asm volatile("s_waitcnt vmcnt(8)" ::: "memory");
    __builtin_amdgcn_s_barrier();
#pragma unroll
    for (int m = 0; m < 4; ++m) aR0[m] = *(const bf16x8*)&smem[aoff + m * 512];
#pragma unroll
    for (int n = 0; n < 4; ++n) bR0[n] = *(const bf16x8*)&smem[boff + n * 512];

#define STEPD(T, AC, BC, AN, BN2)                                                     \
    {                                                                                 \
        int t = (T);                                                                  \
        if (t + 3 < NT) stage((t + 3) & 3, t + 3);                                    \
        if (t + 3 < NT)      asm volatile("s_waitcnt vmcnt(8)" ::: "memory");         \
        else if (t + 2 < NT) asm volatile("s_waitcnt vmcnt(4)" ::: "memory");         \
        else if (t + 1 < NT) asm volatile("s_waitcnt vmcnt(0)" ::: "memory");         \
        __builtin_amdgcn_s_barrier();                                                 \
        const int sb = ((t + 1) & 3) * 8192;                                          \
        const bool pre = (t + 1 < NT);                                                \
        _Pragma("unroll")                                                             \
        for (int q = 0; q < 4; ++q) {                                                 \
            if (pre) {                                                                \
                AN[q] = *(const bf16x8*)&smem[sb + aoff + q * 512];                    \
                BN2[q] = *(const bf16x8*)&smem[sb + boff + q * 512];                   \
            }                                                                         \
            __builtin_amdgcn_s_setprio(1);                                            \
            _Pragma("unroll")                                                         \
            for (int n = 0; n < 4; ++n)                                               \
                acc[q][n] = __builtin_amdgcn_mfma_f32_16x16x32_bf16(AC[q], BC[n], acc[q][n], 0, 0, 0); \
            __builtin_amdgcn_s_setprio(0);                                            \
            __builtin_amdgcn_sched_barrier(0);                                        \
        }                                                                             \
        asm volatile("s_waitcnt lgkmcnt(0)" ::: "memory");                            \
        __builtin_amdgcn_sched_barrier(0);                                            \
    }

    for (int tt = 0; tt < NT; tt += 2) {
        STEPD(tt, aR0, bR0, aR1, bR1)
        STEPD(tt + 1, aR1, bR1, aR0, bR0)
    }
#undef STEPD

    __syncthreads();
    const int orow = (lane >> 4) * 4;
    const int ocol = lane & 15;
#pragma unroll
    for (int i = 0; i < 4; ++i)
#pragma unroll
        for (int j = 0; j < 4; ++j)
#pragma unroll
            for (int rj = 0; rj < 4; ++rj) {
                int lrow = wr * 64 + i * 16 + orow + rj;
                int lcol = wc * 64 + j * 16 + ocol;
                int n = q0 + lrow, m = c0 + lcol;
                float w = (n >= m) ? exp2f((float)(n - m) * LOG2_GAMMA) * KSCALE : 0.f;
                smem[lrow * 128 + lcol] = (short)f2bf(acc[i][j][rj] * w);
            }
    __syncthreads();
#pragma unroll
    for (int p = 0; p < 8; ++p) {
        int s = p * 256 + tid;
        int row = s >> 4;
        int cc = (s & 15) * 8;
        *(int4*)&Sb[(long long)(q0 + row) * SEQ + c0 + cc] = *(const int4*)&smem[row * 128 + cc];
    }
}

// ============ fused weight convert+transpose ============
__global__ __launch_bounds__(256) void wconv_all(
    const float* __restrict__ Wq, const float* __restrict__ Wk,
    const float* __restrict__ Wv, const float* __restrict__ Wg,
    const float* __restrict__ Wo, const float* __restrict__ W1,
    const float* __restrict__ W2,
    unsigned short* __restrict__ WqkvgT, unsigned short* __restrict__ WoT,
    unsigned short* __restrict__ W1T, unsigned short* __restrict__ W2T) {
    const long long dd = 512LL * 512;
    int z = blockIdx.z;
    int l = z / 7, w = z % 7;
    const float* src; unsigned short* dst; int K, N;
    switch (w) {
        case 0: src = Wq + l * dd; dst = WqkvgT + (long long)l * 4 * dd; K = 512; N = 512; break;
        case 1: src = Wk + l * dd; dst = WqkvgT + (long long)l * 4 * dd + dd; K = 512; N = 512; break;
        case 2: src = Wv + l * dd; dst = WqkvgT + (long long)l * 4 * dd + 2 * dd; K = 512; N = 512; break;
        case 3: src = Wg + l * dd; dst = WqkvgT + (long long)l * 4 * dd + 3 * dd; K = 512; N = 512; break;
        case 4: src = Wo + l * dd; dst = WoT + l * dd; K = 512; N = 512; break;
        case 5: src = W1 + (long long)l * 512 * 1024; dst = W1T + (long long)l * 512 * 1024; K = 512; N = 1024; break;
        default: src = W2 + (long long)l * 1024 * 512; dst = W2T + (long long)l * 1024 * 512; K = 1024; N = 512; break;
    }
    if ((int)blockIdx.x >= N / 64 || (int)blockIdx.y >= K / 64) return;
    __shared__ unsigned short t[64][65];
    int n0 = blockIdx.x * 64, k0 = blockIdx.y * 64;
    int tx = threadIdx.x & 63, ty = threadIdx.x >> 6;
#pragma unroll
    for (int i = 0; i < 16; ++i)
        t[ty + i * 4][tx] = f2bf(src[(long long)(k0 + ty + i * 4) * N + n0 + tx]);
    __syncthreads();
#pragma unroll
    for (int i = 0; i < 16; ++i)
        dst[(long long)(n0 + ty + i * 4) * K + k0 + tx] = t[tx][ty + i * 4];
}

// ============ per-batch transpose: bf16 [SEQ][*stride slice] -> [D][SEQ] ============
__global__ __launch_bounds__(256) void vtrans(const unsigned short* __restrict__ in,
                                              unsigned short* __restrict__ out, int istride) {
    __shared__ unsigned short t[64][65];
    const unsigned short* pin = in + (long long)blockIdx.z * SEQ * istride;
    unsigned short* pout = out + (long long)blockIdx.z * D_MODEL * SEQ;
    int c0 = blockIdx.x * 64, r0 = blockIdx.y * 64;
    int tx = threadIdx.x & 63, ty = threadIdx.x >> 6;
#pragma unroll
    for (int i = 0; i < 16; ++i)
        t[ty + i * 4][tx] = pin[(long long)(r0 + ty + i * 4) * istride + c0 + tx];
    __syncthreads();
#pragma unroll
    for (int i = 0; i < 16; ++i)
        pout[(long long)(c0 + ty + i * 4) * SEQ + r0 + tx] = t[tx][ty + i * 4];
}

// ============ fused residual-add + LayerNorm, all bf16 ============
template <int MODE>
__global__ __launch_bounds__(256) void ln_fuse(
    const void* __restrict__ hin_v,
    const unsigned short* __restrict__ delta,
    const float* __restrict__ g, const float* __restrict__ b,
    unsigned short* __restrict__ hout,
    unsigned short* __restrict__ y) {
    int row = blockIdx.x * 4 + (threadIdx.x >> 6);
    int t = threadIdx.x & 63;
    float f[8];
    if (MODE == 2) {
        const float4* r4 = (const float4*)((const float*)hin_v + (long long)row * D_MODEL);
        float4 v0 = r4[2 * t], v1 = r4[2 * t + 1];
        f[0] = v0.x; f[1] = v0.y; f[2] = v0.z; f[3] = v0.w;
        f[4] = v1.x; f[5] = v1.y; f[6] = v1.z; f[7] = v1.w;
    } else {
        const unsigned short* hin = (const unsigned short*)hin_v;
        int4 hv = ((const int4*)(hin + (long long)row * D_MODEL))[t];
        const unsigned short* hu = (const unsigned short*)&hv;
#pragma unroll
        for (int k = 0; k < 8; ++k) f[k] = bf2f(hu[k]);
    }
    if (MODE == 1) {
        int4 dv = ((const int4*)(delta + (long long)row * D_MODEL))[t];
        const unsigned short* du = (const unsigned short*)&dv;
#pragma unroll
        for (int k = 0; k < 8; ++k) f[k] += bf2f(du[k]);
    }
    float s = 0.f, s2 = 0.f;
#pragma unroll
    for (int k = 0; k < 8; ++k) { s += f[k]; s2 += f[k] * f[k]; }
#pragma unroll
    for (int off = 32; off > 0; off >>= 1) {
        s += __shfl_down(s, off);
        s2 += __shfl_down(s2, off);
    }
    s = __shfl(s, 0); s2 = __shfl(s2, 0);
    float mu = s * (1.f / D_MODEL);
    float var = s2 * (1.f / D_MODEL) - mu * mu;
    float rs = rsqrtf(var + 1e-6f);
    if (MODE >= 1) {
        ushort4 ho[2];
        unsigned short* hp = (unsigned short*)ho;
#pragma unroll
        for (int k = 0; k < 8; ++k) hp[k] = f2bf(f[k]);
        ((int4*)(hout + (long long)row * D_MODEL))[t] = *(int4*)ho;
    }
    const float4* g4 = (const float4*)g;
    const float4* b4 = (const float4*)b;
    float4 ga = g4[2 * t], gb2 = g4[2 * t + 1];
    float4 ba = b4[2 * t], bb2 = b4[2 * t + 1];
    float gg[8] = {ga.x, ga.y, ga.z, ga.w, gb2.x, gb2.y, gb2.z, gb2.w};
    float bb[8] = {ba.x, ba.y, ba.z, ba.w, bb2.x, bb2.y, bb2.z, bb2.w};
    ushort4 yo[2];
    unsigned short* yp = (unsigned short*)yo;
#pragma unroll
    for (int k = 0; k < 8; ++k) yp[k] = f2bf((f[k] - mu) * rs * gg[k] + bb[k]);
    ((int4*)(y + (long long)row * D_MODEL))[t] = *(int4*)yo;
}

// ============ gated = silu(g) * groupnorm(ret), all bf16 (g strided) ============
__global__ __launch_bounds__(256) void gate_bf16(const unsigned short* __restrict__ ret,
                                                 const unsigned short* __restrict__ g,
                                                 int gstride,
                                                 unsigned short* __restrict__ out) {
    int row = blockIdx.x * 4 + (threadIdx.x >> 6);
    int t = threadIdx.x & 63;
    int4 rv4 = ((const int4*)(ret + (long long)row * D_MODEL))[t];
    const unsigned short* ru = (const unsigned short*)&rv4;
    float f[8];
#pragma unroll
    for (int k = 0; k < 8; ++k) f[k] = bf2f(ru[k]);
    float s = 0.f, s2 = 0.f;
#pragma unroll
    for (int k = 0; k < 8; ++k) { s += f[k]; s2 += f[k] * f[k]; }
#pragma unroll
    for (int off = 32; off > 0; off >>= 1) {
        s += __shfl_down(s, off);
        s2 += __shfl_down(s2, off);
    }
    s = __shfl(s, 0); s2 = __shfl(s2, 0);
    float mu = s * (1.f / D_MODEL);
    float var = s2 * (1.f / D_MODEL) - mu * mu;
    float rs = rsqrtf(var + 1e-6f);
    int4 gv4 = ((const int4*)(g + (long long)row * gstride))[t];
    const unsigned short* gu = (const unsigned short*)&gv4;
    ushort4 o[2];
    unsigned short* op = (unsigned short*)o;
#pragma unroll
    for (int k = 0; k < 8; ++k) {
        float x = bf2f(gu[k]);
        op[k] = f2bf(x * sigm(x) * (f[k] - mu) * rs);
    }
    ((int4*)(out + (long long)row * D_MODEL))[t] = *(int4*)o;
}

// ============ pooled = sum_rows (h + dlast): two-stage ============
__global__ __launch_bounds__(256) void pool_s1(const unsigned short* __restrict__ h,
                                               const unsigned short* __restrict__ d,
                                               float* __restrict__ partial) {
    int b = blockIdx.x >> 4, g = blockIdx.x & 15;
    long long base = ((long long)b * SEQ + g * 64) * D_MODEL;
    int cw = (threadIdx.x & 63) * 8;
    int rg = threadIdx.x >> 6;
    float a[8] = {};
    for (int r = rg; r < 64; r += 4) {
        long long o = base + (long long)r * D_MODEL + cw;
        int4 hv = *(const int4*)&h[o];
        int4 dv = *(const int4*)&d[o];
        const unsigned short* hp = (const unsigned short*)&hv;
        const unsigned short* dp = (const unsigned short*)&dv;
#pragma unroll
        for (int j = 0; j < 8; ++j) a[j] += bf2f(hp[j]) + bf2f(dp[j]);
    }
    __shared__ float red[4][512];
#pragma unroll
    for (int j = 0; j < 8; ++j) red[rg][cw + j] = a[j];
    __syncthreads();
#pragma unroll
    for (int cc = 0; cc < 2; ++cc) {
        int c = threadIdx.x * 2 + cc;
        partial[(long long)blockIdx.x * D_MODEL + c] =
            red[0][c] + red[1][c] + red[2][c] + red[3][c];
    }
}

__global__ __launch_bounds__(256) void pool_s2(const float* __restrict__ partial,
                                               float* __restrict__ pooled) {
    int idx = blockIdx.x * 256 + threadIdx.x;  // 0..8191
    int b = idx >> 9, c = idx & 511;
    float s = 0.f;
#pragma unroll
    for (int g = 0; g < 16; ++g) s += partial[(long long)(b * 16 + g) * D_MODEL + c];
    pooled[idx] = s;
}

__global__ __launch_bounds__(64) void readout_kernel(const float* __restrict__ pooled,
                                                     const float* __restrict__ Wro,
                                                     const float* __restrict__ bro,
                                                     float* __restrict__ out) {
    int bo = blockIdx.x;
    int b = bo >> 1, o = bo & 1;
    int t = threadIdx.x;
    float s = 0.f;
    for (int i = t; i < D_MODEL; i += 64) s += pooled[b * D_MODEL + i] * Wro[i * 2 + o];
#pragma unroll
    for (int off = 32; off > 0; off >>= 1) s += __shfl_down(s, off);
    if (t == 0) out[b * 2 + o] = s + bro[o];
}

extern "C" void kernel_launch(void* const* d_in, const int* in_sizes, int n_in,
                              void* d_out, int out_size, void* d_ws, size_t ws_size,
                              hipStream_t stream) {
    const float* x = (const float*)d_in[0];
    const float* Wq = (const float*)d_in[1];
    const float* Wk = (const float*)d_in[2];
    const float* Wv = (const float*)d_in[3];
    const float* Wg = (const float*)d_in[4];
    const float* Wo = (const float*)d_in[5];
    const float* ln1_g = (const float*)d_in[6];
    const float* ln1_b = (const float*)d_in[7];
    const float* ln2_g = (const float*)d_in[8];
    const float* ln2_b = (const float*)d_in[9];
    const float* W1 = (const float*)d_in[10];
    const float* b1 = (const float*)d_in[11];
    const float* W2 = (const float*)d_in[12];
    const float* b2 = (const float*)d_in[13];
    const float* Wro = (const float*)d_in[14];
    const float* bro = (const float*)d_in[15];
    float* out = (float*)d_out;

    const long long NE = (long long)NROWS * D_MODEL;  // 8,388,608
    const long long dd = (long long)D_MODEL * D_MODEL;

    unsigned short* h = (unsigned short*)d_ws;   // NE
    unsigned short* y = h + NE;                  // NE
    unsigned short* qkvg = y + NE;               // 4*NE  [16384][2048]
    unsigned short* vT = qkvg + 4 * NE;          // NE    [16][512][1024]
    unsigned short* gated = vT;                  // alias (vT dead after ret GEMM)
    unsigned short* ret = vT + NE;               // NE    (also ffn-delta buffer)
    unsigned short* sg = ret + NE;               // 2*NE  scores / attn-delta / ffn-hidden
    float* pooled = (float*)(sg + 2 * NE);       // 8192 f32
    float* partial = pooled + 8192;              // 256*512 f32
    unsigned short* wts = (unsigned short*)(partial + 256 * 512);
    unsigned short* WqkvgT = wts;                          // [L][2048][512]
    unsigned short* WoT = WqkvgT + 2 * 4 * dd;             // [L][512][512]
    unsigned short* W1T = WoT + 2 * dd;                    // [L][1024][512]
    unsigned short* W2T = W1T + 2 * (long long)D_MODEL * HID;  // [L][512][1024]

    dim3 blk(256);
    wconv_all<<<dim3(16, 16, 14), blk, 0, stream>>>(Wq, Wk, Wv, Wg, Wo, W1, W2,
                                                    WqkvgT, WoT, W1T, W2T);

    for (int l = 0; l < 2; l++) {
        if (l == 0)
            ln_fuse<2><<<NROWS / 4, blk, 0, stream>>>(x, nullptr, ln1_g, ln1_b, h, y);
        else
            ln_fuse<1><<<NROWS / 4, blk, 0, stream>>>(h, ret, ln1_g + l * D_MODEL,
                                                      ln1_b + l * D_MODEL, h, y);
        // qkvg = y @ [Wq|Wk|Wv|Wg]
        gemm256p<0><<<512, 512, 0, stream>>>(
            (const short*)y, (const short*)(WqkvgT + (long long)l * 4 * dd), nullptr, qkvg,
            512, 512, 512, 2048, 8);
        vtrans<<<dim3(8, 16, BATCH), blk, 0, stream>>>(qkvg + 1024, vT, 2048);
        pdecay<<<dim3(8, 8, BATCH), blk, 0, stream>>>(
            (const short*)qkvg, (const short*)(qkvg + 512), sg, 2048, (long long)SEQ * 2048);
        // ret = scores @ v  (banded K window, dist<=2)
        pgemm128<0><<<dim3(4, 8, BATCH), blk, 0, stream>>>(
            (const short*)sg, (const short*)vT, nullptr, ret,
            SEQ, SEQ, SEQ, 512,
            (long long)SEQ * SEQ, (long long)D_MODEL * SEQ, (long long)SEQ * D_MODEL, 2);
        gate_bf16<<<NROWS / 4, blk, 0, stream>>>(ret, qkvg + 1536, 2048, gated);
        // attn delta = gated @ Wo  -> sg
        pgemm128<0><<<dim3(4, 128), blk, 0, stream>>>(
            (const short*)gated, (const short*)(WoT + l * dd), nullptr, sg,
            512, 512, 512, 512, 0, 0, 0, 0);
        // h += attn delta; y = LN2(h)
        ln_fuse<1><<<NROWS / 4, blk, 0, stream>>>(h, sg, ln2_g + l * D_MODEL,
                                                  ln2_b + l * D_MODEL, h, y);
        // hidden = gelu(y @ W1 + b1)
        gemm256p<2><<<256, 512, 0, stream>>>(
            (const short*)y, (const short*)(W1T + (long long)l * D_MODEL * HID),
            b1 + l * HID, sg, 512, 512, 512, HID, 4);
        // ffn delta = hidden @ W2 + b2 -> ret buffer
        pgemm128<1><<<dim3(4, 128), blk, 0, stream>>>(
            (const short*)sg, (const short*)(W2T + (long long)l * HID * D_MODEL),
            b2 + l * D_MODEL, ret, HID, HID, HID, 512, 0, 0, 0, 0);
    }

    pool_s1<<<256, blk, 0, stream>>>(h, ret, partial);
    pool_s2<<<32, blk, 0, stream>>>(partial, pooled);
    readout_kernel<<<32, 64, 0, stream>>>(pooled, Wro, bro, out);
}